// Round 2
// baseline (1571.139 us; speedup 1.0000x reference)
//
#include <hip/hip_runtime.h>
#include <math.h>

// ---------------------------------------------------------------------------
// GlobalSubSampleAttn: conv2d(2x2,s2)+LN -> linear(elu+1) attention -> wm+LN
//                      -> concat MLP -> LN -> +residual
// B=4, N=16384 (128x128), C=256, S=4096 (64x64), NHEAD=8, D=32
// Round 2: same fp32 structure as round 1, but workspace cut 305MB -> ~113MB
// (suspected ws overflow -> device page fault -> abort):
//   - msg buffer lives in d_out (64 MB saved)
//   - MLP runs in 8 row-chunks; h-chunk aliases Km (128 MB saved)
// ---------------------------------------------------------------------------

#define EP_NONE  0
#define EP_BIAS  1
#define EP_ELU1  2
#define EP_SCALE 3
#define EP_RELU  4

#define GA_PLAIN  0
#define GA_CONV   1
#define GA_CONCAT 2

// Transpose conv weight [O=256, CI=256, KH=2, KW=2] -> Wc[k=p*256+ci][o]
__global__ __launch_bounds__(256) void transpose_conv_w(
    const float* __restrict__ sr_w, float* __restrict__ Wc)
{
    int idx = blockIdx.x * 256 + threadIdx.x;   // 262144 total
    int o  = idx & 255;
    int k  = idx >> 8;
    int ci = k & 255;
    int p  = k >> 8;                            // kh*2+kw
    Wc[idx] = sr_w[(o << 10) + (ci << 2) + p];
}

template<int EPI>
__device__ inline float epilogue(float c, float b, float scale) {
    if (EPI == EP_BIAS)  return c + b;
    if (EPI == EP_ELU1)  return c > 0.f ? c + 1.f : expf(c);   // elu(c)+1
    if (EPI == EP_SCALE) return c * scale;
    if (EPI == EP_RELU)  return fmaxf(c, 0.f);
    return c;
}

// Tiled GEMM: C[M,N] = gather_A[M,K] @ Bw[K,N]  (+epilogue)
// 64x64 tile, BK=16, 256 threads, 4x4 microtile per thread.
template<int GATHER, int EPI>
__global__ __launch_bounds__(256) void gemm_kernel(
    const float* __restrict__ A, const float* __restrict__ A2,
    const float* __restrict__ Bw, const float* __restrict__ bias,
    float* __restrict__ C, int M, int N, int K, float scale)
{
    __shared__ float As[16][64];   // As[k][m]
    __shared__ float Bs[16][64];   // Bs[k][n]
    const int tid = threadIdx.x;
    const int bm = blockIdx.x * 64;
    const int bn = blockIdx.y * 64;
    const int tx = tid & 15, ty = tid >> 4;
    const int am = tid >> 2, akq = tid & 3;     // A-load: row am, k-quad akq
    const int bkk = tid >> 4, bnq = tid & 15;   // B-load: k row bkk, n-quad bnq

    float acc[4][4] = {};

    for (int k0 = 0; k0 < K; k0 += 16) {
        // ---- global loads (float4) ----
        int k = k0 + akq * 4;
        int grow = bm + am;
        float4 av;
        if (GATHER == GA_PLAIN) {
            av = *reinterpret_cast<const float4*>(&A[(size_t)grow * K + k]);
        } else if (GATHER == GA_CONCAT) {
            const float* p = (k < 256) ? &A[((size_t)grow << 8) + k]
                                       : &A2[((size_t)grow << 8) + (k - 256)];
            av = *reinterpret_cast<const float4*>(p);
        } else { // GA_CONV: row -> (b, i, j); k -> (p=kh*2+kw, ci)
            int b  = grow >> 12;
            int s  = grow & 4095;
            int ii = s >> 6, jj = s & 63;
            int p  = k >> 8, ci = k & 255;
            int kh = p >> 1, kw = p & 1;
            int pix = (b << 14) + ((2 * ii + kh) << 7) + (2 * jj + kw);
            av = *reinterpret_cast<const float4*>(&A[((size_t)pix << 8) + ci]);
        }
        float4 bv = *reinterpret_cast<const float4*>(
            &Bw[(size_t)(k0 + bkk) * N + bn + bnq * 4]);

        __syncthreads();   // previous compute done before overwriting LDS
        As[akq * 4 + 0][am] = av.x;
        As[akq * 4 + 1][am] = av.y;
        As[akq * 4 + 2][am] = av.z;
        As[akq * 4 + 3][am] = av.w;
        *reinterpret_cast<float4*>(&Bs[bkk][bnq * 4]) = bv;
        __syncthreads();

        // ---- compute ----
        #pragma unroll
        for (int kk = 0; kk < 16; kk++) {
            float4 a4 = *reinterpret_cast<const float4*>(&As[kk][ty * 4]);
            float4 b4 = *reinterpret_cast<const float4*>(&Bs[kk][tx * 4]);
            float ar[4] = {a4.x, a4.y, a4.z, a4.w};
            float br[4] = {b4.x, b4.y, b4.z, b4.w};
            #pragma unroll
            for (int i = 0; i < 4; i++)
                #pragma unroll
                for (int j = 0; j < 4; j++)
                    acc[i][j] = fmaf(ar[i], br[j], acc[i][j]);
        }
    }

    // ---- epilogue + store ----
    #pragma unroll
    for (int i = 0; i < 4; i++) {
        float4 o;
        int col = bn + tx * 4;
        float b0 = (EPI == EP_BIAS) ? bias[col + 0] : 0.f;
        float b1 = (EPI == EP_BIAS) ? bias[col + 1] : 0.f;
        float b2 = (EPI == EP_BIAS) ? bias[col + 2] : 0.f;
        float b3 = (EPI == EP_BIAS) ? bias[col + 3] : 0.f;
        o.x = epilogue<EPI>(acc[i][0], b0, scale);
        o.y = epilogue<EPI>(acc[i][1], b1, scale);
        o.z = epilogue<EPI>(acc[i][2], b2, scale);
        o.w = epilogue<EPI>(acc[i][3], b3, scale);
        *reinterpret_cast<float4*>(
            &C[(size_t)(bm + ty * 4 + i) * N + col]) = o;
    }
}

// block reduce (256 threads) of two values
__device__ inline float2 block_reduce2(float a, float b) {
    #pragma unroll
    for (int off = 32; off > 0; off >>= 1) {
        a += __shfl_down(a, off, 64);
        b += __shfl_down(b, off, 64);
    }
    __shared__ float sa[4], sb[4];
    int w = threadIdx.x >> 6;
    if ((threadIdx.x & 63) == 0) { sa[w] = a; sb[w] = b; }
    __syncthreads();
    float2 r;
    r.x = sa[0] + sa[1] + sa[2] + sa[3];
    r.y = sb[0] + sb[1] + sb[2] + sb[3];
    return r;
}

// LayerNorm over C=256; one block per row. RES: add residual at the end.
template<int RES>
__global__ __launch_bounds__(256) void ln_kernel(
    const float* __restrict__ in, const float* __restrict__ g,
    const float* __restrict__ bta, const float* __restrict__ res,
    float* __restrict__ out)
{
    size_t row = blockIdx.x;
    int tid = threadIdx.x;
    float v = in[(row << 8) + tid];
    float2 s = block_reduce2(v, v * v);
    float mean = s.x * (1.f / 256.f);
    float var  = s.y * (1.f / 256.f) - mean * mean;
    float inv  = rsqrtf(var + 1e-5f);
    float o = (v - mean) * inv * g[tid] + bta[tid];
    if (RES) o += res[(row << 8) + tid];
    out[(row << 8) + tid] = o;
}

// KV[b,h,d,e] = sum_s K[b,s,h,d] * Vsc[b,s,h,e];  Ksum[b,h,d] = sum_s K
// one block per (b,h); K/V stored [B*S, 256] with c = h*32+d
__global__ __launch_bounds__(256) void kv_kernel(
    const float* __restrict__ Km, const float* __restrict__ Vm,
    float* __restrict__ KV, float* __restrict__ Ksum)
{
    int bh = blockIdx.x;            // 0..31
    int b = bh >> 3, h = bh & 7;
    int tid = threadIdx.x;
    int e = tid & 31, dq = tid >> 5;     // dq 0..7
    int d_l = tid & 31, r_l = tid >> 5;  // load roles
    __shared__ float Ks[16][32], Vs[16][32];
    float acc[4] = {0.f, 0.f, 0.f, 0.f};
    float ks = 0.f;
    const size_t base = ((size_t)b * 4096) * 256 + h * 32;

    for (int s0 = 0; s0 < 4096; s0 += 16) {
        Ks[r_l][d_l]     = Km[base + (size_t)(s0 + r_l) * 256 + d_l];
        Ks[r_l + 8][d_l] = Km[base + (size_t)(s0 + r_l + 8) * 256 + d_l];
        Vs[r_l][d_l]     = Vm[base + (size_t)(s0 + r_l) * 256 + d_l];
        Vs[r_l + 8][d_l] = Vm[base + (size_t)(s0 + r_l + 8) * 256 + d_l];
        __syncthreads();
        #pragma unroll
        for (int sr = 0; sr < 16; sr++) {
            float vv = Vs[sr][e];
            #pragma unroll
            for (int i = 0; i < 4; i++)
                acc[i] = fmaf(Ks[sr][dq * 4 + i], vv, acc[i]);
        }
        if (tid < 32) {
            #pragma unroll
            for (int sr = 0; sr < 16; sr++) ks += Ks[sr][tid];
        }
        __syncthreads();
    }
    #pragma unroll
    for (int i = 0; i < 4; i++)
        KV[((size_t)bh * 32 + dq * 4 + i) * 32 + e] = acc[i];
    if (tid < 32) Ksum[bh * 32 + tid] = ks;
}

// msg[row, c=h*32+e] = (sum_d Q[row,h,d]*KV[b,h,d,e]) * S/(Q.Ksum + eps)
// one block handles 32 consecutive rows (same b)
__global__ __launch_bounds__(256) void attn_kernel(
    const float* __restrict__ Q, const float* __restrict__ KV,
    const float* __restrict__ Ksum, float* __restrict__ msg)
{
    int row0 = blockIdx.x * 32;
    int b = row0 >> 14;             // 16384 rows per batch
    int tid = threadIdx.x;
    __shared__ float KVs[8192];     // [h][d][e]
    __shared__ float Kss[256];
    __shared__ float Qs[256];
    for (int i = tid; i < 8192; i += 256) KVs[i] = KV[(size_t)b * 8192 + i];
    Kss[tid] = Ksum[b * 256 + tid];
    __syncthreads();
    int h = tid >> 5;
    int hb = h * 32;
    for (int r = 0; r < 32; r++) {
        size_t off = (size_t)(row0 + r) << 8;
        Qs[tid] = Q[off + tid];
        __syncthreads();
        float dot = 0.f, val = 0.f;
        #pragma unroll
        for (int d = 0; d < 32; d++) {
            float qd = Qs[hb + d];
            dot = fmaf(qd, Kss[hb + d], dot);
            val = fmaf(qd, KVs[(hb + d) * 32 + (tid & 31)], val);
        }
        float z = 4096.f / (dot + 1e-6f);
        msg[off + tid] = val * z;
        __syncthreads();
    }
}

extern "C" void kernel_launch(void* const* d_in, const int* in_sizes, int n_in,
                              void* d_out, int out_size, void* d_ws, size_t ws_size,
                              hipStream_t stream) {
    const float* x      = (const float*)d_in[0];   // [4,16384,256]
    const float* sr_w   = (const float*)d_in[1];   // [256,256,2,2]
    const float* sr_b   = (const float*)d_in[2];   // [256]
    const float* norm_g = (const float*)d_in[3];
    const float* norm_b = (const float*)d_in[4];
    const float* wq     = (const float*)d_in[5];   // [256,256]
    const float* wk     = (const float*)d_in[6];
    const float* wv     = (const float*)d_in[7];
    const float* wm     = (const float*)d_in[8];
    const float* mlp_w1 = (const float*)d_in[9];   // [512,512]
    const float* mlp_w2 = (const float*)d_in[10];  // [512,256]
    const float* n1_g   = (const float*)d_in[11];
    const float* n1_b   = (const float*)d_in[12];
    const float* n2_g   = (const float*)d_in[13];
    const float* n2_b   = (const float*)d_in[14];
    float* out = (float*)d_out;

    // workspace layout (floats) — total ~113 MB
    float* ws = (float*)d_ws;
    float* Wc  = ws;                    // 262144   conv weight [1024,256]
    float* xs  = Wc  + 262144;          // 4194304  [16384,256] conv+LN out
    float* Km  = xs  + 4194304;         // 4194304  K = elu(xs@wk)+1
    float* Vm  = Km  + 4194304;         // 4194304  Vsc = (xs@wv)/S
    float* KVb = Vm  + 4194304;         // 32768    [4,8,32,32]
    float* Ksb = KVb + 32768;           // 1024     [4,8,32]
    float* Qb  = Ksb + 1024;            // 16777216 [65536,256]
    float* Hc  = Km;                    // ALIAS: [8192,512] chunk (Km dead)
    float* Mb  = out;                   // ALIAS: msg lives in d_out

    const float inv_S = 1.f / 4096.f;

    // 1. conv weight transpose
    transpose_conv_w<<<1024, 256, 0, stream>>>(sr_w, Wc);
    // 2. conv as GEMM [16384,1024]@[1024,256] + bias
    gemm_kernel<GA_CONV, EP_BIAS><<<dim3(256, 4), 256, 0, stream>>>(
        x, nullptr, Wc, sr_b, xs, 16384, 256, 1024, 0.f);
    // 3. LN(xs) in place
    ln_kernel<0><<<16384, 256, 0, stream>>>(xs, norm_g, norm_b, nullptr, xs);
    // 4. K = elu(xs@wk)+1 ; Vsc = (xs@wv)/S
    gemm_kernel<GA_PLAIN, EP_ELU1><<<dim3(256, 4), 256, 0, stream>>>(
        xs, nullptr, wk, nullptr, Km, 16384, 256, 256, 0.f);
    gemm_kernel<GA_PLAIN, EP_SCALE><<<dim3(256, 4), 256, 0, stream>>>(
        xs, nullptr, wv, nullptr, Vm, 16384, 256, 256, inv_S);
    // 5. KV + Ksum
    kv_kernel<<<32, 256, 0, stream>>>(Km, Vm, KVb, Ksb);
    // 6. Q = elu(x@wq)+1
    gemm_kernel<GA_PLAIN, EP_ELU1><<<dim3(1024, 4), 256, 0, stream>>>(
        x, nullptr, wq, nullptr, Qb, 65536, 256, 256, 0.f);
    // 7. attention core -> Mb (= d_out), fully overwritten before reads
    attn_kernel<<<2048, 256, 0, stream>>>(Qb, KVb, Ksb, Mb);
    // 8. msg @ wm -> Qb (Q dead)
    gemm_kernel<GA_PLAIN, EP_NONE><<<dim3(1024, 4), 256, 0, stream>>>(
        Mb, nullptr, wm, nullptr, Qb, 65536, 256, 256, 0.f);
    // 9. LN -> Mb (= d_out) holds msg_ln
    ln_kernel<0><<<65536, 256, 0, stream>>>(Qb, n1_g, n1_b, nullptr, Mb);
    // 10+11. MLP in 8 chunks of 8192 rows; h-chunk aliases Km
    for (int c = 0; c < 8; c++) {
        size_t r0 = (size_t)c * 8192;
        gemm_kernel<GA_CONCAT, EP_RELU><<<dim3(128, 8), 256, 0, stream>>>(
            x + r0 * 256, Mb + r0 * 256, mlp_w1, nullptr, Hc,
            8192, 512, 512, 0.f);
        gemm_kernel<GA_PLAIN, EP_NONE><<<dim3(128, 4), 256, 0, stream>>>(
            Hc, nullptr, mlp_w2, nullptr, Qb + r0 * 256,
            8192, 256, 512, 0.f);
    }
    // 12. out = LN(Qb) + x  (in-place safe: d_out read pattern is per-thread)
    ln_kernel<1><<<65536, 256, 0, stream>>>(Qb, n2_g, n2_b, x, out);
}

// Round 4
// 591.536 us; speedup vs baseline: 2.6560x; 2.6560x over previous
//
#include <hip/hip_runtime.h>
#include <math.h>

// ---------------------------------------------------------------------------
// GlobalSubSampleAttn round 3 (resubmit — round-3 bench died on infra):
//  - all GEMMs -> bf16 MFMA (16x16x32), 128x128 tile, BK=32, fp32 accum
//  - kv reduction split into kv_partial (1024 blocks) + kv_reduce (32)
// B=4, N=16384 (128x128), C=256, S=4096 (64x64), NHEAD=8, D=32
// ---------------------------------------------------------------------------

#define EP_NONE  0
#define EP_BIAS  1
#define EP_ELU1  2
#define EP_SCALE 3
#define EP_RELU  4

#define GA_PLAIN  0
#define GA_CONV   1
#define GA_CONCAT 2

typedef __attribute__((ext_vector_type(8))) short short8v;   // 8 bf16
typedef __attribute__((ext_vector_type(4))) float f32x4;

__device__ inline short f2bf(float f) {
    unsigned u = __float_as_uint(f);
    u += 0x7FFFu + ((u >> 16) & 1u);      // round-to-nearest-even
    return (short)(u >> 16);
}

template<int EPI>
__device__ inline float epilogue(float c, float b, float scale) {
    if (EPI == EP_BIAS)  return c + b;
    if (EPI == EP_ELU1)  return c > 0.f ? c + 1.f : expf(c);   // elu(c)+1
    if (EPI == EP_SCALE) return c * scale;
    if (EPI == EP_RELU)  return fmaxf(c, 0.f);
    return c;
}

// W[K][N] fp32 -> Wt[N][K] bf16
__global__ __launch_bounds__(256) void transpose_w_bf16(
    const float* __restrict__ W, short* __restrict__ Wt, int Kd, int Nd)
{
    int idx = blockIdx.x * 256 + threadIdx.x;
    if (idx >= Kd * Nd) return;
    int n = idx / Kd, k = idx - n * Kd;
    Wt[idx] = f2bf(W[(size_t)k * Nd + n]);
}

// sr_w[o][ci][p] (o=256,ci=256,p=4) -> Wt[o][k=p*256+ci] bf16  (Bt form, K=1024)
__global__ __launch_bounds__(256) void transpose_conv_bf16(
    const float* __restrict__ srw, short* __restrict__ Wt)
{
    int idx = blockIdx.x * 256 + threadIdx.x;   // 262144
    int o = idx >> 10, k = idx & 1023;
    int p = k >> 8, ci = k & 255;
    Wt[idx] = f2bf(srw[(o << 10) + (ci << 2) + p]);
}

// ---------------------------------------------------------------------------
// MFMA GEMM: C[M,N] = gather_A[M,K] @ Bt[N,K]^T  (+epilogue), fp32 in/out.
// 128x128 tile, BK=32, 256 threads = 4 waves in 2x2, each wave 64x64
// (4x4 frags of 16x16x32). A staged fp32->bf16; B pre-transposed bf16.
// LDS padded [128][40] shorts: frag reads ~2-way bank alias (free).
// ---------------------------------------------------------------------------
template<int GATHER, int EPI>
__global__ __launch_bounds__(256) void gemm_mfma(
    const float* __restrict__ A, const float* __restrict__ A2,
    const short* __restrict__ Bt, const float* __restrict__ bias,
    float* __restrict__ C, int M, int N, int K, float scale)
{
    __shared__ short Al[128][40];
    __shared__ short Bl[128][40];
    const int tid  = threadIdx.x;
    const int bm   = blockIdx.x * 128;
    const int bn   = blockIdx.y * 128;
    const int lane = tid & 63;
    const int wave = tid >> 6;
    const int wr   = (wave >> 1) * 64;
    const int wc   = (wave & 1) * 64;
    const int l15  = lane & 15;
    const int kg   = lane >> 4;          // 0..3

    f32x4 acc[4][4];
    #pragma unroll
    for (int m = 0; m < 4; m++)
        #pragma unroll
        for (int n = 0; n < 4; n++)
            acc[m][n] = (f32x4){0.f, 0.f, 0.f, 0.f};

    const int ar  = tid >> 3;            // A stage: row 0..31 (+p*32)
    const int ak  = (tid & 7) * 4;       //          k 0,4,..,28
    const int brn = tid >> 2;            // B stage: n 0..63 (+p*64)
    const int bk  = (tid & 3) * 8;       //          k 0,8,16,24

    for (int k0 = 0; k0 < K; k0 += 32) {
        // ---- global loads to regs ----
        float4 av[4];
        #pragma unroll
        for (int p = 0; p < 4; p++) {
            int grow = bm + ar + p * 32;
            int k = k0 + ak;
            if (GATHER == GA_PLAIN) {
                av[p] = *reinterpret_cast<const float4*>(&A[(size_t)grow * K + k]);
            } else if (GATHER == GA_CONCAT) {
                const float* src = (k < 256)
                    ? &A[((size_t)grow << 8) + k]
                    : &A2[((size_t)grow << 8) + (k - 256)];
                av[p] = *reinterpret_cast<const float4*>(src);
            } else { // GA_CONV
                int b  = grow >> 12, s = grow & 4095;
                int ii = s >> 6, jj = s & 63;
                int pp = k >> 8, ci = k & 255;
                int kh = pp >> 1, kw = pp & 1;
                int pix = (b << 14) + ((2 * ii + kh) << 7) + (2 * jj + kw);
                av[p] = *reinterpret_cast<const float4*>(&A[((size_t)pix << 8) + ci]);
            }
        }
        uint4 bv[2];
        #pragma unroll
        for (int p = 0; p < 2; p++)
            bv[p] = *reinterpret_cast<const uint4*>(
                &Bt[(size_t)(bn + brn + p * 64) * K + k0 + bk]);

        __syncthreads();   // previous compute done before LDS overwrite
        #pragma unroll
        for (int p = 0; p < 4; p++) {
            short4 s4;
            s4.x = f2bf(av[p].x); s4.y = f2bf(av[p].y);
            s4.z = f2bf(av[p].z); s4.w = f2bf(av[p].w);
            *reinterpret_cast<short4*>(&Al[ar + p * 32][ak]) = s4;
        }
        #pragma unroll
        for (int p = 0; p < 2; p++)
            *reinterpret_cast<uint4*>(&Bl[brn + p * 64][bk]) = bv[p];
        __syncthreads();

        // ---- fragments + MFMA ----
        short8v afr[4], bfr[4];
        #pragma unroll
        for (int m = 0; m < 4; m++)
            afr[m] = *reinterpret_cast<const short8v*>(&Al[wr + m * 16 + l15][kg * 8]);
        #pragma unroll
        for (int n = 0; n < 4; n++)
            bfr[n] = *reinterpret_cast<const short8v*>(&Bl[wc + n * 16 + l15][kg * 8]);
        #pragma unroll
        for (int m = 0; m < 4; m++)
            #pragma unroll
            for (int n = 0; n < 4; n++)
                acc[m][n] = __builtin_amdgcn_mfma_f32_16x16x32_bf16(
                    afr[m], bfr[n], acc[m][n], 0, 0, 0);
    }

    // ---- epilogue + store (D: col=lane&15, row=(lane>>4)*4+j) ----
    const int r0 = (lane >> 4) * 4;
    #pragma unroll
    for (int n = 0; n < 4; n++) {
        int col = bn + wc + n * 16 + l15;
        float bb = (EPI == EP_BIAS) ? bias[col] : 0.f;
        #pragma unroll
        for (int m = 0; m < 4; m++) {
            int rowb = bm + wr + m * 16 + r0;
            #pragma unroll
            for (int j = 0; j < 4; j++) {
                float o = epilogue<EPI>(acc[m][n][j], bb, scale);
                C[(size_t)(rowb + j) * N + col] = o;
            }
        }
    }
}

// block reduce (256 threads) of two values
__device__ inline float2 block_reduce2(float a, float b) {
    #pragma unroll
    for (int off = 32; off > 0; off >>= 1) {
        a += __shfl_down(a, off, 64);
        b += __shfl_down(b, off, 64);
    }
    __shared__ float sa[4], sb[4];
    int w = threadIdx.x >> 6;
    if ((threadIdx.x & 63) == 0) { sa[w] = a; sb[w] = b; }
    __syncthreads();
    float2 r;
    r.x = sa[0] + sa[1] + sa[2] + sa[3];
    r.y = sb[0] + sb[1] + sb[2] + sb[3];
    return r;
}

// LayerNorm over C=256; one block per row. RES: add residual at the end.
template<int RES>
__global__ __launch_bounds__(256) void ln_kernel(
    const float* __restrict__ in, const float* __restrict__ g,
    const float* __restrict__ bta, const float* __restrict__ res,
    float* __restrict__ out)
{
    size_t row = blockIdx.x;
    int tid = threadIdx.x;
    float v = in[(row << 8) + tid];
    float2 s = block_reduce2(v, v * v);
    float mean = s.x * (1.f / 256.f);
    float var  = s.y * (1.f / 256.f) - mean * mean;
    float inv  = rsqrtf(var + 1e-5f);
    float o = (v - mean) * inv * g[tid] + bta[tid];
    if (RES) o += res[(row << 8) + tid];
    out[(row << 8) + tid] = o;
}

// partial KV over a 128-row s-chunk; blockIdx.x = bh*32 + chunk
__global__ __launch_bounds__(256) void kv_partial(
    const float* __restrict__ Km, const float* __restrict__ Vm,
    float* __restrict__ pKV, float* __restrict__ pKs)
{
    int blk = blockIdx.x;
    int bh = blk >> 5, chunk = blk & 31;
    int b = bh >> 3, h = bh & 7;
    int tid = threadIdx.x;
    int e = tid & 31, dq = tid >> 5;
    int d_l = tid & 31, r_l = tid >> 5;
    __shared__ float Ks[16][32], Vs[16][32];
    float acc[4] = {0.f, 0.f, 0.f, 0.f};
    float ks = 0.f;
    const size_t base = ((size_t)b * 4096 + chunk * 128) * 256 + h * 32;

    for (int s0 = 0; s0 < 128; s0 += 16) {
        Ks[r_l][d_l]     = Km[base + (size_t)(s0 + r_l) * 256 + d_l];
        Ks[r_l + 8][d_l] = Km[base + (size_t)(s0 + r_l + 8) * 256 + d_l];
        Vs[r_l][d_l]     = Vm[base + (size_t)(s0 + r_l) * 256 + d_l];
        Vs[r_l + 8][d_l] = Vm[base + (size_t)(s0 + r_l + 8) * 256 + d_l];
        __syncthreads();
        #pragma unroll
        for (int sr = 0; sr < 16; sr++) {
            float vv = Vs[sr][e];
            #pragma unroll
            for (int i = 0; i < 4; i++)
                acc[i] = fmaf(Ks[sr][dq * 4 + i], vv, acc[i]);
        }
        if (tid < 32) {
            #pragma unroll
            for (int sr = 0; sr < 16; sr++) ks += Ks[sr][tid];
        }
        __syncthreads();
    }
    #pragma unroll
    for (int i = 0; i < 4; i++)
        pKV[(size_t)blk * 1024 + (dq * 4 + i) * 32 + e] = acc[i];
    if (tid < 32) pKs[blk * 32 + tid] = ks;
}

// reduce 32 chunks -> KV[bh][1024], Ksum[bh][32]
__global__ __launch_bounds__(256) void kv_reduce(
    const float* __restrict__ pKV, const float* __restrict__ pKs,
    float* __restrict__ KV, float* __restrict__ Ksum)
{
    int bh = blockIdx.x;
    int tid = threadIdx.x;
    float s0 = 0.f, s1 = 0.f, s2 = 0.f, s3 = 0.f;
    for (int c = 0; c < 32; c++) {
        const float* p = &pKV[(size_t)(bh * 32 + c) * 1024];
        s0 += p[tid]; s1 += p[tid + 256]; s2 += p[tid + 512]; s3 += p[tid + 768];
    }
    KV[bh * 1024 + tid]       = s0;
    KV[bh * 1024 + tid + 256] = s1;
    KV[bh * 1024 + tid + 512] = s2;
    KV[bh * 1024 + tid + 768] = s3;
    if (tid < 32) {
        float s = 0.f;
        for (int c = 0; c < 32; c++) s += pKs[(bh * 32 + c) * 32 + tid];
        Ksum[bh * 32 + tid] = s;
    }
}

// msg[row, c=h*32+e] = (sum_d Q[row,h,d]*KV[b,h,d,e]) * S/(Q.Ksum + eps)
__global__ __launch_bounds__(256) void attn_kernel(
    const float* __restrict__ Q, const float* __restrict__ KV,
    const float* __restrict__ Ksum, float* __restrict__ msg)
{
    int row0 = blockIdx.x * 32;
    int b = row0 >> 14;
    int tid = threadIdx.x;
    __shared__ float KVs[8192];
    __shared__ float Kss[256];
    __shared__ float Qs[256];
    for (int i = tid; i < 8192; i += 256) KVs[i] = KV[(size_t)b * 8192 + i];
    Kss[tid] = Ksum[b * 256 + tid];
    __syncthreads();
    int hb = (tid >> 5) * 32;
    for (int r = 0; r < 32; r++) {
        size_t off = (size_t)(row0 + r) << 8;
        Qs[tid] = Q[off + tid];
        __syncthreads();
        float dot = 0.f, val = 0.f;
        #pragma unroll
        for (int d = 0; d < 32; d++) {
            float qd = Qs[hb + d];
            dot = fmaf(qd, Kss[hb + d], dot);
            val = fmaf(qd, KVs[(hb + d) * 32 + (tid & 31)], val);
        }
        float z = 4096.f / (dot + 1e-6f);
        msg[off + tid] = val * z;
        __syncthreads();
    }
}

extern "C" void kernel_launch(void* const* d_in, const int* in_sizes, int n_in,
                              void* d_out, int out_size, void* d_ws, size_t ws_size,
                              hipStream_t stream) {
    const float* x      = (const float*)d_in[0];
    const float* sr_w   = (const float*)d_in[1];
    const float* sr_b   = (const float*)d_in[2];
    const float* norm_g = (const float*)d_in[3];
    const float* norm_b = (const float*)d_in[4];
    const float* wq     = (const float*)d_in[5];
    const float* wk     = (const float*)d_in[6];
    const float* wv     = (const float*)d_in[7];
    const float* wm     = (const float*)d_in[8];
    const float* mlp_w1 = (const float*)d_in[9];
    const float* mlp_w2 = (const float*)d_in[10];
    const float* n1_g   = (const float*)d_in[11];
    const float* n1_b   = (const float*)d_in[12];
    const float* n2_g   = (const float*)d_in[13];
    const float* n2_b   = (const float*)d_in[14];
    float* out = (float*)d_out;

    // ---- workspace layout (~114 MB) ----
    float* ws = (float*)d_ws;
    short* Wct = (short*)ws;            // 262144 shorts  conv Bt [256][1024]
    short* Wqt = Wct + 262144;          // 65536
    short* Wkt = Wqt + 65536;
    short* Wvt = Wkt + 65536;
    short* Wmt = Wvt + 65536;
    short* W1t = Wmt + 65536;           // 262144  [512][512]
    short* W2t = W1t + 262144;          // 131072  [256][512]
    float* xs  = ws + 458752;           // 4194304  [16384,256]
    float* Km  = xs  + 4194304;         // 4194304
    float* Vm  = Km  + 4194304;         // 4194304
    float* KVb = Vm  + 4194304;         // 32768
    float* Ksb = KVb + 32768;           // 1024
    float* Qb  = Ksb + 1024;            // 16777216 [65536,256]
    float* pKV = Qb;                    // ALIAS: 1048576 (dead before Q gemm)
    float* pKs = Qb + 1048576;          // ALIAS: 32768
    float* Hc  = Km;                    // ALIAS: [16384,512] over Km+Vm
    float* Mb  = out;                   // msg lives in d_out

    const float inv_S = 1.f / 4096.f;

    // weight prep (bf16, Bt form)
    transpose_conv_bf16<<<1024, 256, 0, stream>>>(sr_w, Wct);
    transpose_w_bf16<<<256,  256, 0, stream>>>(wq, Wqt, 256, 256);
    transpose_w_bf16<<<256,  256, 0, stream>>>(wk, Wkt, 256, 256);
    transpose_w_bf16<<<256,  256, 0, stream>>>(wv, Wvt, 256, 256);
    transpose_w_bf16<<<256,  256, 0, stream>>>(wm, Wmt, 256, 256);
    transpose_w_bf16<<<1024, 256, 0, stream>>>(mlp_w1, W1t, 512, 512);
    transpose_w_bf16<<<512,  256, 0, stream>>>(mlp_w2, W2t, 512, 256);

    // conv as GEMM + bias -> xs; LN in place
    gemm_mfma<GA_CONV, EP_BIAS><<<dim3(128, 2), 256, 0, stream>>>(
        x, nullptr, Wct, sr_b, xs, 16384, 256, 1024, 0.f);
    ln_kernel<0><<<16384, 256, 0, stream>>>(xs, norm_g, norm_b, nullptr, xs);

    // K = elu(xs@wk)+1 ; Vsc = (xs@wv)/S
    gemm_mfma<GA_PLAIN, EP_ELU1><<<dim3(128, 2), 256, 0, stream>>>(
        xs, nullptr, Wkt, nullptr, Km, 16384, 256, 256, 0.f);
    gemm_mfma<GA_PLAIN, EP_SCALE><<<dim3(128, 2), 256, 0, stream>>>(
        xs, nullptr, Wvt, nullptr, Vm, 16384, 256, 256, inv_S);

    // KV + Ksum (two-stage)
    kv_partial<<<1024, 256, 0, stream>>>(Km, Vm, pKV, pKs);
    kv_reduce<<<32, 256, 0, stream>>>(pKV, pKs, KVb, Ksb);

    // Q = elu(x@wq)+1  (overwrites pKV alias region)
    gemm_mfma<GA_PLAIN, EP_ELU1><<<dim3(512, 2), 256, 0, stream>>>(
        x, nullptr, Wqt, nullptr, Qb, 65536, 256, 256, 0.f);

    // attention core -> Mb (= d_out)
    attn_kernel<<<2048, 256, 0, stream>>>(Qb, KVb, Ksb, Mb);

    // msg @ wm -> Qb; LN -> Mb
    gemm_mfma<GA_PLAIN, EP_NONE><<<dim3(512, 2), 256, 0, stream>>>(
        Mb, nullptr, Wmt, nullptr, Qb, 65536, 256, 256, 0.f);
    ln_kernel<0><<<65536, 256, 0, stream>>>(Qb, n1_g, n1_b, nullptr, Mb);

    // MLP in 4 chunks of 16384 rows (Hc aliases Km+Vm, 32 MB)
    for (int c = 0; c < 4; c++) {
        size_t r0 = (size_t)c * 16384;
        gemm_mfma<GA_CONCAT, EP_RELU><<<dim3(128, 4), 256, 0, stream>>>(
            x + r0 * 256, Mb + r0 * 256, W1t, nullptr, Hc,
            16384, 512, 512, 0.f);
        gemm_mfma<GA_PLAIN, EP_NONE><<<dim3(128, 2), 256, 0, stream>>>(
            Hc, nullptr, W2t, nullptr, Qb + r0 * 256,
            16384, 256, 512, 0.f);
    }

    // out = LN(Qb) + x
    ln_kernel<1><<<65536, 256, 0, stream>>>(Qb, n2_g, n2_b, x, out);
}

// Round 5
// 523.519 us; speedup vs baseline: 3.0011x; 1.1299x over previous
//
#include <hip/hip_runtime.h>
#include <math.h>

// ---------------------------------------------------------------------------
// GlobalSubSampleAttn round 5:
//  - attn_kernel ELIMINATED: Z folded into Q-GEMM epilogue (shfl-reduce),
//    KV@wm folded into per-batch W2 (w2_prep);  msg@wm == Qz @ W2[b]
//  - Qz stored bf16 (halves A-traffic of the follow-up GEMM)
//  - all GEMMs bf16 MFMA 16x16x32, 128x128 tile, BK=32, fp32 accum
// B=4, N=16384 (128x128), C=256, S=4096 (64x64), NHEAD=8, D=32
// ---------------------------------------------------------------------------

#define EP_NONE  0
#define EP_BIAS  1
#define EP_ELU1  2
#define EP_SCALE 3
#define EP_RELU  4

#define GA_PLAIN  0
#define GA_CONV   1
#define GA_CONCAT 2

typedef __attribute__((ext_vector_type(8))) short short8v;   // 8 bf16
typedef __attribute__((ext_vector_type(4))) float f32x4;

__device__ inline short f2bf(float f) {
    unsigned u = __float_as_uint(f);
    u += 0x7FFFu + ((u >> 16) & 1u);      // round-to-nearest-even
    return (short)(u >> 16);
}

template<int EPI>
__device__ inline float epilogue(float c, float b, float scale) {
    if (EPI == EP_BIAS)  return c + b;
    if (EPI == EP_ELU1)  return c > 0.f ? c + 1.f : expf(c);   // elu(c)+1
    if (EPI == EP_SCALE) return c * scale;
    if (EPI == EP_RELU)  return fmaxf(c, 0.f);
    return c;
}

// W[K][N] fp32 -> Wt[N][K] bf16
__global__ __launch_bounds__(256) void transpose_w_bf16(
    const float* __restrict__ W, short* __restrict__ Wt, int Kd, int Nd)
{
    int idx = blockIdx.x * 256 + threadIdx.x;
    if (idx >= Kd * Nd) return;
    int n = idx / Kd, k = idx - n * Kd;
    Wt[idx] = f2bf(W[(size_t)k * Nd + n]);
}

// sr_w[o][ci][p] (o=256,ci=256,p=4) -> Wt[o][k=p*256+ci] bf16  (Bt, K=1024)
__global__ __launch_bounds__(256) void transpose_conv_bf16(
    const float* __restrict__ srw, short* __restrict__ Wt)
{
    int idx = blockIdx.x * 256 + threadIdx.x;   // 262144
    int o = idx >> 10, k = idx & 1023;
    int p = k >> 8, ci = k & 255;
    Wt[idx] = f2bf(srw[(o << 10) + (ci << 2) + p]);
}

// W2a[b][n][k=h*32+d] = sum_v KV[b,h,d,v] * wm[h*32+v, n]   (bf16 Bt form)
// one block per (b,n): 1024 blocks
__global__ __launch_bounds__(256) void w2_prep(
    const float* __restrict__ KVb, const float* __restrict__ wm,
    short* __restrict__ W2a)
{
    int b = blockIdx.x >> 8, n = blockIdx.x & 255;
    int tid = threadIdx.x;                 // = k
    __shared__ float wcol[256];
    wcol[tid] = wm[tid * 256 + n];
    __syncthreads();
    int h = tid >> 5, d = tid & 31;
    const float* kv = &KVb[b * 8192 + h * 1024 + d * 32];
    float s = 0.f;
    #pragma unroll
    for (int v = 0; v < 32; v++) s = fmaf(kv[v], wcol[h * 32 + v], s);
    W2a[((size_t)(b * 256 + n) << 8) + tid] = f2bf(s);
}

// ---------------------------------------------------------------------------
// MFMA GEMM: C[M,N] = gather_A[M,K] @ Bt[N,K]^T  (+epilogue), fp32 out.
// 128x128 tile, BK=32, 256 threads = 4 waves in 2x2, each wave 64x64.
// ABF: A is bf16 [M][K] (K=256). BB: Bt has per-batch blocks of 256*256
// (batch = row>>14). LDS padded [128][40] shorts (2-way alias, free).
// ---------------------------------------------------------------------------
template<int GATHER, int EPI, int ABF, int BB>
__global__ __launch_bounds__(256) void gemm_mfma(
    const float* __restrict__ A, const float* __restrict__ A2,
    const short* __restrict__ Bt, const float* __restrict__ bias,
    float* __restrict__ C, int M, int N, int K, float scale)
{
    __shared__ short Al[128][40];
    __shared__ short Bl[128][40];
    const int tid  = threadIdx.x;
    const int bm   = blockIdx.x * 128;
    const int bn   = blockIdx.y * 128;
    const int lane = tid & 63;
    const int wave = tid >> 6;
    const int wr   = (wave >> 1) * 64;
    const int wc   = (wave & 1) * 64;
    const int l15  = lane & 15;
    const int kg   = lane >> 4;          // 0..3

    if (BB) Bt += ((size_t)(bm >> 14)) << 16;   // per-batch 256x256 block

    f32x4 acc[4][4];
    #pragma unroll
    for (int m = 0; m < 4; m++)
        #pragma unroll
        for (int n = 0; n < 4; n++)
            acc[m][n] = (f32x4){0.f, 0.f, 0.f, 0.f};

    const int ar  = tid >> 3;            // A fp32 stage: row 0..31 (+p*32)
    const int ak  = (tid & 7) * 4;
    const int brn = tid >> 2;            // B / A-bf16 stage: row 0..63 (+p*64)
    const int bk  = (tid & 3) * 8;

    for (int k0 = 0; k0 < K; k0 += 32) {
        float4 av[4];
        uint4  avb[2];
        if (ABF) {
            const short* Ab = (const short*)A;
            #pragma unroll
            for (int p = 0; p < 2; p++)
                avb[p] = *reinterpret_cast<const uint4*>(
                    &Ab[(size_t)(bm + brn + p * 64) * 256 + k0 + bk]);
        } else {
            #pragma unroll
            for (int p = 0; p < 4; p++) {
                int grow = bm + ar + p * 32;
                int k = k0 + ak;
                if (GATHER == GA_PLAIN) {
                    av[p] = *reinterpret_cast<const float4*>(&A[(size_t)grow * K + k]);
                } else if (GATHER == GA_CONCAT) {
                    const float* src = (k < 256)
                        ? &A[((size_t)grow << 8) + k]
                        : &A2[((size_t)grow << 8) + (k - 256)];
                    av[p] = *reinterpret_cast<const float4*>(src);
                } else { // GA_CONV
                    int b  = grow >> 12, s = grow & 4095;
                    int ii = s >> 6, jj = s & 63;
                    int pp = k >> 8, ci = k & 255;
                    int kh = pp >> 1, kw = pp & 1;
                    int pix = (b << 14) + ((2 * ii + kh) << 7) + (2 * jj + kw);
                    av[p] = *reinterpret_cast<const float4*>(&A[((size_t)pix << 8) + ci]);
                }
            }
        }
        uint4 bv[2];
        #pragma unroll
        for (int p = 0; p < 2; p++)
            bv[p] = *reinterpret_cast<const uint4*>(
                &Bt[(size_t)(bn + brn + p * 64) * K + k0 + bk]);

        __syncthreads();
        if (ABF) {
            #pragma unroll
            for (int p = 0; p < 2; p++)
                *reinterpret_cast<uint4*>(&Al[brn + p * 64][bk]) = avb[p];
        } else {
            #pragma unroll
            for (int p = 0; p < 4; p++) {
                short4 s4;
                s4.x = f2bf(av[p].x); s4.y = f2bf(av[p].y);
                s4.z = f2bf(av[p].z); s4.w = f2bf(av[p].w);
                *reinterpret_cast<short4*>(&Al[ar + p * 32][ak]) = s4;
            }
        }
        #pragma unroll
        for (int p = 0; p < 2; p++)
            *reinterpret_cast<uint4*>(&Bl[brn + p * 64][bk]) = bv[p];
        __syncthreads();

        short8v afr[4], bfr[4];
        #pragma unroll
        for (int m = 0; m < 4; m++)
            afr[m] = *reinterpret_cast<const short8v*>(&Al[wr + m * 16 + l15][kg * 8]);
        #pragma unroll
        for (int n = 0; n < 4; n++)
            bfr[n] = *reinterpret_cast<const short8v*>(&Bl[wc + n * 16 + l15][kg * 8]);
        #pragma unroll
        for (int m = 0; m < 4; m++)
            #pragma unroll
            for (int n = 0; n < 4; n++)
                acc[m][n] = __builtin_amdgcn_mfma_f32_16x16x32_bf16(
                    afr[m], bfr[n], acc[m][n], 0, 0, 0);
    }

    const int r0 = (lane >> 4) * 4;
    #pragma unroll
    for (int n = 0; n < 4; n++) {
        int col = bn + wc + n * 16 + l15;
        float bb = (EPI == EP_BIAS) ? bias[col] : 0.f;
        #pragma unroll
        for (int m = 0; m < 4; m++) {
            int rowb = bm + wr + m * 16 + r0;
            #pragma unroll
            for (int j = 0; j < 4; j++) {
                float o = epilogue<EPI>(acc[m][n][j], bb, scale);
                C[(size_t)(rowb + j) * N + col] = o;
            }
        }
    }
}

// ---------------------------------------------------------------------------
// Q GEMM with fused attention-Z epilogue:
//   Q = elu(x@wq)+1;  Z[row,h] = S/(Q_h . Ksum_h + eps);  Qz = Z*Q  (bf16 out)
// Per-head dot lives in 2 col-fragments x 16 l15-lanes -> shfl_xor reduce.
// ---------------------------------------------------------------------------
__global__ __launch_bounds__(256) void gemm_qz(
    const float* __restrict__ A, const short* __restrict__ Bt,
    const float* __restrict__ Ksb, short* __restrict__ Qz, int M)
{
    __shared__ short Al[128][40];
    __shared__ short Bl[128][40];
    const int tid  = threadIdx.x;
    const int bm   = blockIdx.x * 128;
    const int bn   = blockIdx.y * 128;
    const int lane = tid & 63;
    const int wave = tid >> 6;
    const int wr   = (wave >> 1) * 64;
    const int wc   = (wave & 1) * 64;
    const int l15  = lane & 15;
    const int kg   = lane >> 4;

    f32x4 acc[4][4];
    #pragma unroll
    for (int m = 0; m < 4; m++)
        #pragma unroll
        for (int n = 0; n < 4; n++)
            acc[m][n] = (f32x4){0.f, 0.f, 0.f, 0.f};

    const int ar  = tid >> 3;
    const int ak  = (tid & 7) * 4;
    const int brn = tid >> 2;
    const int bk  = (tid & 3) * 8;

    for (int k0 = 0; k0 < 256; k0 += 32) {
        float4 av[4];
        #pragma unroll
        for (int p = 0; p < 4; p++)
            av[p] = *reinterpret_cast<const float4*>(
                &A[(size_t)(bm + ar + p * 32) * 256 + k0 + ak]);
        uint4 bv[2];
        #pragma unroll
        for (int p = 0; p < 2; p++)
            bv[p] = *reinterpret_cast<const uint4*>(
                &Bt[(size_t)(bn + brn + p * 64) * 256 + k0 + bk]);
        __syncthreads();
        #pragma unroll
        for (int p = 0; p < 4; p++) {
            short4 s4;
            s4.x = f2bf(av[p].x); s4.y = f2bf(av[p].y);
            s4.z = f2bf(av[p].z); s4.w = f2bf(av[p].w);
            *reinterpret_cast<short4*>(&Al[ar + p * 32][ak]) = s4;
        }
        #pragma unroll
        for (int p = 0; p < 2; p++)
            *reinterpret_cast<uint4*>(&Bl[brn + p * 64][bk]) = bv[p];
        __syncthreads();
        short8v afr[4], bfr[4];
        #pragma unroll
        for (int m = 0; m < 4; m++)
            afr[m] = *reinterpret_cast<const short8v*>(&Al[wr + m * 16 + l15][kg * 8]);
        #pragma unroll
        for (int n = 0; n < 4; n++)
            bfr[n] = *reinterpret_cast<const short8v*>(&Bl[wc + n * 16 + l15][kg * 8]);
        #pragma unroll
        for (int m = 0; m < 4; m++)
            #pragma unroll
            for (int n = 0; n < 4; n++)
                acc[m][n] = __builtin_amdgcn_mfma_f32_16x16x32_bf16(
                    afr[m], bfr[n], acc[m][n], 0, 0, 0);
    }

    // epilogue: elu+1, per-(row,head) Z, scale, bf16 store
    const int b = bm >> 14;                    // batch (rows/16384)
    float Ksf[4];
    #pragma unroll
    for (int n = 0; n < 4; n++)
        Ksf[n] = Ksb[b * 256 + bn + wc + n * 16 + l15];
    #pragma unroll
    for (int m = 0; m < 4; m++)
        #pragma unroll
        for (int n = 0; n < 4; n++)
            #pragma unroll
            for (int j = 0; j < 4; j++) {
                float c = acc[m][n][j];
                acc[m][n][j] = c > 0.f ? c + 1.f : expf(c);
            }
    #pragma unroll
    for (int hh = 0; hh < 2; hh++) {
        #pragma unroll
        for (int m = 0; m < 4; m++)
            #pragma unroll
            for (int j = 0; j < 4; j++) {
                float part = acc[m][2 * hh][j] * Ksf[2 * hh]
                           + acc[m][2 * hh + 1][j] * Ksf[2 * hh + 1];
                part += __shfl_xor(part, 1, 64);
                part += __shfl_xor(part, 2, 64);
                part += __shfl_xor(part, 4, 64);
                part += __shfl_xor(part, 8, 64);
                float z = 4096.f / (part + 1e-6f);
                acc[m][2 * hh][j]     *= z;
                acc[m][2 * hh + 1][j] *= z;
            }
    }
    const int r0 = (lane >> 4) * 4;
    #pragma unroll
    for (int n = 0; n < 4; n++) {
        int col = bn + wc + n * 16 + l15;
        #pragma unroll
        for (int m = 0; m < 4; m++) {
            int rowb = bm + wr + m * 16 + r0;
            #pragma unroll
            for (int j = 0; j < 4; j++)
                Qz[(size_t)(rowb + j) * 256 + col] = f2bf(acc[m][n][j]);
        }
    }
}

// block reduce (256 threads) of two values
__device__ inline float2 block_reduce2(float a, float b) {
    #pragma unroll
    for (int off = 32; off > 0; off >>= 1) {
        a += __shfl_down(a, off, 64);
        b += __shfl_down(b, off, 64);
    }
    __shared__ float sa[4], sb[4];
    int w = threadIdx.x >> 6;
    if ((threadIdx.x & 63) == 0) { sa[w] = a; sb[w] = b; }
    __syncthreads();
    float2 r;
    r.x = sa[0] + sa[1] + sa[2] + sa[3];
    r.y = sb[0] + sb[1] + sb[2] + sb[3];
    return r;
}

template<int RES>
__global__ __launch_bounds__(256) void ln_kernel(
    const float* __restrict__ in, const float* __restrict__ g,
    const float* __restrict__ bta, const float* __restrict__ res,
    float* __restrict__ out)
{
    size_t row = blockIdx.x;
    int tid = threadIdx.x;
    float v = in[(row << 8) + tid];
    float2 s = block_reduce2(v, v * v);
    float mean = s.x * (1.f / 256.f);
    float var  = s.y * (1.f / 256.f) - mean * mean;
    float inv  = rsqrtf(var + 1e-5f);
    float o = (v - mean) * inv * g[tid] + bta[tid];
    if (RES) o += res[(row << 8) + tid];
    out[(row << 8) + tid] = o;
}

// partial KV over a 128-row s-chunk; blockIdx.x = bh*32 + chunk
__global__ __launch_bounds__(256) void kv_partial(
    const float* __restrict__ Km, const float* __restrict__ Vm,
    float* __restrict__ pKV, float* __restrict__ pKs)
{
    int blk = blockIdx.x;
    int bh = blk >> 5, chunk = blk & 31;
    int b = bh >> 3, h = bh & 7;
    int tid = threadIdx.x;
    int e = tid & 31, dq = tid >> 5;
    int d_l = tid & 31, r_l = tid >> 5;
    __shared__ float Ks[16][32], Vs[16][32];
    float acc[4] = {0.f, 0.f, 0.f, 0.f};
    float ks = 0.f;
    const size_t base = ((size_t)b * 4096 + chunk * 128) * 256 + h * 32;

    for (int s0 = 0; s0 < 128; s0 += 16) {
        Ks[r_l][d_l]     = Km[base + (size_t)(s0 + r_l) * 256 + d_l];
        Ks[r_l + 8][d_l] = Km[base + (size_t)(s0 + r_l + 8) * 256 + d_l];
        Vs[r_l][d_l]     = Vm[base + (size_t)(s0 + r_l) * 256 + d_l];
        Vs[r_l + 8][d_l] = Vm[base + (size_t)(s0 + r_l + 8) * 256 + d_l];
        __syncthreads();
        #pragma unroll
        for (int sr = 0; sr < 16; sr++) {
            float vv = Vs[sr][e];
            #pragma unroll
            for (int i = 0; i < 4; i++)
                acc[i] = fmaf(Ks[sr][dq * 4 + i], vv, acc[i]);
        }
        if (tid < 32) {
            #pragma unroll
            for (int sr = 0; sr < 16; sr++) ks += Ks[sr][tid];
        }
        __syncthreads();
    }
    #pragma unroll
    for (int i = 0; i < 4; i++)
        pKV[(size_t)blk * 1024 + (dq * 4 + i) * 32 + e] = acc[i];
    if (tid < 32) pKs[blk * 32 + tid] = ks;
}

// reduce 32 chunks -> KV[bh][1024], Ksum[bh][32]
__global__ __launch_bounds__(256) void kv_reduce(
    const float* __restrict__ pKV, const float* __restrict__ pKs,
    float* __restrict__ KV, float* __restrict__ Ksum)
{
    int bh = blockIdx.x;
    int tid = threadIdx.x;
    float s0 = 0.f, s1 = 0.f, s2 = 0.f, s3 = 0.f;
    for (int c = 0; c < 32; c++) {
        const float* p = &pKV[(size_t)(bh * 32 + c) * 1024];
        s0 += p[tid]; s1 += p[tid + 256]; s2 += p[tid + 512]; s3 += p[tid + 768];
    }
    KV[bh * 1024 + tid]       = s0;
    KV[bh * 1024 + tid + 256] = s1;
    KV[bh * 1024 + tid + 512] = s2;
    KV[bh * 1024 + tid + 768] = s3;
    if (tid < 32) {
        float s = 0.f;
        for (int c = 0; c < 32; c++) s += pKs[(bh * 32 + c) * 32 + tid];
        Ksum[bh * 32 + tid] = s;
    }
}

extern "C" void kernel_launch(void* const* d_in, const int* in_sizes, int n_in,
                              void* d_out, int out_size, void* d_ws, size_t ws_size,
                              hipStream_t stream) {
    const float* x      = (const float*)d_in[0];
    const float* sr_w   = (const float*)d_in[1];
    const float* sr_b   = (const float*)d_in[2];
    const float* norm_g = (const float*)d_in[3];
    const float* norm_b = (const float*)d_in[4];
    const float* wq     = (const float*)d_in[5];
    const float* wk     = (const float*)d_in[6];
    const float* wv     = (const float*)d_in[7];
    const float* wm     = (const float*)d_in[8];
    const float* mlp_w1 = (const float*)d_in[9];
    const float* mlp_w2 = (const float*)d_in[10];
    const float* n1_g   = (const float*)d_in[11];
    const float* n1_b   = (const float*)d_in[12];
    const float* n2_g   = (const float*)d_in[13];
    const float* n2_b   = (const float*)d_in[14];
    float* out = (float*)d_out;

    // ---- workspace layout (~120 MB) ----
    float* ws = (float*)d_ws;
    short* Wct = (short*)ws;            // 262144 sh  conv Bt [256][1024]
    short* Wqt = Wct + 262144;          // 65536 sh
    short* Wkt = Wqt + 65536;
    short* Wvt = Wkt + 65536;
    short* W1t = Wvt + 65536;           // 262144 sh  [512][512]
    short* W2t = W1t + 262144;          // 131072 sh  [256][512]
    short* W2a = W2t + 131072;          // 262144 sh  [4][256][256] attn-folded
    float* xs  = ws + 557056;           // 4194304  [16384,256]
    float* Km  = xs  + 4194304;         // 4194304
    float* Vm  = Km  + 4194304;         // 4194304
    float* KVb = Vm  + 4194304;         // 32768
    float* Ksb = KVb + 32768;           // 1024
    float* Qb  = Ksb + 1024;            // 16777216 [65536,256]
    float* pKV = Qb;                    // ALIAS (dead before GEMM6 writes Qb)
    float* pKs = Qb + 1048576;          // ALIAS
    short* Qz  = (short*)xs;            // ALIAS 33.5MB over xs+Km+(Vm head)
    float* Hc  = xs;                    // ALIAS [16384,512] (Qz dead by MLP)
    float* Mb  = out;                   // msg_ln lives in d_out

    const float inv_S = 1.f / 4096.f;

    // weight prep (bf16, Bt form)
    transpose_conv_bf16<<<1024, 256, 0, stream>>>(sr_w, Wct);
    transpose_w_bf16<<<256,  256, 0, stream>>>(wq, Wqt, 256, 256);
    transpose_w_bf16<<<256,  256, 0, stream>>>(wk, Wkt, 256, 256);
    transpose_w_bf16<<<256,  256, 0, stream>>>(wv, Wvt, 256, 256);
    transpose_w_bf16<<<1024, 256, 0, stream>>>(mlp_w1, W1t, 512, 512);
    transpose_w_bf16<<<512,  256, 0, stream>>>(mlp_w2, W2t, 512, 256);

    // conv as GEMM + bias -> xs; LN in place
    gemm_mfma<GA_CONV, EP_BIAS, 0, 0><<<dim3(128, 2), 256, 0, stream>>>(
        x, nullptr, Wct, sr_b, xs, 16384, 256, 1024, 0.f);
    ln_kernel<0><<<16384, 256, 0, stream>>>(xs, norm_g, norm_b, nullptr, xs);

    // K = elu(xs@wk)+1 ; Vsc = (xs@wv)/S
    gemm_mfma<GA_PLAIN, EP_ELU1, 0, 0><<<dim3(128, 2), 256, 0, stream>>>(
        xs, nullptr, Wkt, nullptr, Km, 16384, 256, 256, 0.f);
    gemm_mfma<GA_PLAIN, EP_SCALE, 0, 0><<<dim3(128, 2), 256, 0, stream>>>(
        xs, nullptr, Wvt, nullptr, Vm, 16384, 256, 256, inv_S);

    // KV + Ksum (two-stage), then fold KV@wm -> W2a (per batch)
    kv_partial<<<1024, 256, 0, stream>>>(Km, Vm, pKV, pKs);
    kv_reduce<<<32, 256, 0, stream>>>(pKV, pKs, KVb, Ksb);
    w2_prep<<<1024, 256, 0, stream>>>(KVb, wm, W2a);

    // Qz = Z .* (elu(x@wq)+1)   [bf16]  (xs/Km/Vm dead; Qz aliases them)
    gemm_qz<<<dim3(512, 2), 256, 0, stream>>>(x, Wqt, Ksb, Qz, 65536);

    // msg@wm == Qz @ W2a[batch] -> Qb
    gemm_mfma<GA_PLAIN, EP_NONE, 1, 1><<<dim3(512, 2), 256, 0, stream>>>(
        (const float*)Qz, nullptr, W2a, nullptr, Qb, 65536, 256, 256, 0.f);

    // LN -> Mb (= d_out) holds msg_ln
    ln_kernel<0><<<65536, 256, 0, stream>>>(Qb, n1_g, n1_b, nullptr, Mb);

    // MLP in 4 chunks of 16384 rows (Hc aliases Qz region; Qz dead)
    for (int c = 0; c < 4; c++) {
        size_t r0 = (size_t)c * 16384;
        gemm_mfma<GA_CONCAT, EP_RELU, 0, 0><<<dim3(128, 4), 256, 0, stream>>>(
            x + r0 * 256, Mb + r0 * 256, W1t, nullptr, Hc,
            16384, 512, 512, 0.f);
        gemm_mfma<GA_PLAIN, EP_NONE, 0, 0><<<dim3(128, 2), 256, 0, stream>>>(
            Hc, nullptr, W2t, nullptr, Qb + r0 * 256,
            16384, 256, 512, 0.f);
    }

    // out = LN(Qb) + x
    ln_kernel<1><<<65536, 256, 0, stream>>>(Qb, n2_g, n2_b, x, out);
}

// Round 6
// 305.108 us; speedup vs baseline: 5.1494x; 1.7158x over previous
//
#include <hip/hip_runtime.h>
#include <math.h>

// ---------------------------------------------------------------------------
// GlobalSubSampleAttn round 6:
//  - bf16 everywhere: all GEMM A/B inputs bf16 in memory (epilogues store bf16)
//  - GEMM core: global_load_lds dwordx4 staging (linear LDS dest, pre-swizzled
//    per-lane global src, XOR chunk swizzle c^=(row&7)) + swizzled ds_read_b128
//  - 128x128 tile, BK=64, 4 waves, fp32 accum, 2-barrier K-step (m97 class)
//  - LN: 1 row per wave, shfl-only reduce, vectorized loads
// B=4, N=16384 (128x128), C=256, S=4096 (64x64), NHEAD=8, D=32
// ---------------------------------------------------------------------------

#define EP_NONE  0
#define EP_BIAS  1
#define EP_ELU1  2
#define EP_SCALE 3
#define EP_RELU  4

#define GA_PLAIN  0
#define GA_CONV   1
#define GA_CONCAT 2

typedef __attribute__((ext_vector_type(8))) short short8v;   // 8 bf16
typedef __attribute__((ext_vector_type(4))) float f32x4;

__device__ inline short f2bf(float f) {
    unsigned u = __float_as_uint(f);
    u += 0x7FFFu + ((u >> 16) & 1u);      // round-to-nearest-even
    return (short)(u >> 16);
}
__device__ inline float bf2f(short s) {
    return __uint_as_float(((unsigned)(unsigned short)s) << 16);
}

__device__ inline void gload16(const void* g, void* l) {
    __builtin_amdgcn_global_load_lds(
        (const __attribute__((address_space(1))) void*)g,
        (__attribute__((address_space(3))) void*)l, 16, 0, 0);
}

template<int EPI>
__device__ inline float epilogue(float c, float b, float scale) {
    if (EPI == EP_BIAS)  return c + b;
    if (EPI == EP_ELU1)  return c > 0.f ? c + 1.f : expf(c);   // elu(c)+1
    if (EPI == EP_SCALE) return c * scale;
    if (EPI == EP_RELU)  return fmaxf(c, 0.f);
    return c;
}

// x fp32 -> bf16 (vector)
__global__ __launch_bounds__(256) void cast_bf16(
    const float* __restrict__ in, short* __restrict__ ob, int n4)
{
    int i = blockIdx.x * 256 + threadIdx.x;
    int stride = gridDim.x * 256;
    for (; i < n4; i += stride) {
        float4 v = reinterpret_cast<const float4*>(in)[i];
        short4 s;
        s.x = f2bf(v.x); s.y = f2bf(v.y); s.z = f2bf(v.z); s.w = f2bf(v.w);
        reinterpret_cast<short4*>(ob)[i] = s;
    }
}

// W[K][N] fp32 -> Wt[N][K] bf16
__global__ __launch_bounds__(256) void transpose_w_bf16(
    const float* __restrict__ W, short* __restrict__ Wt, int Kd, int Nd)
{
    int idx = blockIdx.x * 256 + threadIdx.x;
    if (idx >= Kd * Nd) return;
    int n = idx / Kd, k = idx - n * Kd;
    Wt[idx] = f2bf(W[(size_t)k * Nd + n]);
}

// sr_w[o][ci][p] -> Wt[o][k=p*256+ci] bf16  (Bt, K=1024)
__global__ __launch_bounds__(256) void transpose_conv_bf16(
    const float* __restrict__ srw, short* __restrict__ Wt)
{
    int idx = blockIdx.x * 256 + threadIdx.x;   // 262144
    int o = idx >> 10, k = idx & 1023;
    int p = k >> 8, ci = k & 255;
    Wt[idx] = f2bf(srw[(o << 10) + (ci << 2) + p]);
}

// W2a[b][n][k=h*32+d] = sum_v KV[b,h,d,v] * wm[h*32+v, n]   (bf16 Bt form)
__global__ __launch_bounds__(256) void w2_prep(
    const float* __restrict__ KVb, const float* __restrict__ wm,
    short* __restrict__ W2a)
{
    int b = blockIdx.x >> 8, n = blockIdx.x & 255;
    int tid = threadIdx.x;                 // = k
    __shared__ float wcol[256];
    wcol[tid] = wm[tid * 256 + n];
    __syncthreads();
    int h = tid >> 5, d = tid & 31;
    const float* kv = &KVb[b * 8192 + h * 1024 + d * 32];
    float s = 0.f;
    #pragma unroll
    for (int v = 0; v < 32; v++) s = fmaf(kv[v], wcol[h * 32 + v], s);
    W2a[((size_t)(b * 256 + n) << 8) + tid] = f2bf(s);
}

// ---------------------------------------------------------------------------
// Staged bf16 GEMM core: acc[4][4] += A[128,K-tile] @ B[128,K-tile]^T
// LDS tiles [128 rows][64 k] bf16 = 16KB each, flat; 16B chunk c at row r
// holds global chunk c^(r&7) (inverse-swizzled src; same XOR on ds_read).
// ---------------------------------------------------------------------------
template<int GATHER, int BB>
__device__ inline void gemm_core(
    const short* __restrict__ Ab, const short* __restrict__ A2b,
    const short* __restrict__ Bt, int K, int bm, int bn,
    short* AlF, short* BlF, f32x4 acc[4][4])
{
    const int tid  = threadIdx.x;
    const int lane = tid & 63;
    const int wave = tid >> 6;
    const int wr   = (wave >> 1) * 64;
    const int wc   = (wave & 1) * 64;
    const int l15  = lane & 15;
    const int kg   = lane >> 4;
    const int srow = tid >> 3;        // staging row 0..31 (+q*32)
    const int sc   = tid & 7;         // staging chunk 0..7

    if (BB) Bt += (size_t)(bm >> 14) << 16;   // per-batch 256x256 B block

    for (int k0 = 0; k0 < K; k0 += 64) {
        __syncthreads();              // prior ds_reads done before DMA overwrite
        #pragma unroll
        for (int q = 0; q < 4; q++) {
            int row = q * 32 + srow;
            int cp  = sc ^ (row & 7);
            const short* ga;
            if (GATHER == GA_PLAIN) {
                ga = Ab + (size_t)(bm + row) * K + k0 + cp * 8;
            } else if (GATHER == GA_CONCAT) {
                const short* base = (k0 < 256) ? Ab : A2b;
                ga = base + ((size_t)(bm + row) << 8) + (k0 & 255) + cp * 8;
            } else { // GA_CONV: out-pixel -> in-pixel for tap p = k0>>8
                int grow = bm + row;
                int b = grow >> 12, s = grow & 4095;
                int ii = s >> 6, jj = s & 63;
                int p = k0 >> 8;
                int kh = p >> 1, kw = p & 1;
                int pix = (b << 14) + ((2 * ii + kh) << 7) + (2 * jj + kw);
                ga = Ab + ((size_t)pix << 8) + (k0 & 255) + cp * 8;
            }
            gload16(ga, &AlF[(q * 256 + wave * 64) * 8]);
            const short* gb = Bt + (size_t)(bn + row) * K + k0 + cp * 8;
            gload16(gb, &BlF[(q * 256 + wave * 64) * 8]);
        }
        __syncthreads();              // compiler drains vmcnt before barrier

        #pragma unroll
        for (int ks = 0; ks < 2; ks++) {
            short8v afr[4], bfr[4];
            #pragma unroll
            for (int m = 0; m < 4; m++) {
                int R = wr + m * 16 + l15;
                afr[m] = *reinterpret_cast<const short8v*>(
                    &AlF[R * 64 + (((ks * 4 + kg) ^ (R & 7)) * 8)]);
            }
            #pragma unroll
            for (int n = 0; n < 4; n++) {
                int R = wc + n * 16 + l15;
                bfr[n] = *reinterpret_cast<const short8v*>(
                    &BlF[R * 64 + (((ks * 4 + kg) ^ (R & 7)) * 8)]);
            }
            #pragma unroll
            for (int m = 0; m < 4; m++)
                #pragma unroll
                for (int n = 0; n < 4; n++)
                    acc[m][n] = __builtin_amdgcn_mfma_f32_16x16x32_bf16(
                        afr[m], bfr[n], acc[m][n], 0, 0, 0);
        }
    }
}

// generic GEMM wrapper, bf16 output
template<int GATHER, int EPI, int BB>
__global__ __launch_bounds__(256) void gemm_bf16(
    const short* __restrict__ Ab, const short* __restrict__ A2b,
    const short* __restrict__ Bt, const float* __restrict__ bias,
    short* __restrict__ Cb, int N, int K, float scale)
{
    __shared__ short AlF[8192];
    __shared__ short BlF[8192];
    const int bm = blockIdx.x * 128;
    const int bn = blockIdx.y * 128;
    f32x4 acc[4][4];
    #pragma unroll
    for (int m = 0; m < 4; m++)
        #pragma unroll
        for (int n = 0; n < 4; n++)
            acc[m][n] = (f32x4){0.f, 0.f, 0.f, 0.f};

    gemm_core<GATHER, BB>(Ab, A2b, Bt, K, bm, bn, AlF, BlF, acc);

    const int lane = threadIdx.x & 63;
    const int wave = threadIdx.x >> 6;
    const int wr = (wave >> 1) * 64, wc = (wave & 1) * 64;
    const int l15 = lane & 15, r0 = (lane >> 4) * 4;
    #pragma unroll
    for (int n = 0; n < 4; n++) {
        int col = bn + wc + n * 16 + l15;
        float bb = (EPI == EP_BIAS) ? bias[col] : 0.f;
        #pragma unroll
        for (int m = 0; m < 4; m++) {
            int rowb = bm + wr + m * 16 + r0;
            #pragma unroll
            for (int j = 0; j < 4; j++)
                Cb[(size_t)(rowb + j) * N + col] =
                    f2bf(epilogue<EPI>(acc[m][n][j], bb, scale));
        }
    }
}

// Q GEMM with fused attention-Z epilogue -> Qz bf16
__global__ __launch_bounds__(256) void gemm_qz(
    const short* __restrict__ Ab, const short* __restrict__ Bt,
    const float* __restrict__ Ksb, short* __restrict__ Qz)
{
    __shared__ short AlF[8192];
    __shared__ short BlF[8192];
    const int bm = blockIdx.x * 128;
    const int bn = blockIdx.y * 128;
    f32x4 acc[4][4];
    #pragma unroll
    for (int m = 0; m < 4; m++)
        #pragma unroll
        for (int n = 0; n < 4; n++)
            acc[m][n] = (f32x4){0.f, 0.f, 0.f, 0.f};

    gemm_core<GA_PLAIN, 0>(Ab, nullptr, Bt, 256, bm, bn, AlF, BlF, acc);

    const int lane = threadIdx.x & 63;
    const int wave = threadIdx.x >> 6;
    const int wr = (wave >> 1) * 64, wc = (wave & 1) * 64;
    const int l15 = lane & 15;
    const int b = bm >> 14;                    // batch
    float Ksf[4];
    #pragma unroll
    for (int n = 0; n < 4; n++)
        Ksf[n] = Ksb[b * 256 + bn + wc + n * 16 + l15];
    #pragma unroll
    for (int m = 0; m < 4; m++)
        #pragma unroll
        for (int n = 0; n < 4; n++)
            #pragma unroll
            for (int j = 0; j < 4; j++) {
                float c = acc[m][n][j];
                acc[m][n][j] = c > 0.f ? c + 1.f : expf(c);   // elu+1
            }
    #pragma unroll
    for (int hh = 0; hh < 2; hh++) {
        #pragma unroll
        for (int m = 0; m < 4; m++)
            #pragma unroll
            for (int j = 0; j < 4; j++) {
                float part = acc[m][2 * hh][j] * Ksf[2 * hh]
                           + acc[m][2 * hh + 1][j] * Ksf[2 * hh + 1];
                part += __shfl_xor(part, 1, 64);
                part += __shfl_xor(part, 2, 64);
                part += __shfl_xor(part, 4, 64);
                part += __shfl_xor(part, 8, 64);
                float z = 4096.f / (part + 1e-6f);
                acc[m][2 * hh][j]     *= z;
                acc[m][2 * hh + 1][j] *= z;
            }
    }
    const int r0 = (lane >> 4) * 4;
    #pragma unroll
    for (int n = 0; n < 4; n++) {
        int col = bn + wc + n * 16 + l15;
        #pragma unroll
        for (int m = 0; m < 4; m++) {
            int rowb = bm + wr + m * 16 + r0;
            #pragma unroll
            for (int j = 0; j < 4; j++)
                Qz[(size_t)(rowb + j) * 256 + col] = f2bf(acc[m][n][j]);
        }
    }
}

// LayerNorm: 1 row (C=256) per wave, 4 rows/block, shfl-only reduce.
template<int IN16, int OUT16, int RES>
__global__ __launch_bounds__(256) void ln_kernel(
    const void* __restrict__ in, const float* __restrict__ g,
    const float* __restrict__ bta, const float* __restrict__ res,
    void* __restrict__ out)
{
    const int wave = threadIdx.x >> 6, lane = threadIdx.x & 63;
    const size_t row = (size_t)blockIdx.x * 4 + wave;
    float v[4];
    if (IN16) {
        short4 s = reinterpret_cast<const short4*>(in)[row * 64 + lane];
        v[0] = bf2f(s.x); v[1] = bf2f(s.y); v[2] = bf2f(s.z); v[3] = bf2f(s.w);
    } else {
        float4 f = reinterpret_cast<const float4*>(in)[row * 64 + lane];
        v[0] = f.x; v[1] = f.y; v[2] = f.z; v[3] = f.w;
    }
    float s1 = v[0] + v[1] + v[2] + v[3];
    float s2 = v[0]*v[0] + v[1]*v[1] + v[2]*v[2] + v[3]*v[3];
    #pragma unroll
    for (int off = 1; off < 64; off <<= 1) {
        s1 += __shfl_xor(s1, off, 64);
        s2 += __shfl_xor(s2, off, 64);
    }
    float mean = s1 * (1.f / 256.f);
    float var  = s2 * (1.f / 256.f) - mean * mean;
    float inv  = rsqrtf(var + 1e-5f);
    float4 gg = reinterpret_cast<const float4*>(g)[lane];
    float4 bb = reinterpret_cast<const float4*>(bta)[lane];
    float o[4];
    o[0] = (v[0] - mean) * inv * gg.x + bb.x;
    o[1] = (v[1] - mean) * inv * gg.y + bb.y;
    o[2] = (v[2] - mean) * inv * gg.z + bb.z;
    o[3] = (v[3] - mean) * inv * gg.w + bb.w;
    if (RES) {
        float4 r = reinterpret_cast<const float4*>(res)[row * 64 + lane];
        o[0] += r.x; o[1] += r.y; o[2] += r.z; o[3] += r.w;
    }
    if (OUT16) {
        short4 s;
        s.x = f2bf(o[0]); s.y = f2bf(o[1]); s.z = f2bf(o[2]); s.w = f2bf(o[3]);
        reinterpret_cast<short4*>(out)[row * 64 + lane] = s;
    } else {
        float4 f; f.x = o[0]; f.y = o[1]; f.z = o[2]; f.w = o[3];
        reinterpret_cast<float4*>(out)[row * 64 + lane] = f;
    }
}

// partial KV over a 128-row s-chunk (bf16 K/V in); blockIdx.x = bh*32 + chunk
__global__ __launch_bounds__(256) void kv_partial(
    const short* __restrict__ Km, const short* __restrict__ Vm,
    float* __restrict__ pKV, float* __restrict__ pKs)
{
    int blk = blockIdx.x;
    int bh = blk >> 5, chunk = blk & 31;
    int b = bh >> 3, h = bh & 7;
    int tid = threadIdx.x;
    int e = tid & 31, dq = tid >> 5;
    int d_l = tid & 31, r_l = tid >> 5;
    __shared__ float Ks[16][32], Vs[16][32];
    float acc[4] = {0.f, 0.f, 0.f, 0.f};
    float ks = 0.f;
    const size_t base = ((size_t)b * 4096 + chunk * 128) * 256 + h * 32;

    for (int s0 = 0; s0 < 128; s0 += 16) {
        Ks[r_l][d_l]     = bf2f(Km[base + (size_t)(s0 + r_l) * 256 + d_l]);
        Ks[r_l + 8][d_l] = bf2f(Km[base + (size_t)(s0 + r_l + 8) * 256 + d_l]);
        Vs[r_l][d_l]     = bf2f(Vm[base + (size_t)(s0 + r_l) * 256 + d_l]);
        Vs[r_l + 8][d_l] = bf2f(Vm[base + (size_t)(s0 + r_l + 8) * 256 + d_l]);
        __syncthreads();
        #pragma unroll
        for (int sr = 0; sr < 16; sr++) {
            float vv = Vs[sr][e];
            #pragma unroll
            for (int i = 0; i < 4; i++)
                acc[i] = fmaf(Ks[sr][dq * 4 + i], vv, acc[i]);
        }
        if (tid < 32) {
            #pragma unroll
            for (int sr = 0; sr < 16; sr++) ks += Ks[sr][tid];
        }
        __syncthreads();
    }
    #pragma unroll
    for (int i = 0; i < 4; i++)
        pKV[(size_t)blk * 1024 + (dq * 4 + i) * 32 + e] = acc[i];
    if (tid < 32) pKs[blk * 32 + tid] = ks;
}

// reduce 32 chunks -> KV[bh][1024], Ksum[bh][32]
__global__ __launch_bounds__(256) void kv_reduce(
    const float* __restrict__ pKV, const float* __restrict__ pKs,
    float* __restrict__ KV, float* __restrict__ Ksum)
{
    int bh = blockIdx.x;
    int tid = threadIdx.x;
    float s0 = 0.f, s1 = 0.f, s2 = 0.f, s3 = 0.f;
    for (int c = 0; c < 32; c++) {
        const float* p = &pKV[(size_t)(bh * 32 + c) * 1024];
        s0 += p[tid]; s1 += p[tid + 256]; s2 += p[tid + 512]; s3 += p[tid + 768];
    }
    KV[bh * 1024 + tid]       = s0;
    KV[bh * 1024 + tid + 256] = s1;
    KV[bh * 1024 + tid + 512] = s2;
    KV[bh * 1024 + tid + 768] = s3;
    if (tid < 32) {
        float s = 0.f;
        for (int c = 0; c < 32; c++) s += pKs[(bh * 32 + c) * 32 + tid];
        Ksum[bh * 32 + tid] = s;
    }
}

extern "C" void kernel_launch(void* const* d_in, const int* in_sizes, int n_in,
                              void* d_out, int out_size, void* d_ws, size_t ws_size,
                              hipStream_t stream) {
    const float* x      = (const float*)d_in[0];
    const float* sr_w   = (const float*)d_in[1];
    const float* sr_b   = (const float*)d_in[2];
    const float* norm_g = (const float*)d_in[3];
    const float* norm_b = (const float*)d_in[4];
    const float* wq     = (const float*)d_in[5];
    const float* wk     = (const float*)d_in[6];
    const float* wv     = (const float*)d_in[7];
    const float* wm     = (const float*)d_in[8];
    const float* mlp_w1 = (const float*)d_in[9];
    const float* mlp_w2 = (const float*)d_in[10];
    const float* n1_g   = (const float*)d_in[11];
    const float* n1_b   = (const float*)d_in[12];
    const float* n2_g   = (const float*)d_in[13];
    const float* n2_b   = (const float*)d_in[14];
    float* out = (float*)d_out;

    // ---- workspace layout (~103 MB) ----
    short* Wct = (short*)d_ws;          // [256][1024] 512KB
    short* Wqt = Wct + 262144;          // [256][256] 128KB
    short* Wkt = Wqt + 65536;
    short* Wvt = Wkt + 65536;
    short* W1t = Wvt + 65536;           // [512][512] 512KB
    short* W2t = W1t + 262144;          // [256][512] 256KB
    short* W2a = W2t + 131072;          // [4][256][256] 512KB
    float* KVb = (float*)(W2a + 262144);// 32768 f
    float* Ksb = KVb + 32768;           // 1024 f
    float* pKs = Ksb + 1024;            // 32768 f
    float* pKV = pKs + 32768;           // 1048576 f (4MB)
    short* xb16 = (short*)(pKV + 1048576);   // [65536][256] 32MB, live all
    short* Qbb  = xb16 + 16777216;           // [65536][256] 32MB
    short* SCR  = Qbb + 16777216;            // 32MB scratch region:
    short* xs16 = SCR;                  //   [16384][256] 8MB
    short* Km16 = SCR + 4194304;        //   8MB
    short* Vm16 = Km16 + 4194304;       //   8MB (+8MB spare)
    short* Qz   = SCR;                  // ALIAS 32MB (xs16/Km16/Vm16 dead)
    short* Hc   = SCR;                  // ALIAS [16384][512] 16MB (Qz dead)
    short* Mb16 = (short*)d_out;        // ALIAS 32MB in d_out (final LN rewrites)

    const float inv_S = 1.f / 4096.f;

    // prep: cast x, weights -> bf16 Bt form
    cast_bf16<<<2048, 256, 0, stream>>>(x, xb16, 4194304);
    transpose_conv_bf16<<<1024, 256, 0, stream>>>(sr_w, Wct);
    transpose_w_bf16<<<256,  256, 0, stream>>>(wq, Wqt, 256, 256);
    transpose_w_bf16<<<256,  256, 0, stream>>>(wk, Wkt, 256, 256);
    transpose_w_bf16<<<256,  256, 0, stream>>>(wv, Wvt, 256, 256);
    transpose_w_bf16<<<1024, 256, 0, stream>>>(mlp_w1, W1t, 512, 512);
    transpose_w_bf16<<<512,  256, 0, stream>>>(mlp_w2, W2t, 512, 256);

    // conv as GEMM + bias -> xs16 (bf16); LN in place (bf16 in/out)
    gemm_bf16<GA_CONV, EP_BIAS, 0><<<dim3(128, 2), 256, 0, stream>>>(
        xb16, nullptr, Wct, sr_b, xs16, 256, 1024, 0.f);
    ln_kernel<1, 1, 0><<<4096, 256, 0, stream>>>(
        xs16, norm_g, norm_b, nullptr, xs16);

    // K = elu(xs@wk)+1 ; Vsc = (xs@wv)/S   (bf16 out)
    gemm_bf16<GA_PLAIN, EP_ELU1, 0><<<dim3(128, 2), 256, 0, stream>>>(
        xs16, nullptr, Wkt, nullptr, Km16, 256, 256, 0.f);
    gemm_bf16<GA_PLAIN, EP_SCALE, 0><<<dim3(128, 2), 256, 0, stream>>>(
        xs16, nullptr, Wvt, nullptr, Vm16, 256, 256, inv_S);

    // KV + Ksum (two-stage), then fold KV@wm -> W2a
    kv_partial<<<1024, 256, 0, stream>>>(Km16, Vm16, pKV, pKs);
    kv_reduce<<<32, 256, 0, stream>>>(pKV, pKs, KVb, Ksb);
    w2_prep<<<1024, 256, 0, stream>>>(KVb, wm, W2a);

    // Qz = Z .* (elu(x@wq)+1)  [bf16]  (scratch dead -> Qz aliases it)
    gemm_qz<<<dim3(512, 2), 256, 0, stream>>>(xb16, Wqt, Ksb, Qz);

    // msg@wm == Qz @ W2a[batch] -> Qbb (bf16)
    gemm_bf16<GA_PLAIN, EP_NONE, 1><<<dim3(512, 2), 256, 0, stream>>>(
        Qz, nullptr, W2a, nullptr, Qbb, 256, 256, 0.f);

    // LN1 -> Mb16 (bf16, lives in d_out)
    ln_kernel<1, 1, 0><<<16384, 256, 0, stream>>>(
        Qbb, n1_g, n1_b, nullptr, Mb16);

    // MLP in 4 chunks of 16384 rows (Hc bf16 aliases scratch; Qz dead)
    for (int c = 0; c < 4; c++) {
        size_t r0 = (size_t)c * 16384;
        gemm_bf16<GA_CONCAT, EP_RELU, 0><<<dim3(128, 4), 256, 0, stream>>>(
            xb16 + r0 * 256, Mb16 + r0 * 256, W1t, nullptr, Hc, 512, 512, 0.f);
        gemm_bf16<GA_PLAIN, EP_NONE, 0><<<dim3(128, 2), 256, 0, stream>>>(
            Hc, nullptr, W2t, nullptr, Qbb + r0 * 256, 256, 512, 0.f);
    }

    // out = LN2(Qbb) + x  (fp32, fully overwrites d_out incl. Mb16 region)
    ln_kernel<1, 0, 1><<<16384, 256, 0, stream>>>(
        Qbb, n2_g, n2_b, x, out);
}

// Round 8
// 283.927 us; speedup vs baseline: 5.5336x; 1.0746x over previous
//
#include <hip/hip_runtime.h>
#include <math.h>

// ---------------------------------------------------------------------------
// GlobalSubSampleAttn round 7 (resubmit — round-7 bench died on infra):
//  - gemm_ln: BN=256 full-row GEMM with FUSED LayerNorm epilogue
//      FIN=0: QzW2a + LN1 -> msg_ln bf16       (kills ln1 + Qbb bounce)
//      FIN=1: mlp2 + LN2 + residual -> out f32 (kills ln2 + Qbb bounce)
//  - MLP un-chunked (full 64MB Hc; ws_size ~256MiB per harness poison size)
//  - weight prep merged into one kernel
//  - GEMM core unchanged: swizzled global_load_lds, BK=64, 128-row tiles
// B=4, N=16384, C=256, S=4096, NHEAD=8, D=32
// ---------------------------------------------------------------------------

#define EP_NONE  0
#define EP_BIAS  1
#define EP_ELU1  2
#define EP_SCALE 3
#define EP_RELU  4

#define GA_PLAIN  0
#define GA_CONV   1
#define GA_CONCAT 2

typedef __attribute__((ext_vector_type(8))) short short8v;   // 8 bf16
typedef __attribute__((ext_vector_type(4))) float f32x4;

__device__ inline short f2bf(float f) {
    unsigned u = __float_as_uint(f);
    u += 0x7FFFu + ((u >> 16) & 1u);      // round-to-nearest-even
    return (short)(u >> 16);
}
__device__ inline float bf2f(short s) {
    return __uint_as_float(((unsigned)(unsigned short)s) << 16);
}

__device__ inline void gload16(const void* g, void* l) {
    __builtin_amdgcn_global_load_lds(
        (const __attribute__((address_space(1))) void*)g,
        (__attribute__((address_space(3))) void*)l, 16, 0, 0);
}

template<int EPI>
__device__ inline float epilogue(float c, float b, float scale) {
    if (EPI == EP_BIAS)  return c + b;
    if (EPI == EP_ELU1)  return c > 0.f ? c + 1.f : expf(c);   // elu(c)+1
    if (EPI == EP_SCALE) return c * scale;
    if (EPI == EP_RELU)  return fmaxf(c, 0.f);
    return c;
}

// x fp32 -> bf16 (vector)
__global__ __launch_bounds__(256) void cast_bf16(
    const float* __restrict__ in, short* __restrict__ ob, int n4)
{
    int i = blockIdx.x * 256 + threadIdx.x;
    int stride = gridDim.x * 256;
    for (; i < n4; i += stride) {
        float4 v = reinterpret_cast<const float4*>(in)[i];
        short4 s;
        s.x = f2bf(v.x); s.y = f2bf(v.y); s.z = f2bf(v.z); s.w = f2bf(v.w);
        reinterpret_cast<short4*>(ob)[i] = s;
    }
}

// all weight transposes in one launch (3328 blocks)
__global__ __launch_bounds__(256) void prep_weights(
    const float* __restrict__ srw, const float* __restrict__ wq,
    const float* __restrict__ wk,  const float* __restrict__ wv,
    const float* __restrict__ w1,  const float* __restrict__ w2,
    short* __restrict__ Wct, short* __restrict__ Wqt, short* __restrict__ Wkt,
    short* __restrict__ Wvt, short* __restrict__ W1t, short* __restrict__ W2t)
{
    int bid = blockIdx.x, tid = threadIdx.x;
    if (bid < 1024) {                       // conv: [o][k=p*256+ci]
        int idx = bid * 256 + tid;
        int k = idx & 1023, o = idx >> 10;
        int p = k >> 8, ci = k & 255;
        Wct[idx] = f2bf(srw[(o << 10) + (ci << 2) + p]);
    } else if (bid < 1792) {                // wq/wk/wv: [n][k] 256x256
        int which = (bid - 1024) >> 8;
        int idx = ((bid - 1024) & 255) * 256 + tid;
        int n = idx >> 8, k = idx & 255;
        const float* W = which == 0 ? wq : (which == 1 ? wk : wv);
        short* Wt = which == 0 ? Wqt : (which == 1 ? Wkt : Wvt);
        Wt[idx] = f2bf(W[k * 256 + n]);
    } else if (bid < 2816) {                // mlp_w1: [n][k] 512x512
        int idx = (bid - 1792) * 256 + tid;
        int n = idx >> 9, k = idx & 511;
        W1t[idx] = f2bf(w1[k * 512 + n]);
    } else {                                // mlp_w2: [n][k] 256x512
        int idx = (bid - 2816) * 256 + tid;
        int n = idx >> 9, k = idx & 511;
        W2t[idx] = f2bf(w2[k * 256 + n]);
    }
}

// W2a[b][n][k=h*32+d] = sum_v KV[b,h,d,v] * wm[h*32+v, n]   (bf16 Bt form)
__global__ __launch_bounds__(256) void w2_prep(
    const float* __restrict__ KVb, const float* __restrict__ wm,
    short* __restrict__ W2a)
{
    int b = blockIdx.x >> 8, n = blockIdx.x & 255;
    int tid = threadIdx.x;                 // = k
    __shared__ float wcol[256];
    wcol[tid] = wm[tid * 256 + n];
    __syncthreads();
    int h = tid >> 5, d = tid & 31;
    const float* kv = &KVb[b * 8192 + h * 1024 + d * 32];
    float s = 0.f;
    #pragma unroll
    for (int v = 0; v < 32; v++) s = fmaf(kv[v], wcol[h * 32 + v], s);
    W2a[((size_t)(b * 256 + n) << 8) + tid] = f2bf(s);
}

// ---------------------------------------------------------------------------
// 128x128 staged bf16 GEMM core: swizzled gload_lds + ds_read
// ---------------------------------------------------------------------------
template<int GATHER, int BB>
__device__ inline void gemm_core(
    const short* __restrict__ Ab, const short* __restrict__ A2b,
    const short* __restrict__ Bt, int K, int bm, int bn,
    short* AlF, short* BlF, f32x4 acc[4][4])
{
    const int tid  = threadIdx.x;
    const int lane = tid & 63;
    const int wave = tid >> 6;
    const int wr   = (wave >> 1) * 64;
    const int wc   = (wave & 1) * 64;
    const int l15  = lane & 15;
    const int kg   = lane >> 4;
    const int srow = tid >> 3;
    const int sc   = tid & 7;

    if (BB) Bt += (size_t)(bm >> 14) << 16;

    for (int k0 = 0; k0 < K; k0 += 64) {
        __syncthreads();
        #pragma unroll
        for (int q = 0; q < 4; q++) {
            int row = q * 32 + srow;
            int cp  = sc ^ (row & 7);
            const short* ga;
            if (GATHER == GA_PLAIN) {
                ga = Ab + (size_t)(bm + row) * K + k0 + cp * 8;
            } else if (GATHER == GA_CONCAT) {
                const short* base = (k0 < 256) ? Ab : A2b;
                ga = base + ((size_t)(bm + row) << 8) + (k0 & 255) + cp * 8;
            } else { // GA_CONV
                int grow = bm + row;
                int b = grow >> 12, s = grow & 4095;
                int ii = s >> 6, jj = s & 63;
                int p = k0 >> 8;
                int kh = p >> 1, kw = p & 1;
                int pix = (b << 14) + ((2 * ii + kh) << 7) + (2 * jj + kw);
                ga = Ab + ((size_t)pix << 8) + (k0 & 255) + cp * 8;
            }
            gload16(ga, &AlF[(q * 256 + wave * 64) * 8]);
            const short* gb = Bt + (size_t)(bn + row) * K + k0 + cp * 8;
            gload16(gb, &BlF[(q * 256 + wave * 64) * 8]);
        }
        __syncthreads();

        #pragma unroll
        for (int ks = 0; ks < 2; ks++) {
            short8v afr[4], bfr[4];
            #pragma unroll
            for (int m = 0; m < 4; m++) {
                int R = wr + m * 16 + l15;
                afr[m] = *reinterpret_cast<const short8v*>(
                    &AlF[R * 64 + (((ks * 4 + kg) ^ (R & 7)) * 8)]);
            }
            #pragma unroll
            for (int n = 0; n < 4; n++) {
                int R = wc + n * 16 + l15;
                bfr[n] = *reinterpret_cast<const short8v*>(
                    &BlF[R * 64 + (((ks * 4 + kg) ^ (R & 7)) * 8)]);
            }
            #pragma unroll
            for (int m = 0; m < 4; m++)
                #pragma unroll
                for (int n = 0; n < 4; n++)
                    acc[m][n] = __builtin_amdgcn_mfma_f32_16x16x32_bf16(
                        afr[m], bfr[n], acc[m][n], 0, 0, 0);
        }
    }
}

// generic 128x128 GEMM, bf16 output
template<int GATHER, int EPI, int BB>
__global__ __launch_bounds__(256) void gemm_bf16(
    const short* __restrict__ Ab, const short* __restrict__ A2b,
    const short* __restrict__ Bt, const float* __restrict__ bias,
    short* __restrict__ Cb, int N, int K, float scale)
{
    __shared__ short AlF[8192];
    __shared__ short BlF[8192];
    const int bm = blockIdx.x * 128;
    const int bn = blockIdx.y * 128;
    f32x4 acc[4][4];
    #pragma unroll
    for (int m = 0; m < 4; m++)
        #pragma unroll
        for (int n = 0; n < 4; n++)
            acc[m][n] = (f32x4){0.f, 0.f, 0.f, 0.f};

    gemm_core<GATHER, BB>(Ab, A2b, Bt, K, bm, bn, AlF, BlF, acc);

    const int lane = threadIdx.x & 63;
    const int wave = threadIdx.x >> 6;
    const int wr = (wave >> 1) * 64, wc = (wave & 1) * 64;
    const int l15 = lane & 15, r0 = (lane >> 4) * 4;
    #pragma unroll
    for (int n = 0; n < 4; n++) {
        int col = bn + wc + n * 16 + l15;
        float bb = (EPI == EP_BIAS) ? bias[col] : 0.f;
        #pragma unroll
        for (int m = 0; m < 4; m++) {
            int rowb = bm + wr + m * 16 + r0;
            #pragma unroll
            for (int j = 0; j < 4; j++)
                Cb[(size_t)(rowb + j) * N + col] =
                    f2bf(epilogue<EPI>(acc[m][n][j], bb, scale));
        }
    }
}

// ---------------------------------------------------------------------------
// gemm_ln: BM=128, BN=256 (full row) GEMM + fused LayerNorm epilogue.
//   FIN=0: out bf16 = LN(acc)                  (QzW2a -> msg_ln)
//   FIN=1: out f32  = LN(acc) + res            (mlp2  -> final out)
// 4 waves 2x2: each wave 64 rows x 128 cols (acc[4][8]).
// ---------------------------------------------------------------------------
template<int BB, int FIN>
__global__ __launch_bounds__(256) void gemm_ln(
    const short* __restrict__ Ab, const short* __restrict__ Bt,
    const float* __restrict__ g, const float* __restrict__ bv,
    const float* __restrict__ res, void* __restrict__ Co, int K)
{
    __shared__ short Al[8192];      // [128][64]
    __shared__ short Bl[16384];     // [256][64]
    __shared__ float redS[2][128], redQ[2][128];
    const int tid  = threadIdx.x;
    const int lane = tid & 63;
    const int wave = tid >> 6;
    const int wr   = (wave >> 1) * 64;
    const int wcid = wave & 1;
    const int l15  = lane & 15;
    const int kg   = lane >> 4;
    const int srow = tid >> 3;
    const int sc   = tid & 7;
    const int bm   = blockIdx.x * 128;
    const short* Bp = BB ? Bt + ((size_t)(bm >> 14) << 16) : Bt;

    f32x4 acc[4][8];
    #pragma unroll
    for (int m = 0; m < 4; m++)
        #pragma unroll
        for (int n = 0; n < 8; n++)
            acc[m][n] = (f32x4){0.f, 0.f, 0.f, 0.f};

    for (int k0 = 0; k0 < K; k0 += 64) {
        __syncthreads();
        #pragma unroll
        for (int q = 0; q < 4; q++) {
            int row = q * 32 + srow;
            int cp  = sc ^ (row & 7);
            gload16(Ab + (size_t)(bm + row) * K + k0 + cp * 8,
                    &Al[(q * 256 + wave * 64) * 8]);
        }
        #pragma unroll
        for (int q = 0; q < 8; q++) {
            int row = q * 32 + srow;
            int cp  = sc ^ (row & 7);
            gload16(Bp + (size_t)row * K + k0 + cp * 8,
                    &Bl[(q * 256 + wave * 64) * 8]);
        }
        __syncthreads();

        #pragma unroll
        for (int ks = 0; ks < 2; ks++) {
            short8v afr[4], bfr[8];
            #pragma unroll
            for (int m = 0; m < 4; m++) {
                int R = wr + m * 16 + l15;
                afr[m] = *reinterpret_cast<const short8v*>(
                    &Al[R * 64 + (((ks * 4 + kg) ^ (R & 7)) * 8)]);
            }
            #pragma unroll
            for (int n = 0; n < 8; n++) {
                int R = wcid * 128 + n * 16 + l15;
                bfr[n] = *reinterpret_cast<const short8v*>(
                    &Bl[R * 64 + (((ks * 4 + kg) ^ (R & 7)) * 8)]);
            }
            #pragma unroll
            for (int m = 0; m < 4; m++)
                #pragma unroll
                for (int n = 0; n < 8; n++)
                    acc[m][n] = __builtin_amdgcn_mfma_f32_16x16x32_bf16(
                        afr[m], bfr[n], acc[m][n], 0, 0, 0);
        }
    }

    // ---- fused LayerNorm epilogue ----
    #pragma unroll
    for (int m = 0; m < 4; m++)
        #pragma unroll
        for (int j = 0; j < 4; j++) {
            float s1 = 0.f, s2 = 0.f;
            #pragma unroll
            for (int n = 0; n < 8; n++) {
                float v = acc[m][n][j];
                s1 += v; s2 += v * v;
            }
            s1 += __shfl_xor(s1, 1, 64); s2 += __shfl_xor(s2, 1, 64);
            s1 += __shfl_xor(s1, 2, 64); s2 += __shfl_xor(s2, 2, 64);
            s1 += __shfl_xor(s1, 4, 64); s2 += __shfl_xor(s2, 4, 64);
            s1 += __shfl_xor(s1, 8, 64); s2 += __shfl_xor(s2, 8, 64);
            if (l15 == 0) {
                int row = wr + m * 16 + kg * 4 + j;
                redS[wcid][row] = s1;
                redQ[wcid][row] = s2;
            }
        }
    __syncthreads();

    float gc[8], bc[8];
    #pragma unroll
    for (int n = 0; n < 8; n++) {
        int col = wcid * 128 + n * 16 + l15;
        gc[n] = g[col]; bc[n] = bv[col];
    }
    #pragma unroll
    for (int m = 0; m < 4; m++)
        #pragma unroll
        for (int j = 0; j < 4; j++) {
            int row = wr + m * 16 + kg * 4 + j;
            float mean = (redS[0][row] + redS[1][row]) * (1.f / 256.f);
            float var  = (redQ[0][row] + redQ[1][row]) * (1.f / 256.f)
                         - mean * mean;
            float inv  = rsqrtf(var + 1e-5f);
            #pragma unroll
            for (int n = 0; n < 8; n++) {
                int col = wcid * 128 + n * 16 + l15;
                float o = (acc[m][n][j] - mean) * inv * gc[n] + bc[n];
                size_t gi = (size_t)(bm + row) * 256 + col;
                if (FIN) ((float*)Co)[gi] = o + res[gi];
                else     ((short*)Co)[gi] = f2bf(o);
            }
        }
}

// Q GEMM with fused attention-Z epilogue -> Qz bf16  (128x128)
__global__ __launch_bounds__(256) void gemm_qz(
    const short* __restrict__ Ab, const short* __restrict__ Bt,
    const float* __restrict__ Ksb, short* __restrict__ Qz)
{
    __shared__ short AlF[8192];
    __shared__ short BlF[8192];
    const int bm = blockIdx.x * 128;
    const int bn = blockIdx.y * 128;
    f32x4 acc[4][4];
    #pragma unroll
    for (int m = 0; m < 4; m++)
        #pragma unroll
        for (int n = 0; n < 4; n++)
            acc[m][n] = (f32x4){0.f, 0.f, 0.f, 0.f};

    gemm_core<GA_PLAIN, 0>(Ab, nullptr, Bt, 256, bm, bn, AlF, BlF, acc);

    const int lane = threadIdx.x & 63;
    const int wave = threadIdx.x >> 6;
    const int wr = (wave >> 1) * 64, wc = (wave & 1) * 64;
    const int l15 = lane & 15;
    const int b = bm >> 14;
    float Ksf[4];
    #pragma unroll
    for (int n = 0; n < 4; n++)
        Ksf[n] = Ksb[b * 256 + bn + wc + n * 16 + l15];
    #pragma unroll
    for (int m = 0; m < 4; m++)
        #pragma unroll
        for (int n = 0; n < 4; n++)
            #pragma unroll
            for (int j = 0; j < 4; j++) {
                float c = acc[m][n][j];
                acc[m][n][j] = c > 0.f ? c + 1.f : expf(c);   // elu+1
            }
    #pragma unroll
    for (int hh = 0; hh < 2; hh++) {
        #pragma unroll
        for (int m = 0; m < 4; m++)
            #pragma unroll
            for (int j = 0; j < 4; j++) {
                float part = acc[m][2 * hh][j] * Ksf[2 * hh]
                           + acc[m][2 * hh + 1][j] * Ksf[2 * hh + 1];
                part += __shfl_xor(part, 1, 64);
                part += __shfl_xor(part, 2, 64);
                part += __shfl_xor(part, 4, 64);
                part += __shfl_xor(part, 8, 64);
                float z = 4096.f / (part + 1e-6f);
                acc[m][2 * hh][j]     *= z;
                acc[m][2 * hh + 1][j] *= z;
            }
    }
    const int r0 = (lane >> 4) * 4;
    #pragma unroll
    for (int n = 0; n < 4; n++) {
        int col = bn + wc + n * 16 + l15;
        #pragma unroll
        for (int m = 0; m < 4; m++) {
            int rowb = bm + wr + m * 16 + r0;
            #pragma unroll
            for (int j = 0; j < 4; j++)
                Qz[(size_t)(rowb + j) * 256 + col] = f2bf(acc[m][n][j]);
        }
    }
}

// LayerNorm: 1 row (C=256) per wave (bf16 in/out) — used for conv-LN only
__global__ __launch_bounds__(256) void ln_bf16(
    const short* __restrict__ in, const float* __restrict__ g,
    const float* __restrict__ bta, short* __restrict__ out)
{
    const int wave = threadIdx.x >> 6, lane = threadIdx.x & 63;
    const size_t row = (size_t)blockIdx.x * 4 + wave;
    short4 s = reinterpret_cast<const short4*>(in)[row * 64 + lane];
    float v[4] = {bf2f(s.x), bf2f(s.y), bf2f(s.z), bf2f(s.w)};
    float s1 = v[0] + v[1] + v[2] + v[3];
    float s2 = v[0]*v[0] + v[1]*v[1] + v[2]*v[2] + v[3]*v[3];
    #pragma unroll
    for (int off = 1; off < 64; off <<= 1) {
        s1 += __shfl_xor(s1, off, 64);
        s2 += __shfl_xor(s2, off, 64);
    }
    float mean = s1 * (1.f / 256.f);
    float var  = s2 * (1.f / 256.f) - mean * mean;
    float inv  = rsqrtf(var + 1e-5f);
    float4 gg = reinterpret_cast<const float4*>(g)[lane];
    float4 bb = reinterpret_cast<const float4*>(bta)[lane];
    short4 o;
    o.x = f2bf((v[0] - mean) * inv * gg.x + bb.x);
    o.y = f2bf((v[1] - mean) * inv * gg.y + bb.y);
    o.z = f2bf((v[2] - mean) * inv * gg.z + bb.z);
    o.w = f2bf((v[3] - mean) * inv * gg.w + bb.w);
    reinterpret_cast<short4*>(out)[row * 64 + lane] = o;
}

// partial KV over a 128-row s-chunk (bf16 K/V in)
__global__ __launch_bounds__(256) void kv_partial(
    const short* __restrict__ Km, const short* __restrict__ Vm,
    float* __restrict__ pKV, float* __restrict__ pKs)
{
    int blk = blockIdx.x;
    int bh = blk >> 5, chunk = blk & 31;
    int b = bh >> 3, h = bh & 7;
    int tid = threadIdx.x;
    int e = tid & 31, dq = tid >> 5;
    int d_l = tid & 31, r_l = tid >> 5;
    __shared__ float Ks[16][32], Vs[16][32];
    float acc[4] = {0.f, 0.f, 0.f, 0.f};
    float ks = 0.f;
    const size_t base = ((size_t)b * 4096 + chunk * 128) * 256 + h * 32;

    for (int s0 = 0; s0 < 128; s0 += 16) {
        Ks[r_l][d_l]     = bf2f(Km[base + (size_t)(s0 + r_l) * 256 + d_l]);
        Ks[r_l + 8][d_l] = bf2f(Km[base + (size_t)(s0 + r_l + 8) * 256 + d_l]);
        Vs[r_l][d_l]     = bf2f(Vm[base + (size_t)(s0 + r_l) * 256 + d_l]);
        Vs[r_l + 8][d_l] = bf2f(Vm[base + (size_t)(s0 + r_l + 8) * 256 + d_l]);
        __syncthreads();
        #pragma unroll
        for (int sr = 0; sr < 16; sr++) {
            float vv = Vs[sr][e];
            #pragma unroll
            for (int i = 0; i < 4; i++)
                acc[i] = fmaf(Ks[sr][dq * 4 + i], vv, acc[i]);
        }
        if (tid < 32) {
            #pragma unroll
            for (int sr = 0; sr < 16; sr++) ks += Ks[sr][tid];
        }
        __syncthreads();
    }
    #pragma unroll
    for (int i = 0; i < 4; i++)
        pKV[(size_t)blk * 1024 + (dq * 4 + i) * 32 + e] = acc[i];
    if (tid < 32) pKs[blk * 32 + tid] = ks;
}

// reduce 32 chunks -> KV[bh][1024], Ksum[bh][32]
__global__ __launch_bounds__(256) void kv_reduce(
    const float* __restrict__ pKV, const float* __restrict__ pKs,
    float* __restrict__ KV, float* __restrict__ Ksum)
{
    int bh = blockIdx.x;
    int tid = threadIdx.x;
    float s0 = 0.f, s1 = 0.f, s2 = 0.f, s3 = 0.f;
    for (int c = 0; c < 32; c++) {
        const float* p = &pKV[(size_t)(bh * 32 + c) * 1024];
        s0 += p[tid]; s1 += p[tid + 256]; s2 += p[tid + 512]; s3 += p[tid + 768];
    }
    KV[bh * 1024 + tid]       = s0;
    KV[bh * 1024 + tid + 256] = s1;
    KV[bh * 1024 + tid + 512] = s2;
    KV[bh * 1024 + tid + 768] = s3;
    if (tid < 32) {
        float s = 0.f;
        for (int c = 0; c < 32; c++) s += pKs[(bh * 32 + c) * 32 + tid];
        Ksum[bh * 32 + tid] = s;
    }
}

extern "C" void kernel_launch(void* const* d_in, const int* in_sizes, int n_in,
                              void* d_out, int out_size, void* d_ws, size_t ws_size,
                              hipStream_t stream) {
    const float* x      = (const float*)d_in[0];
    const float* sr_w   = (const float*)d_in[1];
    const float* sr_b   = (const float*)d_in[2];
    const float* norm_g = (const float*)d_in[3];
    const float* norm_b = (const float*)d_in[4];
    const float* wq     = (const float*)d_in[5];
    const float* wk     = (const float*)d_in[6];
    const float* wv     = (const float*)d_in[7];
    const float* wm     = (const float*)d_in[8];
    const float* mlp_w1 = (const float*)d_in[9];
    const float* mlp_w2 = (const float*)d_in[10];
    const float* n1_g   = (const float*)d_in[11];
    const float* n1_b   = (const float*)d_in[12];
    const float* n2_g   = (const float*)d_in[13];
    const float* n2_b   = (const float*)d_in[14];
    float* out = (float*)d_out;

    // ---- workspace layout (~141 MB of ~256 MiB) ----
    short* Wct = (short*)d_ws;          // [256][1024]
    short* Wqt = Wct + 262144;          // [256][256]
    short* Wkt = Wqt + 65536;
    short* Wvt = Wkt + 65536;
    short* W1t = Wvt + 65536;           // [512][512]
    short* W2t = W1t + 262144;          // [256][512]
    short* W2a = W2t + 131072;          // [4][256][256]
    float* KVb = (float*)(W2a + 262144);// 32768 f
    float* Ksb = KVb + 32768;           // 1024 f
    float* pKs = Ksb + 1024;            // 32768 f
    float* pKV = pKs + 32768;           // 1048576 f
    short* xb16 = (short*)(pKV + 1048576);   // [65536][256] 32MB
    short* SCR  = xb16 + 16777216;           // 32MB scratch:
    short* xs16 = SCR;                  //   [16384][256] 8MB
    short* Km16 = SCR + 4194304;        //   8MB
    short* Vm16 = Km16 + 4194304;       //   8MB
    short* Qz   = SCR;                  // ALIAS 32MB (xs/Km/Vm dead)
    short* Hc   = SCR + 16777216;       // [65536][512] 64MB
    short* Mb16 = (short*)d_out;        // msg_ln bf16 in d_out (overwritten)

    const float inv_S = 1.f / 4096.f;

    // prep: weights + x cast
    prep_weights<<<3328, 256, 0, stream>>>(
        sr_w, wq, wk, wv, mlp_w1, mlp_w2, Wct, Wqt, Wkt, Wvt, W1t, W2t);
    cast_bf16<<<2048, 256, 0, stream>>>(x, xb16, 4194304);

    // conv as GEMM + bias -> xs16; LN in place
    gemm_bf16<GA_CONV, EP_BIAS, 0><<<dim3(128, 2), 256, 0, stream>>>(
        xb16, nullptr, Wct, sr_b, xs16, 256, 1024, 0.f);
    ln_bf16<<<4096, 256, 0, stream>>>(xs16, norm_g, norm_b, xs16);

    // K = elu(xs@wk)+1 ; Vsc = (xs@wv)/S
    gemm_bf16<GA_PLAIN, EP_ELU1, 0><<<dim3(128, 2), 256, 0, stream>>>(
        xs16, nullptr, Wkt, nullptr, Km16, 256, 256, 0.f);
    gemm_bf16<GA_PLAIN, EP_SCALE, 0><<<dim3(128, 2), 256, 0, stream>>>(
        xs16, nullptr, Wvt, nullptr, Vm16, 256, 256, inv_S);

    // KV + Ksum, fold KV@wm -> W2a
    kv_partial<<<1024, 256, 0, stream>>>(Km16, Vm16, pKV, pKs);
    kv_reduce<<<32, 256, 0, stream>>>(pKV, pKs, KVb, Ksb);
    w2_prep<<<1024, 256, 0, stream>>>(KVb, wm, W2a);

    // Qz = Z .* (elu(x@wq)+1)  [bf16] (aliases dead xs/Km/Vm)
    gemm_qz<<<dim3(512, 2), 256, 0, stream>>>(xb16, Wqt, Ksb, Qz);

    // msg_ln = LN1(Qz @ W2a[b]) -> Mb16 (bf16, in d_out)  [fused]
    gemm_ln<1, 0><<<512, 256, 0, stream>>>(
        Qz, W2a, n1_g, n1_b, nullptr, Mb16, 256);

    // h = relu([x|msg_ln] @ w1) -> Hc (single launch)
    gemm_bf16<GA_CONCAT, EP_RELU, 0><<<dim3(512, 4), 256, 0, stream>>>(
        xb16, Mb16, W1t, nullptr, Hc, 512, 512, 0.f);

    // out = LN2(h @ w2) + x  (fused, fp32, overwrites all of d_out)
    gemm_ln<0, 1><<<512, 256, 0, stream>>>(
        Hc, W2t, n2_g, n2_b, x, out, 512);
}

// Round 9
// 266.347 us; speedup vs baseline: 5.8989x; 1.0660x over previous
//
#include <hip/hip_runtime.h>
#include <math.h>

// ---------------------------------------------------------------------------
// GlobalSubSampleAttn round 9:
//  - gemm_ln RESTRUCTURED for occupancy: BM=64 (was 128), 4 waves each
//    owning 64 cols x 64 rows -> acc[4][4] (64 VGPR vs 128), LDS 42KB,
//    grid 1024 blocks (was 512).  Was: 176 VGPR / 50KB -> 2 blocks/CU,
//    MfmaUtil 9.5%.  Target: ~4 waves/SIMD, 3 blocks/CU.
//  - everything else unchanged from round 8 (284 us)
// B=4, N=16384, C=256, S=4096, NHEAD=8, D=32
// ---------------------------------------------------------------------------

#define EP_NONE  0
#define EP_BIAS  1
#define EP_ELU1  2
#define EP_SCALE 3
#define EP_RELU  4

#define GA_PLAIN  0
#define GA_CONV   1
#define GA_CONCAT 2

typedef __attribute__((ext_vector_type(8))) short short8v;   // 8 bf16
typedef __attribute__((ext_vector_type(4))) float f32x4;

__device__ inline short f2bf(float f) {
    unsigned u = __float_as_uint(f);
    u += 0x7FFFu + ((u >> 16) & 1u);      // round-to-nearest-even
    return (short)(u >> 16);
}
__device__ inline float bf2f(short s) {
    return __uint_as_float(((unsigned)(unsigned short)s) << 16);
}

__device__ inline void gload16(const void* g, void* l) {
    __builtin_amdgcn_global_load_lds(
        (const __attribute__((address_space(1))) void*)g,
        (__attribute__((address_space(3))) void*)l, 16, 0, 0);
}

template<int EPI>
__device__ inline float epilogue(float c, float b, float scale) {
    if (EPI == EP_BIAS)  return c + b;
    if (EPI == EP_ELU1)  return c > 0.f ? c + 1.f : expf(c);   // elu(c)+1
    if (EPI == EP_SCALE) return c * scale;
    if (EPI == EP_RELU)  return fmaxf(c, 0.f);
    return c;
}

// x fp32 -> bf16 (vector)
__global__ __launch_bounds__(256) void cast_bf16(
    const float* __restrict__ in, short* __restrict__ ob, int n4)
{
    int i = blockIdx.x * 256 + threadIdx.x;
    int stride = gridDim.x * 256;
    for (; i < n4; i += stride) {
        float4 v = reinterpret_cast<const float4*>(in)[i];
        short4 s;
        s.x = f2bf(v.x); s.y = f2bf(v.y); s.z = f2bf(v.z); s.w = f2bf(v.w);
        reinterpret_cast<short4*>(ob)[i] = s;
    }
}

// all weight transposes in one launch (3328 blocks)
__global__ __launch_bounds__(256) void prep_weights(
    const float* __restrict__ srw, const float* __restrict__ wq,
    const float* __restrict__ wk,  const float* __restrict__ wv,
    const float* __restrict__ w1,  const float* __restrict__ w2,
    short* __restrict__ Wct, short* __restrict__ Wqt, short* __restrict__ Wkt,
    short* __restrict__ Wvt, short* __restrict__ W1t, short* __restrict__ W2t)
{
    int bid = blockIdx.x, tid = threadIdx.x;
    if (bid < 1024) {                       // conv: [o][k=p*256+ci]
        int idx = bid * 256 + tid;
        int k = idx & 1023, o = idx >> 10;
        int p = k >> 8, ci = k & 255;
        Wct[idx] = f2bf(srw[(o << 10) + (ci << 2) + p]);
    } else if (bid < 1792) {                // wq/wk/wv: [n][k] 256x256
        int which = (bid - 1024) >> 8;
        int idx = ((bid - 1024) & 255) * 256 + tid;
        int n = idx >> 8, k = idx & 255;
        const float* W = which == 0 ? wq : (which == 1 ? wk : wv);
        short* Wt = which == 0 ? Wqt : (which == 1 ? Wkt : Wvt);
        Wt[idx] = f2bf(W[k * 256 + n]);
    } else if (bid < 2816) {                // mlp_w1: [n][k] 512x512
        int idx = (bid - 1792) * 256 + tid;
        int n = idx >> 9, k = idx & 511;
        W1t[idx] = f2bf(w1[k * 512 + n]);
    } else {                                // mlp_w2: [n][k] 256x512
        int idx = (bid - 2816) * 256 + tid;
        int n = idx >> 9, k = idx & 511;
        W2t[idx] = f2bf(w2[k * 256 + n]);
    }
}

// W2a[b][n][k=h*32+d] = sum_v KV[b,h,d,v] * wm[h*32+v, n]   (bf16 Bt form)
__global__ __launch_bounds__(256) void w2_prep(
    const float* __restrict__ KVb, const float* __restrict__ wm,
    short* __restrict__ W2a)
{
    int b = blockIdx.x >> 8, n = blockIdx.x & 255;
    int tid = threadIdx.x;                 // = k
    __shared__ float wcol[256];
    wcol[tid] = wm[tid * 256 + n];
    __syncthreads();
    int h = tid >> 5, d = tid & 31;
    const float* kv = &KVb[b * 8192 + h * 1024 + d * 32];
    float s = 0.f;
    #pragma unroll
    for (int v = 0; v < 32; v++) s = fmaf(kv[v], wcol[h * 32 + v], s);
    W2a[((size_t)(b * 256 + n) << 8) + tid] = f2bf(s);
}

// ---------------------------------------------------------------------------
// 128x128 staged bf16 GEMM core: swizzled gload_lds + ds_read
// ---------------------------------------------------------------------------
template<int GATHER, int BB>
__device__ inline void gemm_core(
    const short* __restrict__ Ab, const short* __restrict__ A2b,
    const short* __restrict__ Bt, int K, int bm, int bn,
    short* AlF, short* BlF, f32x4 acc[4][4])
{
    const int tid  = threadIdx.x;
    const int lane = tid & 63;
    const int wave = tid >> 6;
    const int wr   = (wave >> 1) * 64;
    const int wc   = (wave & 1) * 64;
    const int l15  = lane & 15;
    const int kg   = lane >> 4;
    const int srow = tid >> 3;
    const int sc   = tid & 7;

    if (BB) Bt += (size_t)(bm >> 14) << 16;

    for (int k0 = 0; k0 < K; k0 += 64) {
        __syncthreads();
        #pragma unroll
        for (int q = 0; q < 4; q++) {
            int row = q * 32 + srow;
            int cp  = sc ^ (row & 7);
            const short* ga;
            if (GATHER == GA_PLAIN) {
                ga = Ab + (size_t)(bm + row) * K + k0 + cp * 8;
            } else if (GATHER == GA_CONCAT) {
                const short* base = (k0 < 256) ? Ab : A2b;
                ga = base + ((size_t)(bm + row) << 8) + (k0 & 255) + cp * 8;
            } else { // GA_CONV
                int grow = bm + row;
                int b = grow >> 12, s = grow & 4095;
                int ii = s >> 6, jj = s & 63;
                int p = k0 >> 8;
                int kh = p >> 1, kw = p & 1;
                int pix = (b << 14) + ((2 * ii + kh) << 7) + (2 * jj + kw);
                ga = Ab + ((size_t)pix << 8) + (k0 & 255) + cp * 8;
            }
            gload16(ga, &AlF[(q * 256 + wave * 64) * 8]);
            const short* gb = Bt + (size_t)(bn + row) * K + k0 + cp * 8;
            gload16(gb, &BlF[(q * 256 + wave * 64) * 8]);
        }
        __syncthreads();

        #pragma unroll
        for (int ks = 0; ks < 2; ks++) {
            short8v afr[4], bfr[4];
            #pragma unroll
            for (int m = 0; m < 4; m++) {
                int R = wr + m * 16 + l15;
                afr[m] = *reinterpret_cast<const short8v*>(
                    &AlF[R * 64 + (((ks * 4 + kg) ^ (R & 7)) * 8)]);
            }
            #pragma unroll
            for (int n = 0; n < 4; n++) {
                int R = wc + n * 16 + l15;
                bfr[n] = *reinterpret_cast<const short8v*>(
                    &BlF[R * 64 + (((ks * 4 + kg) ^ (R & 7)) * 8)]);
            }
            #pragma unroll
            for (int m = 0; m < 4; m++)
                #pragma unroll
                for (int n = 0; n < 4; n++)
                    acc[m][n] = __builtin_amdgcn_mfma_f32_16x16x32_bf16(
                        afr[m], bfr[n], acc[m][n], 0, 0, 0);
        }
    }
}

// generic 128x128 GEMM, bf16 output
template<int GATHER, int EPI, int BB>
__global__ __launch_bounds__(256) void gemm_bf16(
    const short* __restrict__ Ab, const short* __restrict__ A2b,
    const short* __restrict__ Bt, const float* __restrict__ bias,
    short* __restrict__ Cb, int N, int K, float scale)
{
    __shared__ short AlF[8192];
    __shared__ short BlF[8192];
    const int bm = blockIdx.x * 128;
    const int bn = blockIdx.y * 128;
    f32x4 acc[4][4];
    #pragma unroll
    for (int m = 0; m < 4; m++)
        #pragma unroll
        for (int n = 0; n < 4; n++)
            acc[m][n] = (f32x4){0.f, 0.f, 0.f, 0.f};

    gemm_core<GATHER, BB>(Ab, A2b, Bt, K, bm, bn, AlF, BlF, acc);

    const int lane = threadIdx.x & 63;
    const int wave = threadIdx.x >> 6;
    const int wr = (wave >> 1) * 64, wc = (wave & 1) * 64;
    const int l15 = lane & 15, r0 = (lane >> 4) * 4;
    #pragma unroll
    for (int n = 0; n < 4; n++) {
        int col = bn + wc + n * 16 + l15;
        float bb = (EPI == EP_BIAS) ? bias[col] : 0.f;
        #pragma unroll
        for (int m = 0; m < 4; m++) {
            int rowb = bm + wr + m * 16 + r0;
            #pragma unroll
            for (int j = 0; j < 4; j++)
                Cb[(size_t)(rowb + j) * N + col] =
                    f2bf(epilogue<EPI>(acc[m][n][j], bb, scale));
        }
    }
}

// ---------------------------------------------------------------------------
// gemm_ln v2: BM=64, BN=256 (full row) GEMM + fused LayerNorm epilogue.
// 4 waves; wave w owns cols [w*64, w*64+64) of ALL 64 rows -> acc[4][4].
// LDS: Al [64][64] 8KB + Bl [256][64] 32KB + red 2KB = 42KB; grid M/64.
//   FIN=0: out bf16 = LN(acc)            (QzW2a -> msg_ln)
//   FIN=1: out f32  = LN(acc) + res      (mlp2  -> final out)
// ---------------------------------------------------------------------------
template<int BB, int FIN>
__global__ __launch_bounds__(256) void gemm_ln(
    const short* __restrict__ Ab, const short* __restrict__ Bt,
    const float* __restrict__ g, const float* __restrict__ bv,
    const float* __restrict__ res, void* __restrict__ Co, int K)
{
    __shared__ short Al[4096];      // [64][64]
    __shared__ short Bl[16384];     // [256][64]
    __shared__ float redS[4][64], redQ[4][64];
    const int tid  = threadIdx.x;
    const int lane = tid & 63;
    const int wave = tid >> 6;      // col-slice owner
    const int l15  = lane & 15;
    const int kg   = lane >> 4;
    const int srow = tid >> 3;      // 0..31
    const int sc   = tid & 7;
    const int bm   = blockIdx.x * 64;
    const short* Bp = BB ? Bt + ((size_t)(bm >> 14) << 16) : Bt;

    f32x4 acc[4][4];
    #pragma unroll
    for (int m = 0; m < 4; m++)
        #pragma unroll
        for (int n = 0; n < 4; n++)
            acc[m][n] = (f32x4){0.f, 0.f, 0.f, 0.f};

    for (int k0 = 0; k0 < K; k0 += 64) {
        __syncthreads();
        #pragma unroll
        for (int q = 0; q < 2; q++) {       // A: 64 rows
            int row = q * 32 + srow;
            int cp  = sc ^ (row & 7);
            gload16(Ab + (size_t)(bm + row) * K + k0 + cp * 8,
                    &Al[(q * 256 + wave * 64) * 8]);
        }
        #pragma unroll
        for (int q = 0; q < 8; q++) {       // B: 256 rows
            int row = q * 32 + srow;
            int cp  = sc ^ (row & 7);
            gload16(Bp + (size_t)row * K + k0 + cp * 8,
                    &Bl[(q * 256 + wave * 64) * 8]);
        }
        __syncthreads();

        #pragma unroll
        for (int ks = 0; ks < 2; ks++) {
            short8v afr[4], bfr[4];
            #pragma unroll
            for (int m = 0; m < 4; m++) {
                int R = m * 16 + l15;
                afr[m] = *reinterpret_cast<const short8v*>(
                    &Al[R * 64 + (((ks * 4 + kg) ^ (R & 7)) * 8)]);
            }
            #pragma unroll
            for (int n = 0; n < 4; n++) {
                int R = wave * 64 + n * 16 + l15;
                bfr[n] = *reinterpret_cast<const short8v*>(
                    &Bl[R * 64 + (((ks * 4 + kg) ^ (R & 7)) * 8)]);
            }
            #pragma unroll
            for (int m = 0; m < 4; m++)
                #pragma unroll
                for (int n = 0; n < 4; n++)
                    acc[m][n] = __builtin_amdgcn_mfma_f32_16x16x32_bf16(
                        afr[m], bfr[n], acc[m][n], 0, 0, 0);
        }
    }

    // ---- fused LayerNorm epilogue ----
    #pragma unroll
    for (int m = 0; m < 4; m++)
        #pragma unroll
        for (int j = 0; j < 4; j++) {
            float s1 = 0.f, s2 = 0.f;
            #pragma unroll
            for (int n = 0; n < 4; n++) {
                float v = acc[m][n][j];
                s1 += v; s2 += v * v;
            }
            s1 += __shfl_xor(s1, 1, 64); s2 += __shfl_xor(s2, 1, 64);
            s1 += __shfl_xor(s1, 2, 64); s2 += __shfl_xor(s2, 2, 64);
            s1 += __shfl_xor(s1, 4, 64); s2 += __shfl_xor(s2, 4, 64);
            s1 += __shfl_xor(s1, 8, 64); s2 += __shfl_xor(s2, 8, 64);
            if (l15 == 0) {
                int row = m * 16 + kg * 4 + j;
                redS[wave][row] = s1;
                redQ[wave][row] = s2;
            }
        }
    __syncthreads();

    float gc[4], bc[4];
    #pragma unroll
    for (int n = 0; n < 4; n++) {
        int col = wave * 64 + n * 16 + l15;
        gc[n] = g[col]; bc[n] = bv[col];
    }
    #pragma unroll
    for (int m = 0; m < 4; m++)
        #pragma unroll
        for (int j = 0; j < 4; j++) {
            int row = m * 16 + kg * 4 + j;
            float mean = (redS[0][row] + redS[1][row] +
                          redS[2][row] + redS[3][row]) * (1.f / 256.f);
            float var  = (redQ[0][row] + redQ[1][row] +
                          redQ[2][row] + redQ[3][row]) * (1.f / 256.f)
                         - mean * mean;
            float inv  = rsqrtf(var + 1e-5f);
            #pragma unroll
            for (int n = 0; n < 4; n++) {
                int col = wave * 64 + n * 16 + l15;
                float o = (acc[m][n][j] - mean) * inv * gc[n] + bc[n];
                size_t gi = (size_t)(bm + row) * 256 + col;
                if (FIN) ((float*)Co)[gi] = o + res[gi];
                else     ((short*)Co)[gi] = f2bf(o);
            }
        }
}

// Q GEMM with fused attention-Z epilogue -> Qz bf16  (128x128)
__global__ __launch_bounds__(256) void gemm_qz(
    const short* __restrict__ Ab, const short* __restrict__ Bt,
    const float* __restrict__ Ksb, short* __restrict__ Qz)
{
    __shared__ short AlF[8192];
    __shared__ short BlF[8192];
    const int bm = blockIdx.x * 128;
    const int bn = blockIdx.y * 128;
    f32x4 acc[4][4];
    #pragma unroll
    for (int m = 0; m < 4; m++)
        #pragma unroll
        for (int n = 0; n < 4; n++)
            acc[m][n] = (f32x4){0.f, 0.f, 0.f, 0.f};

    gemm_core<GA_PLAIN, 0>(Ab, nullptr, Bt, 256, bm, bn, AlF, BlF, acc);

    const int lane = threadIdx.x & 63;
    const int wave = threadIdx.x >> 6;
    const int wr = (wave >> 1) * 64, wc = (wave & 1) * 64;
    const int l15 = lane & 15;
    const int b = bm >> 14;
    float Ksf[4];
    #pragma unroll
    for (int n = 0; n < 4; n++)
        Ksf[n] = Ksb[b * 256 + bn + wc + n * 16 + l15];
    #pragma unroll
    for (int m = 0; m < 4; m++)
        #pragma unroll
        for (int n = 0; n < 4; n++)
            #pragma unroll
            for (int j = 0; j < 4; j++) {
                float c = acc[m][n][j];
                acc[m][n][j] = c > 0.f ? c + 1.f : expf(c);   // elu+1
            }
    #pragma unroll
    for (int hh = 0; hh < 2; hh++) {
        #pragma unroll
        for (int m = 0; m < 4; m++)
            #pragma unroll
            for (int j = 0; j < 4; j++) {
                float part = acc[m][2 * hh][j] * Ksf[2 * hh]
                           + acc[m][2 * hh + 1][j] * Ksf[2 * hh + 1];
                part += __shfl_xor(part, 1, 64);
                part += __shfl_xor(part, 2, 64);
                part += __shfl_xor(part, 4, 64);
                part += __shfl_xor(part, 8, 64);
                float z = 4096.f / (part + 1e-6f);
                acc[m][2 * hh][j]     *= z;
                acc[m][2 * hh + 1][j] *= z;
            }
    }
    const int r0 = (lane >> 4) * 4;
    #pragma unroll
    for (int n = 0; n < 4; n++) {
        int col = bn + wc + n * 16 + l15;
        #pragma unroll
        for (int m = 0; m < 4; m++) {
            int rowb = bm + wr + m * 16 + r0;
            #pragma unroll
            for (int j = 0; j < 4; j++)
                Qz[(size_t)(rowb + j) * 256 + col] = f2bf(acc[m][n][j]);
        }
    }
}

// LayerNorm: 1 row (C=256) per wave (bf16 in/out) — used for conv-LN only
__global__ __launch_bounds__(256) void ln_bf16(
    const short* __restrict__ in, const float* __restrict__ g,
    const float* __restrict__ bta, short* __restrict__ out)
{
    const int wave = threadIdx.x >> 6, lane = threadIdx.x & 63;
    const size_t row = (size_t)blockIdx.x * 4 + wave;
    short4 s = reinterpret_cast<const short4*>(in)[row * 64 + lane];
    float v[4] = {bf2f(s.x), bf2f(s.y), bf2f(s.z), bf2f(s.w)};
    float s1 = v[0] + v[1] + v[2] + v[3];
    float s2 = v[0]*v[0] + v[1]*v[1] + v[2]*v[2] + v[3]*v[3];
    #pragma unroll
    for (int off = 1; off < 64; off <<= 1) {
        s1 += __shfl_xor(s1, off, 64);
        s2 += __shfl_xor(s2, off, 64);
    }
    float mean = s1 * (1.f / 256.f);
    float var  = s2 * (1.f / 256.f) - mean * mean;
    float inv  = rsqrtf(var + 1e-5f);
    float4 gg = reinterpret_cast<const float4*>(g)[lane];
    float4 bb = reinterpret_cast<const float4*>(bta)[lane];
    short4 o;
    o.x = f2bf((v[0] - mean) * inv * gg.x + bb.x);
    o.y = f2bf((v[1] - mean) * inv * gg.y + bb.y);
    o.z = f2bf((v[2] - mean) * inv * gg.z + bb.z);
    o.w = f2bf((v[3] - mean) * inv * gg.w + bb.w);
    reinterpret_cast<short4*>(out)[row * 64 + lane] = o;
}

// partial KV over a 128-row s-chunk (bf16 K/V in)
__global__ __launch_bounds__(256) void kv_partial(
    const short* __restrict__ Km, const short* __restrict__ Vm,
    float* __restrict__ pKV, float* __restrict__ pKs)
{
    int blk = blockIdx.x;
    int bh = blk >> 5, chunk = blk & 31;
    int b = bh >> 3, h = bh & 7;
    int tid = threadIdx.x;
    int e = tid & 31, dq = tid >> 5;
    int d_l = tid & 31, r_l = tid >> 5;
    __shared__ float Ks[16][32], Vs[16][32];
    float acc[4] = {0.f, 0.f, 0.f, 0.f};
    float ks = 0.f;
    const size_t base = ((size_t)b * 4096 + chunk * 128) * 256 + h * 32;

    for (int s0 = 0; s0 < 128; s0 += 16) {
        Ks[r_l][d_l]     = bf2f(Km[base + (size_t)(s0 + r_l) * 256 + d_l]);
        Ks[r_l + 8][d_l] = bf2f(Km[base + (size_t)(s0 + r_l + 8) * 256 + d_l]);
        Vs[r_l][d_l]     = bf2f(Vm[base + (size_t)(s0 + r_l) * 256 + d_l]);
        Vs[r_l + 8][d_l] = bf2f(Vm[base + (size_t)(s0 + r_l + 8) * 256 + d_l]);
        __syncthreads();
        #pragma unroll
        for (int sr = 0; sr < 16; sr++) {
            float vv = Vs[sr][e];
            #pragma unroll
            for (int i = 0; i < 4; i++)
                acc[i] = fmaf(Ks[sr][dq * 4 + i], vv, acc[i]);
        }
        if (tid < 32) {
            #pragma unroll
            for (int sr = 0; sr < 16; sr++) ks += Ks[sr][tid];
        }
        __syncthreads();
    }
    #pragma unroll
    for (int i = 0; i < 4; i++)
        pKV[(size_t)blk * 1024 + (dq * 4 + i) * 32 + e] = acc[i];
    if (tid < 32) pKs[blk * 32 + tid] = ks;
}

// reduce 32 chunks -> KV[bh][1024], Ksum[bh][32]
__global__ __launch_bounds__(256) void kv_reduce(
    const float* __restrict__ pKV, const float* __restrict__ pKs,
    float* __restrict__ KV, float* __restrict__ Ksum)
{
    int bh = blockIdx.x;
    int tid = threadIdx.x;
    float s0 = 0.f, s1 = 0.f, s2 = 0.f, s3 = 0.f;
    for (int c = 0; c < 32; c++) {
        const float* p = &pKV[(size_t)(bh * 32 + c) * 1024];
        s0 += p[tid]; s1 += p[tid + 256]; s2 += p[tid + 512]; s3 += p[tid + 768];
    }
    KV[bh * 1024 + tid]       = s0;
    KV[bh * 1024 + tid + 256] = s1;
    KV[bh * 1024 + tid + 512] = s2;
    KV[bh * 1024 + tid + 768] = s3;
    if (tid < 32) {
        float s = 0.f;
        for (int c = 0; c < 32; c++) s += pKs[(bh * 32 + c) * 32 + tid];
        Ksum[bh * 32 + tid] = s;
    }
}

extern "C" void kernel_launch(void* const* d_in, const int* in_sizes, int n_in,
                              void* d_out, int out_size, void* d_ws, size_t ws_size,
                              hipStream_t stream) {
    const float* x      = (const float*)d_in[0];
    const float* sr_w   = (const float*)d_in[1];
    const float* sr_b   = (const float*)d_in[2];
    const float* norm_g = (const float*)d_in[3];
    const float* norm_b = (const float*)d_in[4];
    const float* wq     = (const float*)d_in[5];
    const float* wk     = (const float*)d_in[6];
    const float* wv     = (const float*)d_in[7];
    const float* wm     = (const float*)d_in[8];
    const float* mlp_w1 = (const float*)d_in[9];
    const float* mlp_w2 = (const float*)d_in[10];
    const float* n1_g   = (const float*)d_in[11];
    const float* n1_b   = (const float*)d_in[12];
    const float* n2_g   = (const float*)d_in[13];
    const float* n2_b   = (const float*)d_in[14];
    float* out = (float*)d_out;

    // ---- workspace layout (~141 MB of ~256 MiB) ----
    short* Wct = (short*)d_ws;          // [256][1024]
    short* Wqt = Wct + 262144;          // [256][256]
    short* Wkt = Wqt + 65536;
    short* Wvt = Wkt + 65536;
    short* W1t = Wvt + 65536;           // [512][512]
    short* W2t = W1t + 262144;          // [256][512]
    short* W2a = W2t + 131072;          // [4][256][256]
    float* KVb = (float*)(W2a + 262144);// 32768 f
    float* Ksb = KVb + 32768;           // 1024 f
    float* pKs = Ksb + 1024;            // 32768 f
    float* pKV = pKs + 32768;           // 1048576 f
    short* xb16 = (short*)(pKV + 1048576);   // [65536][256] 32MB
    short* SCR  = xb16 + 16777216;           // 32MB scratch:
    short* xs16 = SCR;                  //   [16384][256] 8MB
    short* Km16 = SCR + 4194304;        //   8MB
    short* Vm16 = Km16 + 4194304;       //   8MB
    short* Qz   = SCR;                  // ALIAS 32MB (xs/Km/Vm dead)
    short* Hc   = SCR + 16777216;       // [65536][512] 64MB
    short* Mb16 = (short*)d_out;        // msg_ln bf16 in d_out (overwritten)

    const float inv_S = 1.f / 4096.f;

    // prep: weights + x cast
    prep_weights<<<3328, 256, 0, stream>>>(
        sr_w, wq, wk, wv, mlp_w1, mlp_w2, Wct, Wqt, Wkt, Wvt, W1t, W2t);
    cast_bf16<<<2048, 256, 0, stream>>>(x, xb16, 4194304);

    // conv as GEMM + bias -> xs16; LN in place
    gemm_bf16<GA_CONV, EP_BIAS, 0><<<dim3(128, 2), 256, 0, stream>>>(
        xb16, nullptr, Wct, sr_b, xs16, 256, 1024, 0.f);
    ln_bf16<<<4096, 256, 0, stream>>>(xs16, norm_g, norm_b, xs16);

    // K = elu(xs@wk)+1 ; Vsc = (xs@wv)/S
    gemm_bf16<GA_PLAIN, EP_ELU1, 0><<<dim3(128, 2), 256, 0, stream>>>(
        xs16, nullptr, Wkt, nullptr, Km16, 256, 256, 0.f);
    gemm_bf16<GA_PLAIN, EP_SCALE, 0><<<dim3(128, 2), 256, 0, stream>>>(
        xs16, nullptr, Wvt, nullptr, Vm16, 256, 256, inv_S);

    // KV + Ksum, fold KV@wm -> W2a
    kv_partial<<<1024, 256, 0, stream>>>(Km16, Vm16, pKV, pKs);
    kv_reduce<<<32, 256, 0, stream>>>(pKV, pKs, KVb, Ksb);
    w2_prep<<<1024, 256, 0, stream>>>(KVb, wm, W2a);

    // Qz = Z .* (elu(x@wq)+1)  [bf16] (aliases dead xs/Km/Vm)
    gemm_qz<<<dim3(512, 2), 256, 0, stream>>>(xb16, Wqt, Ksb, Qz);

    // msg_ln = LN1(Qz @ W2a[b]) -> Mb16 (bf16, in d_out)  [fused]
    gemm_ln<1, 0><<<1024, 256, 0, stream>>>(
        Qz, W2a, n1_g, n1_b, nullptr, Mb16, 256);

    // h = relu([x|msg_ln] @ w1) -> Hc (single launch)
    gemm_bf16<GA_CONCAT, EP_RELU, 0><<<dim3(512, 4), 256, 0, stream>>>(
        xb16, Mb16, W1t, nullptr, Hc, 512, 512, 0.f);

    // out = LN2(h @ w2) + x  (fused, fp32, overwrites all of d_out)
    gemm_ln<0, 1><<<1024, 256, 0, stream>>>(
        Hc, W2t, n2_g, n2_b, x, out, 512);
}

// Round 10
// 264.803 us; speedup vs baseline: 5.9332x; 1.0058x over previous
//
#include <hip/hip_runtime.h>
#include <math.h>

// ---------------------------------------------------------------------------
// GlobalSubSampleAttn round 10:
//  - grid-order swap in all 2D GEMMs: bn = blockIdx.x (fastest) so consecutive
//    blocks share the A row-panel (was: rows fastest -> A fetched ~2-4x;
//    mlp1 FETCH 113MB vs ~65 ideal)
//  - gemm_ln<FIN=1> residual read switched to bf16 xb16 (-32MB traffic)
//  - everything else unchanged from round 9 (266 us)
// B=4, N=16384, C=256, S=4096, NHEAD=8, D=32
// ---------------------------------------------------------------------------

#define EP_NONE  0
#define EP_BIAS  1
#define EP_ELU1  2
#define EP_SCALE 3
#define EP_RELU  4

#define GA_PLAIN  0
#define GA_CONV   1
#define GA_CONCAT 2

typedef __attribute__((ext_vector_type(8))) short short8v;   // 8 bf16
typedef __attribute__((ext_vector_type(4))) float f32x4;

__device__ inline short f2bf(float f) {
    unsigned u = __float_as_uint(f);
    u += 0x7FFFu + ((u >> 16) & 1u);      // round-to-nearest-even
    return (short)(u >> 16);
}
__device__ inline float bf2f(short s) {
    return __uint_as_float(((unsigned)(unsigned short)s) << 16);
}

__device__ inline void gload16(const void* g, void* l) {
    __builtin_amdgcn_global_load_lds(
        (const __attribute__((address_space(1))) void*)g,
        (__attribute__((address_space(3))) void*)l, 16, 0, 0);
}

template<int EPI>
__device__ inline float epilogue(float c, float b, float scale) {
    if (EPI == EP_BIAS)  return c + b;
    if (EPI == EP_ELU1)  return c > 0.f ? c + 1.f : expf(c);   // elu(c)+1
    if (EPI == EP_SCALE) return c * scale;
    if (EPI == EP_RELU)  return fmaxf(c, 0.f);
    return c;
}

// x fp32 -> bf16 (vector)
__global__ __launch_bounds__(256) void cast_bf16(
    const float* __restrict__ in, short* __restrict__ ob, int n4)
{
    int i = blockIdx.x * 256 + threadIdx.x;
    int stride = gridDim.x * 256;
    for (; i < n4; i += stride) {
        float4 v = reinterpret_cast<const float4*>(in)[i];
        short4 s;
        s.x = f2bf(v.x); s.y = f2bf(v.y); s.z = f2bf(v.z); s.w = f2bf(v.w);
        reinterpret_cast<short4*>(ob)[i] = s;
    }
}

// all weight transposes in one launch (3328 blocks)
__global__ __launch_bounds__(256) void prep_weights(
    const float* __restrict__ srw, const float* __restrict__ wq,
    const float* __restrict__ wk,  const float* __restrict__ wv,
    const float* __restrict__ w1,  const float* __restrict__ w2,
    short* __restrict__ Wct, short* __restrict__ Wqt, short* __restrict__ Wkt,
    short* __restrict__ Wvt, short* __restrict__ W1t, short* __restrict__ W2t)
{
    int bid = blockIdx.x, tid = threadIdx.x;
    if (bid < 1024) {                       // conv: [o][k=p*256+ci]
        int idx = bid * 256 + tid;
        int k = idx & 1023, o = idx >> 10;
        int p = k >> 8, ci = k & 255;
        Wct[idx] = f2bf(srw[(o << 10) + (ci << 2) + p]);
    } else if (bid < 1792) {                // wq/wk/wv: [n][k] 256x256
        int which = (bid - 1024) >> 8;
        int idx = ((bid - 1024) & 255) * 256 + tid;
        int n = idx >> 8, k = idx & 255;
        const float* W = which == 0 ? wq : (which == 1 ? wk : wv);
        short* Wt = which == 0 ? Wqt : (which == 1 ? Wkt : Wvt);
        Wt[idx] = f2bf(W[k * 256 + n]);
    } else if (bid < 2816) {                // mlp_w1: [n][k] 512x512
        int idx = (bid - 1792) * 256 + tid;
        int n = idx >> 9, k = idx & 511;
        W1t[idx] = f2bf(w1[k * 512 + n]);
    } else {                                // mlp_w2: [n][k] 256x512
        int idx = (bid - 2816) * 256 + tid;
        int n = idx >> 9, k = idx & 511;
        W2t[idx] = f2bf(w2[k * 256 + n]);
    }
}

// W2a[b][n][k=h*32+d] = sum_v KV[b,h,d,v] * wm[h*32+v, n]   (bf16 Bt form)
__global__ __launch_bounds__(256) void w2_prep(
    const float* __restrict__ KVb, const float* __restrict__ wm,
    short* __restrict__ W2a)
{
    int b = blockIdx.x >> 8, n = blockIdx.x & 255;
    int tid = threadIdx.x;                 // = k
    __shared__ float wcol[256];
    wcol[tid] = wm[tid * 256 + n];
    __syncthreads();
    int h = tid >> 5, d = tid & 31;
    const float* kv = &KVb[b * 8192 + h * 1024 + d * 32];
    float s = 0.f;
    #pragma unroll
    for (int v = 0; v < 32; v++) s = fmaf(kv[v], wcol[h * 32 + v], s);
    W2a[((size_t)(b * 256 + n) << 8) + tid] = f2bf(s);
}

// ---------------------------------------------------------------------------
// 128x128 staged bf16 GEMM core: swizzled gload_lds + ds_read
// ---------------------------------------------------------------------------
template<int GATHER, int BB>
__device__ inline void gemm_core(
    const short* __restrict__ Ab, const short* __restrict__ A2b,
    const short* __restrict__ Bt, int K, int bm, int bn,
    short* AlF, short* BlF, f32x4 acc[4][4])
{
    const int tid  = threadIdx.x;
    const int lane = tid & 63;
    const int wave = tid >> 6;
    const int wr   = (wave >> 1) * 64;
    const int wc   = (wave & 1) * 64;
    const int l15  = lane & 15;
    const int kg   = lane >> 4;
    const int srow = tid >> 3;
    const int sc   = tid & 7;

    if (BB) Bt += (size_t)(bm >> 14) << 16;

    for (int k0 = 0; k0 < K; k0 += 64) {
        __syncthreads();
        #pragma unroll
        for (int q = 0; q < 4; q++) {
            int row = q * 32 + srow;
            int cp  = sc ^ (row & 7);
            const short* ga;
            if (GATHER == GA_PLAIN) {
                ga = Ab + (size_t)(bm + row) * K + k0 + cp * 8;
            } else if (GATHER == GA_CONCAT) {
                const short* base = (k0 < 256) ? Ab : A2b;
                ga = base + ((size_t)(bm + row) << 8) + (k0 & 255) + cp * 8;
            } else { // GA_CONV
                int grow = bm + row;
                int b = grow >> 12, s = grow & 4095;
                int ii = s >> 6, jj = s & 63;
                int p = k0 >> 8;
                int kh = p >> 1, kw = p & 1;
                int pix = (b << 14) + ((2 * ii + kh) << 7) + (2 * jj + kw);
                ga = Ab + ((size_t)pix << 8) + (k0 & 255) + cp * 8;
            }
            gload16(ga, &AlF[(q * 256 + wave * 64) * 8]);
            const short* gb = Bt + (size_t)(bn + row) * K + k0 + cp * 8;
            gload16(gb, &BlF[(q * 256 + wave * 64) * 8]);
        }
        __syncthreads();

        #pragma unroll
        for (int ks = 0; ks < 2; ks++) {
            short8v afr[4], bfr[4];
            #pragma unroll
            for (int m = 0; m < 4; m++) {
                int R = wr + m * 16 + l15;
                afr[m] = *reinterpret_cast<const short8v*>(
                    &AlF[R * 64 + (((ks * 4 + kg) ^ (R & 7)) * 8)]);
            }
            #pragma unroll
            for (int n = 0; n < 4; n++) {
                int R = wc + n * 16 + l15;
                bfr[n] = *reinterpret_cast<const short8v*>(
                    &BlF[R * 64 + (((ks * 4 + kg) ^ (R & 7)) * 8)]);
            }
            #pragma unroll
            for (int m = 0; m < 4; m++)
                #pragma unroll
                for (int n = 0; n < 4; n++)
                    acc[m][n] = __builtin_amdgcn_mfma_f32_16x16x32_bf16(
                        afr[m], bfr[n], acc[m][n], 0, 0, 0);
        }
    }
}

// generic 128x128 GEMM, bf16 output.  GRID: x = col tile (fastest), y = row.
template<int GATHER, int EPI, int BB>
__global__ __launch_bounds__(256) void gemm_bf16(
    const short* __restrict__ Ab, const short* __restrict__ A2b,
    const short* __restrict__ Bt, const float* __restrict__ bias,
    short* __restrict__ Cb, int N, int K, float scale)
{
    __shared__ short AlF[8192];
    __shared__ short BlF[8192];
    const int bm = blockIdx.y * 128;    // rows = slow index
    const int bn = blockIdx.x * 128;    // cols = fast index (A-panel reuse)
    f32x4 acc[4][4];
    #pragma unroll
    for (int m = 0; m < 4; m++)
        #pragma unroll
        for (int n = 0; n < 4; n++)
            acc[m][n] = (f32x4){0.f, 0.f, 0.f, 0.f};

    gemm_core<GATHER, BB>(Ab, A2b, Bt, K, bm, bn, AlF, BlF, acc);

    const int lane = threadIdx.x & 63;
    const int wave = threadIdx.x >> 6;
    const int wr = (wave >> 1) * 64, wc = (wave & 1) * 64;
    const int l15 = lane & 15, r0 = (lane >> 4) * 4;
    #pragma unroll
    for (int n = 0; n < 4; n++) {
        int col = bn + wc + n * 16 + l15;
        float bb = (EPI == EP_BIAS) ? bias[col] : 0.f;
        #pragma unroll
        for (int m = 0; m < 4; m++) {
            int rowb = bm + wr + m * 16 + r0;
            #pragma unroll
            for (int j = 0; j < 4; j++)
                Cb[(size_t)(rowb + j) * N + col] =
                    f2bf(epilogue<EPI>(acc[m][n][j], bb, scale));
        }
    }
}

// ---------------------------------------------------------------------------
// gemm_ln v2: BM=64, BN=256 (full row) GEMM + fused LayerNorm epilogue.
// 4 waves; wave w owns cols [w*64, w*64+64) of ALL 64 rows -> acc[4][4].
//   FIN=0: out bf16 = LN(acc)                  (QzW2a -> msg_ln)
//   FIN=1: out f32  = LN(acc) + bf2f(res16)    (mlp2  -> final out)
// ---------------------------------------------------------------------------
template<int BB, int FIN>
__global__ __launch_bounds__(256) void gemm_ln(
    const short* __restrict__ Ab, const short* __restrict__ Bt,
    const float* __restrict__ g, const float* __restrict__ bv,
    const short* __restrict__ res16, void* __restrict__ Co, int K)
{
    __shared__ short Al[4096];      // [64][64]
    __shared__ short Bl[16384];     // [256][64]
    __shared__ float redS[4][64], redQ[4][64];
    const int tid  = threadIdx.x;
    const int lane = tid & 63;
    const int wave = tid >> 6;      // col-slice owner
    const int l15  = lane & 15;
    const int kg   = lane >> 4;
    const int srow = tid >> 3;      // 0..31
    const int sc   = tid & 7;
    const int bm   = blockIdx.x * 64;
    const short* Bp = BB ? Bt + ((size_t)(bm >> 14) << 16) : Bt;

    f32x4 acc[4][4];
    #pragma unroll
    for (int m = 0; m < 4; m++)
        #pragma unroll
        for (int n = 0; n < 4; n++)
            acc[m][n] = (f32x4){0.f, 0.f, 0.f, 0.f};

    for (int k0 = 0; k0 < K; k0 += 64) {
        __syncthreads();
        #pragma unroll
        for (int q = 0; q < 2; q++) {       // A: 64 rows
            int row = q * 32 + srow;
            int cp  = sc ^ (row & 7);
            gload16(Ab + (size_t)(bm + row) * K + k0 + cp * 8,
                    &Al[(q * 256 + wave * 64) * 8]);
        }
        #pragma unroll
        for (int q = 0; q < 8; q++) {       // B: 256 rows
            int row = q * 32 + srow;
            int cp  = sc ^ (row & 7);
            gload16(Bp + (size_t)row * K + k0 + cp * 8,
                    &Bl[(q * 256 + wave * 64) * 8]);
        }
        __syncthreads();

        #pragma unroll
        for (int ks = 0; ks < 2; ks++) {
            short8v afr[4], bfr[4];
            #pragma unroll
            for (int m = 0; m < 4; m++) {
                int R = m * 16 + l15;
                afr[m] = *reinterpret_cast<const short8v*>(
                    &Al[R * 64 + (((ks * 4 + kg) ^ (R & 7)) * 8)]);
            }
            #pragma unroll
            for (int n = 0; n < 4; n++) {
                int R = wave * 64 + n * 16 + l15;
                bfr[n] = *reinterpret_cast<const short8v*>(
                    &Bl[R * 64 + (((ks * 4 + kg) ^ (R & 7)) * 8)]);
            }
            #pragma unroll
            for (int m = 0; m < 4; m++)
                #pragma unroll
                for (int n = 0; n < 4; n++)
                    acc[m][n] = __builtin_amdgcn_mfma_f32_16x16x32_bf16(
                        afr[m], bfr[n], acc[m][n], 0, 0, 0);
        }
    }

    // ---- fused LayerNorm epilogue ----
    #pragma unroll
    for (int m = 0; m < 4; m++)
        #pragma unroll
        for (int j = 0; j < 4; j++) {
            float s1 = 0.f, s2 = 0.f;
            #pragma unroll
            for (int n = 0; n < 4; n++) {
                float v = acc[m][n][j];
                s1 += v; s2 += v * v;
            }
            s1 += __shfl_xor(s1, 1, 64); s2 += __shfl_xor(s2, 1, 64);
            s1 += __shfl_xor(s1, 2, 64); s2 += __shfl_xor(s2, 2, 64);
            s1 += __shfl_xor(s1, 4, 64); s2 += __shfl_xor(s2, 4, 64);
            s1 += __shfl_xor(s1, 8, 64); s2 += __shfl_xor(s2, 8, 64);
            if (l15 == 0) {
                int row = m * 16 + kg * 4 + j;
                redS[wave][row] = s1;
                redQ[wave][row] = s2;
            }
        }
    __syncthreads();

    float gc[4], bc[4];
    #pragma unroll
    for (int n = 0; n < 4; n++) {
        int col = wave * 64 + n * 16 + l15;
        gc[n] = g[col]; bc[n] = bv[col];
    }
    #pragma unroll
    for (int m = 0; m < 4; m++)
        #pragma unroll
        for (int j = 0; j < 4; j++) {
            int row = m * 16 + kg * 4 + j;
            float mean = (redS[0][row] + redS[1][row] +
                          redS[2][row] + redS[3][row]) * (1.f / 256.f);
            float var  = (redQ[0][row] + redQ[1][row] +
                          redQ[2][row] + redQ[3][row]) * (1.f / 256.f)
                         - mean * mean;
            float inv  = rsqrtf(var + 1e-5f);
            #pragma unroll
            for (int n = 0; n < 4; n++) {
                int col = wave * 64 + n * 16 + l15;
                float o = (acc[m][n][j] - mean) * inv * gc[n] + bc[n];
                size_t gi = (size_t)(bm + row) * 256 + col;
                if (FIN) ((float*)Co)[gi] = o + bf2f(res16[gi]);
                else     ((short*)Co)[gi] = f2bf(o);
            }
        }
}

// Q GEMM with fused attention-Z epilogue -> Qz bf16.  GRID: x = col (fast).
__global__ __launch_bounds__(256) void gemm_qz(
    const short* __restrict__ Ab, const short* __restrict__ Bt,
    const float* __restrict__ Ksb, short* __restrict__ Qz)
{
    __shared__ short AlF[8192];
    __shared__ short BlF[8192];
    const int bm = blockIdx.y * 128;
    const int bn = blockIdx.x * 128;
    f32x4 acc[4][4];
    #pragma unroll
    for (int m = 0; m < 4; m++)
        #pragma unroll
        for (int n = 0; n < 4; n++)
            acc[m][n] = (f32x4){0.f, 0.f, 0.f, 0.f};

    gemm_core<GA_PLAIN, 0>(Ab, nullptr, Bt, 256, bm, bn, AlF, BlF, acc);

    const int lane = threadIdx.x & 63;
    const int wave = threadIdx.x >> 6;
    const int wr = (wave >> 1) * 64, wc = (wave & 1) * 64;
    const int l15 = lane & 15;
    const int b = bm >> 14;
    float Ksf[4];
    #pragma unroll
    for (int n = 0; n < 4; n++)
        Ksf[n] = Ksb[b * 256 + bn + wc + n * 16 + l15];
    #pragma unroll
    for (int m = 0; m < 4; m++)
        #pragma unroll
        for (int n = 0; n < 4; n++)
            #pragma unroll
            for (int j = 0; j < 4; j++) {
                float c = acc[m][n][j];
                acc[m][n][j] = c > 0.f ? c + 1.f : expf(c);   // elu+1
            }
    #pragma unroll
    for (int hh = 0; hh < 2; hh++) {
        #pragma unroll
        for (int m = 0; m < 4; m++)
            #pragma unroll
            for (int j = 0; j < 4; j++) {
                float part = acc[m][2 * hh][j] * Ksf[2 * hh]
                           + acc[m][2 * hh + 1][j] * Ksf[2 * hh + 1];
                part += __shfl_xor(part, 1, 64);
                part += __shfl_xor(part, 2, 64);
                part += __shfl_xor(part, 4, 64);
                part += __shfl_xor(part, 8, 64);
                float z = 4096.f / (part + 1e-6f);
                acc[m][2 * hh][j]     *= z;
                acc[m][2 * hh + 1][j] *= z;
            }
    }
    const int r0 = (lane >> 4) * 4;
    #pragma unroll
    for (int n = 0; n < 4; n++) {
        int col = bn + wc + n * 16 + l15;
        #pragma unroll
        for (int m = 0; m < 4; m++) {
            int rowb = bm + wr + m * 16 + r0;
            #pragma unroll
            for (int j = 0; j < 4; j++)
                Qz[(size_t)(rowb + j) * 256 + col] = f2bf(acc[m][n][j]);
        }
    }
}

// LayerNorm: 1 row (C=256) per wave (bf16 in/out) — used for conv-LN only
__global__ __launch_bounds__(256) void ln_bf16(
    const short* __restrict__ in, const float* __restrict__ g,
    const float* __restrict__ bta, short* __restrict__ out)
{
    const int wave = threadIdx.x >> 6, lane = threadIdx.x & 63;
    const size_t row = (size_t)blockIdx.x * 4 + wave;
    short4 s = reinterpret_cast<const short4*>(in)[row * 64 + lane];
    float v[4] = {bf2f(s.x), bf2f(s.y), bf2f(s.z), bf2f(s.w)};
    float s1 = v[0] + v[1] + v[2] + v[3];
    float s2 = v[0]*v[0] + v[1]*v[1] + v[2]*v[2] + v[3]*v[3];
    #pragma unroll
    for (int off = 1; off < 64; off <<= 1) {
        s1 += __shfl_xor(s1, off, 64);
        s2 += __shfl_xor(s2, off, 64);
    }
    float mean = s1 * (1.f / 256.f);
    float var  = s2 * (1.f / 256.f) - mean * mean;
    float inv  = rsqrtf(var + 1e-5f);
    float4 gg = reinterpret_cast<const float4*>(g)[lane];
    float4 bb = reinterpret_cast<const float4*>(bta)[lane];
    short4 o;
    o.x = f2bf((v[0] - mean) * inv * gg.x + bb.x);
    o.y = f2bf((v[1] - mean) * inv * gg.y + bb.y);
    o.z = f2bf((v[2] - mean) * inv * gg.z + bb.z);
    o.w = f2bf((v[3] - mean) * inv * gg.w + bb.w);
    reinterpret_cast<short4*>(out)[row * 64 + lane] = o;
}

// partial KV over a 128-row s-chunk (bf16 K/V in)
__global__ __launch_bounds__(256) void kv_partial(
    const short* __restrict__ Km, const short* __restrict__ Vm,
    float* __restrict__ pKV, float* __restrict__ pKs)
{
    int blk = blockIdx.x;
    int bh = blk >> 5, chunk = blk & 31;
    int b = bh >> 3, h = bh & 7;
    int tid = threadIdx.x;
    int e = tid & 31, dq = tid >> 5;
    int d_l = tid & 31, r_l = tid >> 5;
    __shared__ float Ks[16][32], Vs[16][32];
    float acc[4] = {0.f, 0.f, 0.f, 0.f};
    float ks = 0.f;
    const size_t base = ((size_t)b * 4096 + chunk * 128) * 256 + h * 32;

    for (int s0 = 0; s0 < 128; s0 += 16) {
        Ks[r_l][d_l]     = bf2f(Km[base + (size_t)(s0 + r_l) * 256 + d_l]);
        Ks[r_l + 8][d_l] = bf2f(Km[base + (size_t)(s0 + r_l + 8) * 256 + d_l]);
        Vs[r_l][d_l]     = bf2f(Vm[base + (size_t)(s0 + r_l) * 256 + d_l]);
        Vs[r_l + 8][d_l] = bf2f(Vm[base + (size_t)(s0 + r_l + 8) * 256 + d_l]);
        __syncthreads();
        #pragma unroll
        for (int sr = 0; sr < 16; sr++) {
            float vv = Vs[sr][e];
            #pragma unroll
            for (int i = 0; i < 4; i++)
                acc[i] = fmaf(Ks[sr][dq * 4 + i], vv, acc[i]);
        }
        if (tid < 32) {
            #pragma unroll
            for (int sr = 0; sr < 16; sr++) ks += Ks[sr][tid];
        }
        __syncthreads();
    }
    #pragma unroll
    for (int i = 0; i < 4; i++)
        pKV[(size_t)blk * 1024 + (dq * 4 + i) * 32 + e] = acc[i];
    if (tid < 32) pKs[blk * 32 + tid] = ks;
}

// reduce 32 chunks -> KV[bh][1024], Ksum[bh][32]
__global__ __launch_bounds__(256) void kv_reduce(
    const float* __restrict__ pKV, const float* __restrict__ pKs,
    float* __restrict__ KV, float* __restrict__ Ksum)
{
    int bh = blockIdx.x;
    int tid = threadIdx.x;
    float s0 = 0.f, s1 = 0.f, s2 = 0.f, s3 = 0.f;
    for (int c = 0; c < 32; c++) {
        const float* p = &pKV[(size_t)(bh * 32 + c) * 1024];
        s0 += p[tid]; s1 += p[tid + 256]; s2 += p[tid + 512]; s3 += p[tid + 768];
    }
    KV[bh * 1024 + tid]       = s0;
    KV[bh * 1024 + tid + 256] = s1;
    KV[bh * 1024 + tid + 512] = s2;
    KV[bh * 1024 + tid + 768] = s3;
    if (tid < 32) {
        float s = 0.f;
        for (int c = 0; c < 32; c++) s += pKs[(bh * 32 + c) * 32 + tid];
        Ksum[bh * 32 + tid] = s;
    }
}

extern "C" void kernel_launch(void* const* d_in, const int* in_sizes, int n_in,
                              void* d_out, int out_size, void* d_ws, size_t ws_size,
                              hipStream_t stream) {
    const float* x      = (const float*)d_in[0];
    const float* sr_w   = (const float*)d_in[1];
    const float* sr_b   = (const float*)d_in[2];
    const float* norm_g = (const float*)d_in[3];
    const float* norm_b = (const float*)d_in[4];
    const float* wq     = (const float*)d_in[5];
    const float* wk     = (const float*)d_in[6];
    const float* wv     = (const float*)d_in[7];
    const float* wm     = (const float*)d_in[8];
    const float* mlp_w1 = (const float*)d_in[9];
    const float* mlp_w2 = (const float*)d_in[10];
    const float* n1_g   = (const float*)d_in[11];
    const float* n1_b   = (const float*)d_in[12];
    const float* n2_g   = (const float*)d_in[13];
    const float* n2_b   = (const float*)d_in[14];
    float* out = (float*)d_out;

    // ---- workspace layout (~141 MB of ~256 MiB) ----
    short* Wct = (short*)d_ws;          // [256][1024]
    short* Wqt = Wct + 262144;          // [256][256]
    short* Wkt = Wqt + 65536;
    short* Wvt = Wkt + 65536;
    short* W1t = Wvt + 65536;           // [512][512]
    short* W2t = W1t + 262144;          // [256][512]
    short* W2a = W2t + 131072;          // [4][256][256]
    float* KVb = (float*)(W2a + 262144);// 32768 f
    float* Ksb = KVb + 32768;           // 1024 f
    float* pKs = Ksb + 1024;            // 32768 f
    float* pKV = pKs + 32768;           // 1048576 f
    short* xb16 = (short*)(pKV + 1048576);   // [65536][256] 32MB
    short* SCR  = xb16 + 16777216;           // 32MB scratch:
    short* xs16 = SCR;                  //   [16384][256] 8MB
    short* Km16 = SCR + 4194304;        //   8MB
    short* Vm16 = Km16 + 4194304;       //   8MB
    short* Qz   = SCR;                  // ALIAS 32MB (xs/Km/Vm dead)
    short* Hc   = SCR + 16777216;       // [65536][512] 64MB
    short* Mb16 = (short*)d_out;        // msg_ln bf16 in d_out (overwritten)

    const float inv_S = 1.f / 4096.f;

    // prep: weights + x cast
    prep_weights<<<3328, 256, 0, stream>>>(
        sr_w, wq, wk, wv, mlp_w1, mlp_w2, Wct, Wqt, Wkt, Wvt, W1t, W2t);
    cast_bf16<<<2048, 256, 0, stream>>>(x, xb16, 4194304);

    // conv as GEMM + bias -> xs16; LN in place   (cols fastest)
    gemm_bf16<GA_CONV, EP_BIAS, 0><<<dim3(2, 128), 256, 0, stream>>>(
        xb16, nullptr, Wct, sr_b, xs16, 256, 1024, 0.f);
    ln_bf16<<<4096, 256, 0, stream>>>(xs16, norm_g, norm_b, xs16);

    // K = elu(xs@wk)+1 ; Vsc = (xs@wv)/S
    gemm_bf16<GA_PLAIN, EP_ELU1, 0><<<dim3(2, 128), 256, 0, stream>>>(
        xs16, nullptr, Wkt, nullptr, Km16, 256, 256, 0.f);
    gemm_bf16<GA_PLAIN, EP_SCALE, 0><<<dim3(2, 128), 256, 0, stream>>>(
        xs16, nullptr, Wvt, nullptr, Vm16, 256, 256, inv_S);

    // KV + Ksum, fold KV@wm -> W2a
    kv_partial<<<1024, 256, 0, stream>>>(Km16, Vm16, pKV, pKs);
    kv_reduce<<<32, 256, 0, stream>>>(pKV, pKs, KVb, Ksb);
    w2_prep<<<1024, 256, 0, stream>>>(KVb, wm, W2a);

    // Qz = Z .* (elu(x@wq)+1)  [bf16] (aliases dead xs/Km/Vm)
    gemm_qz<<<dim3(2, 512), 256, 0, stream>>>(xb16, Wqt, Ksb, Qz);

    // msg_ln = LN1(Qz @ W2a[b]) -> Mb16 (bf16, in d_out)  [fused]
    gemm_ln<1, 0><<<1024, 256, 0, stream>>>(
        Qz, W2a, n1_g, n1_b, nullptr, Mb16, 256);

    // h = relu([x|msg_ln] @ w1) -> Hc  (cols fastest: A-panel reuse)
    gemm_bf16<GA_CONCAT, EP_RELU, 0><<<dim3(4, 512), 256, 0, stream>>>(
        xb16, Mb16, W1t, nullptr, Hc, 512, 512, 0.f);

    // out = LN2(h @ w2) + x  (fused; residual read bf16)
    gemm_ln<0, 1><<<1024, 256, 0, stream>>>(
        Hc, W2t, n2_g, n2_b, xb16, out, 512);
}

// Round 11
// 256.020 us; speedup vs baseline: 6.1368x; 1.0343x over previous
//
#include <hip/hip_runtime.h>
#include <math.h>

// ---------------------------------------------------------------------------
// GlobalSubSampleAttn round 11:
//  - T1 XCD-chunked bijective block swizzle in gemm_bf16/gemm_qz: the 4
//    col-tiles sharing an A row-panel now run on the SAME XCD's L2.
//    (round 10's plain grid-order swap put them on 4 different XCDs ->
//    mlp1 FETCH went 113->132MB; per-XCD L2s are not shared)
//  - K/V GEMMs merged: Wkt||Wvt is a contiguous [512][256] Bt; EP_KV
//    epilogue (bn<256 ? elu+1 : *1/S) -> fused KVm[16384][512];
//    kv_partial reads stride 512.  Saves one xs16 pass + a launch.
// B=4, N=16384, C=256, S=4096, NHEAD=8, D=32
// ---------------------------------------------------------------------------

#define EP_NONE  0
#define EP_BIAS  1
#define EP_ELU1  2
#define EP_SCALE 3
#define EP_RELU  4
#define EP_KV    5

#define GA_PLAIN  0
#define GA_CONV   1
#define GA_CONCAT 2

typedef __attribute__((ext_vector_type(8))) short short8v;   // 8 bf16
typedef __attribute__((ext_vector_type(4))) float f32x4;

__device__ inline short f2bf(float f) {
    unsigned u = __float_as_uint(f);
    u += 0x7FFFu + ((u >> 16) & 1u);      // round-to-nearest-even
    return (short)(u >> 16);
}
__device__ inline float bf2f(short s) {
    return __uint_as_float(((unsigned)(unsigned short)s) << 16);
}

__device__ inline void gload16(const void* g, void* l) {
    __builtin_amdgcn_global_load_lds(
        (const __attribute__((address_space(1))) void*)g,
        (__attribute__((address_space(3))) void*)l, 16, 0, 0);
}

template<int EPI>
__device__ inline float epilogue(float c, float b, float scale) {
    if (EPI == EP_BIAS)  return c + b;
    if (EPI == EP_ELU1)  return c > 0.f ? c + 1.f : expf(c);   // elu(c)+1
    if (EPI == EP_SCALE) return c * scale;
    if (EPI == EP_RELU)  return fmaxf(c, 0.f);
    return c;
}

// XCD-chunked bijective swizzle (nwg % 8 == 0 for all our grids)
__device__ inline int xcd_swz(int lid, int nwg) {
    return (lid & 7) * (nwg >> 3) + (lid >> 3);
}

// x fp32 -> bf16 (vector)
__global__ __launch_bounds__(256) void cast_bf16(
    const float* __restrict__ in, short* __restrict__ ob, int n4)
{
    int i = blockIdx.x * 256 + threadIdx.x;
    int stride = gridDim.x * 256;
    for (; i < n4; i += stride) {
        float4 v = reinterpret_cast<const float4*>(in)[i];
        short4 s;
        s.x = f2bf(v.x); s.y = f2bf(v.y); s.z = f2bf(v.z); s.w = f2bf(v.w);
        reinterpret_cast<short4*>(ob)[i] = s;
    }
}

// all weight transposes in one launch (3328 blocks)
__global__ __launch_bounds__(256) void prep_weights(
    const float* __restrict__ srw, const float* __restrict__ wq,
    const float* __restrict__ wk,  const float* __restrict__ wv,
    const float* __restrict__ w1,  const float* __restrict__ w2,
    short* __restrict__ Wct, short* __restrict__ Wqt, short* __restrict__ Wkt,
    short* __restrict__ Wvt, short* __restrict__ W1t, short* __restrict__ W2t)
{
    int bid = blockIdx.x, tid = threadIdx.x;
    if (bid < 1024) {                       // conv: [o][k=p*256+ci]
        int idx = bid * 256 + tid;
        int k = idx & 1023, o = idx >> 10;
        int p = k >> 8, ci = k & 255;
        Wct[idx] = f2bf(srw[(o << 10) + (ci << 2) + p]);
    } else if (bid < 1792) {                // wq/wk/wv: [n][k] 256x256
        int which = (bid - 1024) >> 8;
        int idx = ((bid - 1024) & 255) * 256 + tid;
        int n = idx >> 8, k = idx & 255;
        const float* W = which == 0 ? wq : (which == 1 ? wk : wv);
        short* Wt = which == 0 ? Wqt : (which == 1 ? Wkt : Wvt);
        Wt[idx] = f2bf(W[k * 256 + n]);
    } else if (bid < 2816) {                // mlp_w1: [n][k] 512x512
        int idx = (bid - 1792) * 256 + tid;
        int n = idx >> 9, k = idx & 511;
        W1t[idx] = f2bf(w1[k * 512 + n]);
    } else {                                // mlp_w2: [n][k] 256x512
        int idx = (bid - 2816) * 256 + tid;
        int n = idx >> 9, k = idx & 511;
        W2t[idx] = f2bf(w2[k * 256 + n]);
    }
}

// W2a[b][n][k=h*32+d] = sum_v KV[b,h,d,v] * wm[h*32+v, n]   (bf16 Bt form)
__global__ __launch_bounds__(256) void w2_prep(
    const float* __restrict__ KVb, const float* __restrict__ wm,
    short* __restrict__ W2a)
{
    int b = blockIdx.x >> 8, n = blockIdx.x & 255;
    int tid = threadIdx.x;                 // = k
    __shared__ float wcol[256];
    wcol[tid] = wm[tid * 256 + n];
    __syncthreads();
    int h = tid >> 5, d = tid & 31;
    const float* kv = &KVb[b * 8192 + h * 1024 + d * 32];
    float s = 0.f;
    #pragma unroll
    for (int v = 0; v < 32; v++) s = fmaf(kv[v], wcol[h * 32 + v], s);
    W2a[((size_t)(b * 256 + n) << 8) + tid] = f2bf(s);
}

// ---------------------------------------------------------------------------
// 128x128 staged bf16 GEMM core: swizzled gload_lds + ds_read
// ---------------------------------------------------------------------------
template<int GATHER, int BB>
__device__ inline void gemm_core(
    const short* __restrict__ Ab, const short* __restrict__ A2b,
    const short* __restrict__ Bt, int K, int bm, int bn,
    short* AlF, short* BlF, f32x4 acc[4][4])
{
    const int tid  = threadIdx.x;
    const int lane = tid & 63;
    const int wave = tid >> 6;
    const int wr   = (wave >> 1) * 64;
    const int wc   = (wave & 1) * 64;
    const int l15  = lane & 15;
    const int kg   = lane >> 4;
    const int srow = tid >> 3;
    const int sc   = tid & 7;

    if (BB) Bt += (size_t)(bm >> 14) << 16;

    for (int k0 = 0; k0 < K; k0 += 64) {
        __syncthreads();
        #pragma unroll
        for (int q = 0; q < 4; q++) {
            int row = q * 32 + srow;
            int cp  = sc ^ (row & 7);
            const short* ga;
            if (GATHER == GA_PLAIN) {
                ga = Ab + (size_t)(bm + row) * K + k0 + cp * 8;
            } else if (GATHER == GA_CONCAT) {
                const short* base = (k0 < 256) ? Ab : A2b;
                ga = base + ((size_t)(bm + row) << 8) + (k0 & 255) + cp * 8;
            } else { // GA_CONV
                int grow = bm + row;
                int b = grow >> 12, s = grow & 4095;
                int ii = s >> 6, jj = s & 63;
                int p = k0 >> 8;
                int kh = p >> 1, kw = p & 1;
                int pix = (b << 14) + ((2 * ii + kh) << 7) + (2 * jj + kw);
                ga = Ab + ((size_t)pix << 8) + (k0 & 255) + cp * 8;
            }
            gload16(ga, &AlF[(q * 256 + wave * 64) * 8]);
            const short* gb = Bt + (size_t)(bn + row) * K + k0 + cp * 8;
            gload16(gb, &BlF[(q * 256 + wave * 64) * 8]);
        }
        __syncthreads();

        #pragma unroll
        for (int ks = 0; ks < 2; ks++) {
            short8v afr[4], bfr[4];
            #pragma unroll
            for (int m = 0; m < 4; m++) {
                int R = wr + m * 16 + l15;
                afr[m] = *reinterpret_cast<const short8v*>(
                    &AlF[R * 64 + (((ks * 4 + kg) ^ (R & 7)) * 8)]);
            }
            #pragma unroll
            for (int n = 0; n < 4; n++) {
                int R = wc + n * 16 + l15;
                bfr[n] = *reinterpret_cast<const short8v*>(
                    &BlF[R * 64 + (((ks * 4 + kg) ^ (R & 7)) * 8)]);
            }
            #pragma unroll
            for (int m = 0; m < 4; m++)
                #pragma unroll
                for (int n = 0; n < 4; n++)
                    acc[m][n] = __builtin_amdgcn_mfma_f32_16x16x32_bf16(
                        afr[m], bfr[n], acc[m][n], 0, 0, 0);
        }
    }
}

// generic 128x128 GEMM, bf16 output, XCD-swizzled block order (cols fastest)
template<int GATHER, int EPI, int BB>
__global__ __launch_bounds__(256) void gemm_bf16(
    const short* __restrict__ Ab, const short* __restrict__ A2b,
    const short* __restrict__ Bt, const float* __restrict__ bias,
    short* __restrict__ Cb, int N, int K, float scale)
{
    __shared__ short AlF[8192];
    __shared__ short BlF[8192];
    const int nwg = gridDim.x * gridDim.y;
    const int lid = blockIdx.y * gridDim.x + blockIdx.x;
    const int swz = xcd_swz(lid, nwg);
    const int bn  = (swz % gridDim.x) * 128;   // col = fast index
    const int bm  = (swz / gridDim.x) * 128;
    f32x4 acc[4][4];
    #pragma unroll
    for (int m = 0; m < 4; m++)
        #pragma unroll
        for (int n = 0; n < 4; n++)
            acc[m][n] = (f32x4){0.f, 0.f, 0.f, 0.f};

    gemm_core<GATHER, BB>(Ab, A2b, Bt, K, bm, bn, AlF, BlF, acc);

    const int lane = threadIdx.x & 63;
    const int wave = threadIdx.x >> 6;
    const int wr = (wave >> 1) * 64, wc = (wave & 1) * 64;
    const int l15 = lane & 15, r0 = (lane >> 4) * 4;
    #pragma unroll
    for (int n = 0; n < 4; n++) {
        int col = bn + wc + n * 16 + l15;
        float bb = (EPI == EP_BIAS) ? bias[col] : 0.f;
        #pragma unroll
        for (int m = 0; m < 4; m++) {
            int rowb = bm + wr + m * 16 + r0;
            #pragma unroll
            for (int j = 0; j < 4; j++) {
                float c = acc[m][n][j];
                float o;
                if (EPI == EP_KV)
                    o = (bn < 256) ? (c > 0.f ? c + 1.f : expf(c)) : c * scale;
                else
                    o = epilogue<EPI>(c, bb, scale);
                Cb[(size_t)(rowb + j) * N + col] = f2bf(o);
            }
        }
    }
}

// ---------------------------------------------------------------------------
// gemm_ln: BM=64, BN=256 (full row) GEMM + fused LayerNorm epilogue.
//   FIN=0: out bf16 = LN(acc)                  (QzW2a -> msg_ln)
//   FIN=1: out f32  = LN(acc) + bf2f(res16)    (mlp2  -> final out)
// ---------------------------------------------------------------------------
template<int BB, int FIN>
__global__ __launch_bounds__(256) void gemm_ln(
    const short* __restrict__ Ab, const short* __restrict__ Bt,
    const float* __restrict__ g, const float* __restrict__ bv,
    const short* __restrict__ res16, void* __restrict__ Co, int K)
{
    __shared__ short Al[4096];      // [64][64]
    __shared__ short Bl[16384];     // [256][64]
    __shared__ float redS[4][64], redQ[4][64];
    const int tid  = threadIdx.x;
    const int lane = tid & 63;
    const int wave = tid >> 6;      // col-slice owner
    const int l15  = lane & 15;
    const int kg   = lane >> 4;
    const int srow = tid >> 3;      // 0..31
    const int sc   = tid & 7;
    const int bm   = blockIdx.x * 64;
    const short* Bp = BB ? Bt + ((size_t)(bm >> 14) << 16) : Bt;

    f32x4 acc[4][4];
    #pragma unroll
    for (int m = 0; m < 4; m++)
        #pragma unroll
        for (int n = 0; n < 4; n++)
            acc[m][n] = (f32x4){0.f, 0.f, 0.f, 0.f};

    for (int k0 = 0; k0 < K; k0 += 64) {
        __syncthreads();
        #pragma unroll
        for (int q = 0; q < 2; q++) {       // A: 64 rows
            int row = q * 32 + srow;
            int cp  = sc ^ (row & 7);
            gload16(Ab + (size_t)(bm + row) * K + k0 + cp * 8,
                    &Al[(q * 256 + wave * 64) * 8]);
        }
        #pragma unroll
        for (int q = 0; q < 8; q++) {       // B: 256 rows
            int row = q * 32 + srow;
            int cp  = sc ^ (row & 7);
            gload16(Bp + (size_t)row * K + k0 + cp * 8,
                    &Bl[(q * 256 + wave * 64) * 8]);
        }
        __syncthreads();

        #pragma unroll
        for (int ks = 0; ks < 2; ks++) {
            short8v afr[4], bfr[4];
            #pragma unroll
            for (int m = 0; m < 4; m++) {
                int R = m * 16 + l15;
                afr[m] = *reinterpret_cast<const short8v*>(
                    &Al[R * 64 + (((ks * 4 + kg) ^ (R & 7)) * 8)]);
            }
            #pragma unroll
            for (int n = 0; n < 4; n++) {
                int R = wave * 64 + n * 16 + l15;
                bfr[n] = *reinterpret_cast<const short8v*>(
                    &Bl[R * 64 + (((ks * 4 + kg) ^ (R & 7)) * 8)]);
            }
            #pragma unroll
            for (int m = 0; m < 4; m++)
                #pragma unroll
                for (int n = 0; n < 4; n++)
                    acc[m][n] = __builtin_amdgcn_mfma_f32_16x16x32_bf16(
                        afr[m], bfr[n], acc[m][n], 0, 0, 0);
        }
    }

    // ---- fused LayerNorm epilogue ----
    #pragma unroll
    for (int m = 0; m < 4; m++)
        #pragma unroll
        for (int j = 0; j < 4; j++) {
            float s1 = 0.f, s2 = 0.f;
            #pragma unroll
            for (int n = 0; n < 4; n++) {
                float v = acc[m][n][j];
                s1 += v; s2 += v * v;
            }
            s1 += __shfl_xor(s1, 1, 64); s2 += __shfl_xor(s2, 1, 64);
            s1 += __shfl_xor(s1, 2, 64); s2 += __shfl_xor(s2, 2, 64);
            s1 += __shfl_xor(s1, 4, 64); s2 += __shfl_xor(s2, 4, 64);
            s1 += __shfl_xor(s1, 8, 64); s2 += __shfl_xor(s2, 8, 64);
            if (l15 == 0) {
                int row = m * 16 + kg * 4 + j;
                redS[wave][row] = s1;
                redQ[wave][row] = s2;
            }
        }
    __syncthreads();

    float gc[4], bc[4];
    #pragma unroll
    for (int n = 0; n < 4; n++) {
        int col = wave * 64 + n * 16 + l15;
        gc[n] = g[col]; bc[n] = bv[col];
    }
    #pragma unroll
    for (int m = 0; m < 4; m++)
        #pragma unroll
        for (int j = 0; j < 4; j++) {
            int row = m * 16 + kg * 4 + j;
            float mean = (redS[0][row] + redS[1][row] +
                          redS[2][row] + redS[3][row]) * (1.f / 256.f);
            float var  = (redQ[0][row] + redQ[1][row] +
                          redQ[2][row] + redQ[3][row]) * (1.f / 256.f)
                         - mean * mean;
            float inv  = rsqrtf(var + 1e-5f);
            #pragma unroll
            for (int n = 0; n < 4; n++) {
                int col = wave * 64 + n * 16 + l15;
                float o = (acc[m][n][j] - mean) * inv * gc[n] + bc[n];
                size_t gi = (size_t)(bm + row) * 256 + col;
                if (FIN) ((float*)Co)[gi] = o + bf2f(res16[gi]);
                else     ((short*)Co)[gi] = f2bf(o);
            }
        }
}

// Q GEMM with fused attention-Z epilogue -> Qz bf16 (XCD-swizzled)
__global__ __launch_bounds__(256) void gemm_qz(
    const short* __restrict__ Ab, const short* __restrict__ Bt,
    const float* __restrict__ Ksb, short* __restrict__ Qz)
{
    __shared__ short AlF[8192];
    __shared__ short BlF[8192];
    const int nwg = gridDim.x * gridDim.y;
    const int lid = blockIdx.y * gridDim.x + blockIdx.x;
    const int swz = xcd_swz(lid, nwg);
    const int bn  = (swz % gridDim.x) * 128;
    const int bm  = (swz / gridDim.x) * 128;
    f32x4 acc[4][4];
    #pragma unroll
    for (int m = 0; m < 4; m++)
        #pragma unroll
        for (int n = 0; n < 4; n++)
            acc[m][n] = (f32x4){0.f, 0.f, 0.f, 0.f};

    gemm_core<GA_PLAIN, 0>(Ab, nullptr, Bt, 256, bm, bn, AlF, BlF, acc);

    const int lane = threadIdx.x & 63;
    const int wave = threadIdx.x >> 6;
    const int wr = (wave >> 1) * 64, wc = (wave & 1) * 64;
    const int l15 = lane & 15;
    const int b = bm >> 14;
    float Ksf[4];
    #pragma unroll
    for (int n = 0; n < 4; n++)
        Ksf[n] = Ksb[b * 256 + bn + wc + n * 16 + l15];
    #pragma unroll
    for (int m = 0; m < 4; m++)
        #pragma unroll
        for (int n = 0; n < 4; n++)
            #pragma unroll
            for (int j = 0; j < 4; j++) {
                float c = acc[m][n][j];
                acc[m][n][j] = c > 0.f ? c + 1.f : expf(c);   // elu+1
            }
    #pragma unroll
    for (int hh = 0; hh < 2; hh++) {
        #pragma unroll
        for (int m = 0; m < 4; m++)
            #pragma unroll
            for (int j = 0; j < 4; j++) {
                float part = acc[m][2 * hh][j] * Ksf[2 * hh]
                           + acc[m][2 * hh + 1][j] * Ksf[2 * hh + 1];
                part += __shfl_xor(part, 1, 64);
                part += __shfl_xor(part, 2, 64);
                part += __shfl_xor(part, 4, 64);
                part += __shfl_xor(part, 8, 64);
                float z = 4096.f / (part + 1e-6f);
                acc[m][2 * hh][j]     *= z;
                acc[m][2 * hh + 1][j] *= z;
            }
    }
    const int r0 = (lane >> 4) * 4;
    #pragma unroll
    for (int n = 0; n < 4; n++) {
        int col = bn + wc + n * 16 + l15;
        #pragma unroll
        for (int m = 0; m < 4; m++) {
            int rowb = bm + wr + m * 16 + r0;
            #pragma unroll
            for (int j = 0; j < 4; j++)
                Qz[(size_t)(rowb + j) * 256 + col] = f2bf(acc[m][n][j]);
        }
    }
}

// LayerNorm: 1 row (C=256) per wave (bf16 in/out) — conv-LN only
__global__ __launch_bounds__(256) void ln_bf16(
    const short* __restrict__ in, const float* __restrict__ g,
    const float* __restrict__ bta, short* __restrict__ out)
{
    const int wave = threadIdx.x >> 6, lane = threadIdx.x & 63;
    const size_t row = (size_t)blockIdx.x * 4 + wave;
    short4 s = reinterpret_cast<const short4*>(in)[row * 64 + lane];
    float v[4] = {bf2f(s.x), bf2f(s.y), bf2f(s.z), bf2f(s.w)};
    float s1 = v[0] + v[1] + v[2] + v[3];
    float s2 = v[0]*v[0] + v[1]*v[1] + v[2]*v[2] + v[3]*v[3];
    #pragma unroll
    for (int off = 1; off < 64; off <<= 1) {
        s1 += __shfl_xor(s1, off, 64);
        s2 += __shfl_xor(s2, off, 64);
    }
    float mean = s1 * (1.f / 256.f);
    float var  = s2 * (1.f / 256.f) - mean * mean;
    float inv  = rsqrtf(var + 1e-5f);
    float4 gg = reinterpret_cast<const float4*>(g)[lane];
    float4 bb = reinterpret_cast<const float4*>(bta)[lane];
    short4 o;
    o.x = f2bf((v[0] - mean) * inv * gg.x + bb.x);
    o.y = f2bf((v[1] - mean) * inv * gg.y + bb.y);
    o.z = f2bf((v[2] - mean) * inv * gg.z + bb.z);
    o.w = f2bf((v[3] - mean) * inv * gg.w + bb.w);
    reinterpret_cast<short4*>(out)[row * 64 + lane] = o;
}

// partial KV over a 128-row s-chunk; KVm fused [row][512]: K cols 0..255,
// V cols 256..511
__global__ __launch_bounds__(256) void kv_partial(
    const short* __restrict__ KVm,
    float* __restrict__ pKV, float* __restrict__ pKs)
{
    int blk = blockIdx.x;
    int bh = blk >> 5, chunk = blk & 31;
    int b = bh >> 3, h = bh & 7;
    int tid = threadIdx.x;
    int e = tid & 31, dq = tid >> 5;
    int d_l = tid & 31, r_l = tid >> 5;
    __shared__ float Ks[16][32], Vs[16][32];
    float acc[4] = {0.f, 0.f, 0.f, 0.f};
    float ks = 0.f;
    const size_t base = ((size_t)b * 4096 + chunk * 128) * 512 + h * 32;

    for (int s0 = 0; s0 < 128; s0 += 16) {
        Ks[r_l][d_l]     = bf2f(KVm[base + (size_t)(s0 + r_l) * 512 + d_l]);
        Ks[r_l + 8][d_l] = bf2f(KVm[base + (size_t)(s0 + r_l + 8) * 512 + d_l]);
        Vs[r_l][d_l]     = bf2f(KVm[base + (size_t)(s0 + r_l) * 512 + 256 + d_l]);
        Vs[r_l + 8][d_l] = bf2f(KVm[base + (size_t)(s0 + r_l + 8) * 512 + 256 + d_l]);
        __syncthreads();
        #pragma unroll
        for (int sr = 0; sr < 16; sr++) {
            float vv = Vs[sr][e];
            #pragma unroll
            for (int i = 0; i < 4; i++)
                acc[i] = fmaf(Ks[sr][dq * 4 + i], vv, acc[i]);
        }
        if (tid < 32) {
            #pragma unroll
            for (int sr = 0; sr < 16; sr++) ks += Ks[sr][tid];
        }
        __syncthreads();
    }
    #pragma unroll
    for (int i = 0; i < 4; i++)
        pKV[(size_t)blk * 1024 + (dq * 4 + i) * 32 + e] = acc[i];
    if (tid < 32) pKs[blk * 32 + tid] = ks;
}

// reduce 32 chunks -> KV[bh][1024], Ksum[bh][32]
__global__ __launch_bounds__(256) void kv_reduce(
    const float* __restrict__ pKV, const float* __restrict__ pKs,
    float* __restrict__ KV, float* __restrict__ Ksum)
{
    int bh = blockIdx.x;
    int tid = threadIdx.x;
    float s0 = 0.f, s1 = 0.f, s2 = 0.f, s3 = 0.f;
    for (int c = 0; c < 32; c++) {
        const float* p = &pKV[(size_t)(bh * 32 + c) * 1024];
        s0 += p[tid]; s1 += p[tid + 256]; s2 += p[tid + 512]; s3 += p[tid + 768];
    }
    KV[bh * 1024 + tid]       = s0;
    KV[bh * 1024 + tid + 256] = s1;
    KV[bh * 1024 + tid + 512] = s2;
    KV[bh * 1024 + tid + 768] = s3;
    if (tid < 32) {
        float s = 0.f;
        for (int c = 0; c < 32; c++) s += pKs[(bh * 32 + c) * 32 + tid];
        Ksum[bh * 32 + tid] = s;
    }
}

extern "C" void kernel_launch(void* const* d_in, const int* in_sizes, int n_in,
                              void* d_out, int out_size, void* d_ws, size_t ws_size,
                              hipStream_t stream) {
    const float* x      = (const float*)d_in[0];
    const float* sr_w   = (const float*)d_in[1];
    const float* sr_b   = (const float*)d_in[2];
    const float* norm_g = (const float*)d_in[3];
    const float* norm_b = (const float*)d_in[4];
    const float* wq     = (const float*)d_in[5];
    const float* wk     = (const float*)d_in[6];
    const float* wv     = (const float*)d_in[7];
    const float* wm     = (const float*)d_in[8];
    const float* mlp_w1 = (const float*)d_in[9];
    const float* mlp_w2 = (const float*)d_in[10];
    const float* n1_g   = (const float*)d_in[11];
    const float* n1_b   = (const float*)d_in[12];
    const float* n2_g   = (const float*)d_in[13];
    const float* n2_b   = (const float*)d_in[14];
    float* out = (float*)d_out;

    // ---- workspace layout (~141 MB of ~256 MiB) ----
    short* Wct = (short*)d_ws;          // [256][1024]
    short* Wqt = Wct + 262144;          // [256][256]
    short* Wkt = Wqt + 65536;           // [256][256]  \ contiguous = [512][256]
    short* Wvt = Wkt + 65536;           // [256][256]  /
    short* W1t = Wvt + 65536;           // [512][512]
    short* W2t = W1t + 262144;          // [256][512]
    short* W2a = W2t + 131072;          // [4][256][256]
    float* KVb = (float*)(W2a + 262144);// 32768 f
    float* Ksb = KVb + 32768;           // 1024 f
    float* pKs = Ksb + 1024;            // 32768 f
    float* pKV = pKs + 32768;           // 1048576 f
    short* xb16 = (short*)(pKV + 1048576);   // [65536][256] 32MB
    short* SCR  = xb16 + 16777216;           // 32MB scratch:
    short* xs16 = SCR;                  //   [16384][256] 8MB
    short* KVm  = SCR + 4194304;        //   [16384][512] 16MB fused K|V
    short* Qz   = SCR;                  // ALIAS 32MB (xs/KVm dead)
    short* Hc   = SCR + 16777216;       // [65536][512] 64MB
    short* Mb16 = (short*)d_out;        // msg_ln bf16 in d_out (overwritten)

    const float inv_S = 1.f / 4096.f;

    // prep: weights + x cast
    prep_weights<<<3328, 256, 0, stream>>>(
        sr_w, wq, wk, wv, mlp_w1, mlp_w2, Wct, Wqt, Wkt, Wvt, W1t, W2t);
    cast_bf16<<<2048, 256, 0, stream>>>(x, xb16, 4194304);

    // conv as GEMM + bias -> xs16; LN in place
    gemm_bf16<GA_CONV, EP_BIAS, 0><<<dim3(2, 128), 256, 0, stream>>>(
        xb16, nullptr, Wct, sr_b, xs16, 256, 1024, 0.f);
    ln_bf16<<<4096, 256, 0, stream>>>(xs16, norm_g, norm_b, xs16);

    // fused K|V GEMM: B = Wkt||Wvt [512][256]; KVm[row][0:256]=elu(K)+1,
    // [256:512]=V/S
    gemm_bf16<GA_PLAIN, EP_KV, 0><<<dim3(4, 128), 256, 0, stream>>>(
        xs16, nullptr, Wkt, nullptr, KVm, 512, 256, inv_S);

    // KV + Ksum, fold KV@wm -> W2a
    kv_partial<<<1024, 256, 0, stream>>>(KVm, pKV, pKs);
    kv_reduce<<<32, 256, 0, stream>>>(pKV, pKs, KVb, Ksb);
    w2_prep<<<1024, 256, 0, stream>>>(KVb, wm, W2a);

    // Qz = Z .* (elu(x@wq)+1)  [bf16] (aliases dead xs/KVm)
    gemm_qz<<<dim3(2, 512), 256, 0, stream>>>(xb16, Wqt, Ksb, Qz);

    // msg_ln = LN1(Qz @ W2a[b]) -> Mb16 (bf16, in d_out)  [fused]
    gemm_ln<1, 0><<<1024, 256, 0, stream>>>(
        Qz, W2a, n1_g, n1_b, nullptr, Mb16, 256);

    // h = relu([x|msg_ln] @ w1) -> Hc  (XCD-swizzled A-panel reuse)
    gemm_bf16<GA_CONCAT, EP_RELU, 0><<<dim3(4, 512), 256, 0, stream>>>(
        xb16, Mb16, W1t, nullptr, Hc, 512, 512, 0.f);

    // out = LN2(h @ w2) + x  (fused; residual read bf16)
    gemm_ln<0, 1><<<1024, 256, 0, stream>>>(
        Hc, W2t, n2_g, n2_b, xb16, out, 512);
}

// Round 12
// 238.856 us; speedup vs baseline: 6.5778x; 1.0719x over previous
//
#include <hip/hip_runtime.h>
#include <math.h>

// ---------------------------------------------------------------------------
// GlobalSubSampleAttn round 12:
//  - gemm_ln v3: 512 threads, BM=128, 8 waves (2 row x 4 col), acc[4][4],
//    LDS 52KB, 6 gload16/thread/K-step (was: BM=64, 4 waves, 10 loads,
//    ~1.5 blocks/CU -> 60us each at MfmaUtil 10%).  Same math -> same absmax.
//  - everything else unchanged from round 11 (256 us)
// B=4, N=16384, C=256, S=4096, NHEAD=8, D=32
// ---------------------------------------------------------------------------

#define EP_NONE  0
#define EP_BIAS  1
#define EP_ELU1  2
#define EP_SCALE 3
#define EP_RELU  4
#define EP_KV    5

#define GA_PLAIN  0
#define GA_CONV   1
#define GA_CONCAT 2

typedef __attribute__((ext_vector_type(8))) short short8v;   // 8 bf16
typedef __attribute__((ext_vector_type(4))) float f32x4;

__device__ inline short f2bf(float f) {
    unsigned u = __float_as_uint(f);
    u += 0x7FFFu + ((u >> 16) & 1u);      // round-to-nearest-even
    return (short)(u >> 16);
}
__device__ inline float bf2f(short s) {
    return __uint_as_float(((unsigned)(unsigned short)s) << 16);
}

__device__ inline void gload16(const void* g, void* l) {
    __builtin_amdgcn_global_load_lds(
        (const __attribute__((address_space(1))) void*)g,
        (__attribute__((address_space(3))) void*)l, 16, 0, 0);
}

template<int EPI>
__device__ inline float epilogue(float c, float b, float scale) {
    if (EPI == EP_BIAS)  return c + b;
    if (EPI == EP_ELU1)  return c > 0.f ? c + 1.f : expf(c);   // elu(c)+1
    if (EPI == EP_SCALE) return c * scale;
    if (EPI == EP_RELU)  return fmaxf(c, 0.f);
    return c;
}

// XCD-chunked bijective swizzle (nwg % 8 == 0 for all our grids)
__device__ inline int xcd_swz(int lid, int nwg) {
    return (lid & 7) * (nwg >> 3) + (lid >> 3);
}

// x fp32 -> bf16 (vector)
__global__ __launch_bounds__(256) void cast_bf16(
    const float* __restrict__ in, short* __restrict__ ob, int n4)
{
    int i = blockIdx.x * 256 + threadIdx.x;
    int stride = gridDim.x * 256;
    for (; i < n4; i += stride) {
        float4 v = reinterpret_cast<const float4*>(in)[i];
        short4 s;
        s.x = f2bf(v.x); s.y = f2bf(v.y); s.z = f2bf(v.z); s.w = f2bf(v.w);
        reinterpret_cast<short4*>(ob)[i] = s;
    }
}

// all weight transposes in one launch (3328 blocks)
__global__ __launch_bounds__(256) void prep_weights(
    const float* __restrict__ srw, const float* __restrict__ wq,
    const float* __restrict__ wk,  const float* __restrict__ wv,
    const float* __restrict__ w1,  const float* __restrict__ w2,
    short* __restrict__ Wct, short* __restrict__ Wqt, short* __restrict__ Wkt,
    short* __restrict__ Wvt, short* __restrict__ W1t, short* __restrict__ W2t)
{
    int bid = blockIdx.x, tid = threadIdx.x;
    if (bid < 1024) {                       // conv: [o][k=p*256+ci]
        int idx = bid * 256 + tid;
        int k = idx & 1023, o = idx >> 10;
        int p = k >> 8, ci = k & 255;
        Wct[idx] = f2bf(srw[(o << 10) + (ci << 2) + p]);
    } else if (bid < 1792) {                // wq/wk/wv: [n][k] 256x256
        int which = (bid - 1024) >> 8;
        int idx = ((bid - 1024) & 255) * 256 + tid;
        int n = idx >> 8, k = idx & 255;
        const float* W = which == 0 ? wq : (which == 1 ? wk : wv);
        short* Wt = which == 0 ? Wqt : (which == 1 ? Wkt : Wvt);
        Wt[idx] = f2bf(W[k * 256 + n]);
    } else if (bid < 2816) {                // mlp_w1: [n][k] 512x512
        int idx = (bid - 1792) * 256 + tid;
        int n = idx >> 9, k = idx & 511;
        W1t[idx] = f2bf(w1[k * 512 + n]);
    } else {                                // mlp_w2: [n][k] 256x512
        int idx = (bid - 2816) * 256 + tid;
        int n = idx >> 9, k = idx & 511;
        W2t[idx] = f2bf(w2[k * 256 + n]);
    }
}

// W2a[b][n][k=h*32+d] = sum_v KV[b,h,d,v] * wm[h*32+v, n]   (bf16 Bt form)
__global__ __launch_bounds__(256) void w2_prep(
    const float* __restrict__ KVb, const float* __restrict__ wm,
    short* __restrict__ W2a)
{
    int b = blockIdx.x >> 8, n = blockIdx.x & 255;
    int tid = threadIdx.x;                 // = k
    __shared__ float wcol[256];
    wcol[tid] = wm[tid * 256 + n];
    __syncthreads();
    int h = tid >> 5, d = tid & 31;
    const float* kv = &KVb[b * 8192 + h * 1024 + d * 32];
    float s = 0.f;
    #pragma unroll
    for (int v = 0; v < 32; v++) s = fmaf(kv[v], wcol[h * 32 + v], s);
    W2a[((size_t)(b * 256 + n) << 8) + tid] = f2bf(s);
}

// ---------------------------------------------------------------------------
// 128x128 staged bf16 GEMM core: swizzled gload_lds + ds_read
// ---------------------------------------------------------------------------
template<int GATHER, int BB>
__device__ inline void gemm_core(
    const short* __restrict__ Ab, const short* __restrict__ A2b,
    const short* __restrict__ Bt, int K, int bm, int bn,
    short* AlF, short* BlF, f32x4 acc[4][4])
{
    const int tid  = threadIdx.x;
    const int lane = tid & 63;
    const int wave = tid >> 6;
    const int wr   = (wave >> 1) * 64;
    const int wc   = (wave & 1) * 64;
    const int l15  = lane & 15;
    const int kg   = lane >> 4;
    const int srow = tid >> 3;
    const int sc   = tid & 7;

    if (BB) Bt += (size_t)(bm >> 14) << 16;

    for (int k0 = 0; k0 < K; k0 += 64) {
        __syncthreads();
        #pragma unroll
        for (int q = 0; q < 4; q++) {
            int row = q * 32 + srow;
            int cp  = sc ^ (row & 7);
            const short* ga;
            if (GATHER == GA_PLAIN) {
                ga = Ab + (size_t)(bm + row) * K + k0 + cp * 8;
            } else if (GATHER == GA_CONCAT) {
                const short* base = (k0 < 256) ? Ab : A2b;
                ga = base + ((size_t)(bm + row) << 8) + (k0 & 255) + cp * 8;
            } else { // GA_CONV
                int grow = bm + row;
                int b = grow >> 12, s = grow & 4095;
                int ii = s >> 6, jj = s & 63;
                int p = k0 >> 8;
                int kh = p >> 1, kw = p & 1;
                int pix = (b << 14) + ((2 * ii + kh) << 7) + (2 * jj + kw);
                ga = Ab + ((size_t)pix << 8) + (k0 & 255) + cp * 8;
            }
            gload16(ga, &AlF[(q * 256 + wave * 64) * 8]);
            const short* gb = Bt + (size_t)(bn + row) * K + k0 + cp * 8;
            gload16(gb, &BlF[(q * 256 + wave * 64) * 8]);
        }
        __syncthreads();

        #pragma unroll
        for (int ks = 0; ks < 2; ks++) {
            short8v afr[4], bfr[4];
            #pragma unroll
            for (int m = 0; m < 4; m++) {
                int R = wr + m * 16 + l15;
                afr[m] = *reinterpret_cast<const short8v*>(
                    &AlF[R * 64 + (((ks * 4 + kg) ^ (R & 7)) * 8)]);
            }
            #pragma unroll
            for (int n = 0; n < 4; n++) {
                int R = wc + n * 16 + l15;
                bfr[n] = *reinterpret_cast<const short8v*>(
                    &BlF[R * 64 + (((ks * 4 + kg) ^ (R & 7)) * 8)]);
            }
            #pragma unroll
            for (int m = 0; m < 4; m++)
                #pragma unroll
                for (int n = 0; n < 4; n++)
                    acc[m][n] = __builtin_amdgcn_mfma_f32_16x16x32_bf16(
                        afr[m], bfr[n], acc[m][n], 0, 0, 0);
        }
    }
}

// generic 128x128 GEMM, bf16 output, XCD-swizzled block order (cols fastest)
template<int GATHER, int EPI, int BB>
__global__ __launch_bounds__(256) void gemm_bf16(
    const short* __restrict__ Ab, const short* __restrict__ A2b,
    const short* __restrict__ Bt, const float* __restrict__ bias,
    short* __restrict__ Cb, int N, int K, float scale)
{
    __shared__ short AlF[8192];
    __shared__ short BlF[8192];
    const int nwg = gridDim.x * gridDim.y;
    const int lid = blockIdx.y * gridDim.x + blockIdx.x;
    const int swz = xcd_swz(lid, nwg);
    const int bn  = (swz % gridDim.x) * 128;   // col = fast index
    const int bm  = (swz / gridDim.x) * 128;
    f32x4 acc[4][4];
    #pragma unroll
    for (int m = 0; m < 4; m++)
        #pragma unroll
        for (int n = 0; n < 4; n++)
            acc[m][n] = (f32x4){0.f, 0.f, 0.f, 0.f};

    gemm_core<GATHER, BB>(Ab, A2b, Bt, K, bm, bn, AlF, BlF, acc);

    const int lane = threadIdx.x & 63;
    const int wave = threadIdx.x >> 6;
    const int wr = (wave >> 1) * 64, wc = (wave & 1) * 64;
    const int l15 = lane & 15, r0 = (lane >> 4) * 4;
    #pragma unroll
    for (int n = 0; n < 4; n++) {
        int col = bn + wc + n * 16 + l15;
        float bb = (EPI == EP_BIAS) ? bias[col] : 0.f;
        #pragma unroll
        for (int m = 0; m < 4; m++) {
            int rowb = bm + wr + m * 16 + r0;
            #pragma unroll
            for (int j = 0; j < 4; j++) {
                float c = acc[m][n][j];
                float o;
                if (EPI == EP_KV)
                    o = (bn < 256) ? (c > 0.f ? c + 1.f : expf(c)) : c * scale;
                else
                    o = epilogue<EPI>(c, bb, scale);
                Cb[(size_t)(rowb + j) * N + col] = f2bf(o);
            }
        }
    }
}

// ---------------------------------------------------------------------------
// gemm_ln v3: 512 threads, BM=128, BN=256 (full row), 8 waves (2 row x 4 col),
// each wave 64x64 -> acc[4][4].  LDS: Al 16KB + Bl 32KB + red 4KB = 52KB.
//   FIN=0: out bf16 = LN(acc)                  (QzW2a -> msg_ln)
//   FIN=1: out f32  = LN(acc) + bf2f(res16)    (mlp2  -> final out)
// ---------------------------------------------------------------------------
template<int BB, int FIN>
__global__ __launch_bounds__(512) void gemm_ln(
    const short* __restrict__ Ab, const short* __restrict__ Bt,
    const float* __restrict__ g, const float* __restrict__ bv,
    const short* __restrict__ res16, void* __restrict__ Co, int K)
{
    __shared__ short Al[8192];      // [128][64]
    __shared__ short Bl[16384];     // [256][64]
    __shared__ float redS[4][128], redQ[4][128];
    const int tid  = threadIdx.x;
    const int lane = tid & 63;
    const int wave = tid >> 6;          // 0..7
    const int wr   = (wave >> 2) * 64;  // row half
    const int wc   = wave & 3;          // col quarter
    const int l15  = lane & 15;
    const int kg   = lane >> 4;
    const int srow = tid >> 3;          // 0..63
    const int sc   = tid & 7;
    const int bm   = blockIdx.x * 128;
    const short* Bp = BB ? Bt + ((size_t)(bm >> 14) << 16) : Bt;

    f32x4 acc[4][4];
    #pragma unroll
    for (int m = 0; m < 4; m++)
        #pragma unroll
        for (int n = 0; n < 4; n++)
            acc[m][n] = (f32x4){0.f, 0.f, 0.f, 0.f};

    for (int k0 = 0; k0 < K; k0 += 64) {
        __syncthreads();
        #pragma unroll
        for (int q = 0; q < 2; q++) {       // A: 128 rows
            int row = q * 64 + srow;
            int cp  = sc ^ (row & 7);
            gload16(Ab + (size_t)(bm + row) * K + k0 + cp * 8,
                    &Al[(q * 512 + wave * 64) * 8]);
        }
        #pragma unroll
        for (int q = 0; q < 4; q++) {       // B: 256 rows
            int row = q * 64 + srow;
            int cp  = sc ^ (row & 7);
            gload16(Bp + (size_t)row * K + k0 + cp * 8,
                    &Bl[(q * 512 + wave * 64) * 8]);
        }
        __syncthreads();

        #pragma unroll
        for (int ks = 0; ks < 2; ks++) {
            short8v afr[4], bfr[4];
            #pragma unroll
            for (int m = 0; m < 4; m++) {
                int R = wr + m * 16 + l15;
                afr[m] = *reinterpret_cast<const short8v*>(
                    &Al[R * 64 + (((ks * 4 + kg) ^ (R & 7)) * 8)]);
            }
            #pragma unroll
            for (int n = 0; n < 4; n++) {
                int R = wc * 64 + n * 16 + l15;
                bfr[n] = *reinterpret_cast<const short8v*>(
                    &Bl[R * 64 + (((ks * 4 + kg) ^ (R & 7)) * 8)]);
            }
            #pragma unroll
            for (int m = 0; m < 4; m++)
                #pragma unroll
                for (int n = 0; n < 4; n++)
                    acc[m][n] = __builtin_amdgcn_mfma_f32_16x16x32_bf16(
                        afr[m], bfr[n], acc[m][n], 0, 0, 0);
        }
    }

    // ---- fused LayerNorm epilogue ----
    #pragma unroll
    for (int m = 0; m < 4; m++)
        #pragma unroll
        for (int j = 0; j < 4; j++) {
            float s1 = 0.f, s2 = 0.f;
            #pragma unroll
            for (int n = 0; n < 4; n++) {
                float v = acc[m][n][j];
                s1 += v; s2 += v * v;
            }
            s1 += __shfl_xor(s1, 1, 64); s2 += __shfl_xor(s2, 1, 64);
            s1 += __shfl_xor(s1, 2, 64); s2 += __shfl_xor(s2, 2, 64);
            s1 += __shfl_xor(s1, 4, 64); s2 += __shfl_xor(s2, 4, 64);
            s1 += __shfl_xor(s1, 8, 64); s2 += __shfl_xor(s2, 8, 64);
            if (l15 == 0) {
                int row = wr + m * 16 + kg * 4 + j;
                redS[wc][row] = s1;
                redQ[wc][row] = s2;
            }
        }
    __syncthreads();

    float gc[4], bc[4];
    #pragma unroll
    for (int n = 0; n < 4; n++) {
        int col = wc * 64 + n * 16 + l15;
        gc[n] = g[col]; bc[n] = bv[col];
    }
    #pragma unroll
    for (int m = 0; m < 4; m++)
        #pragma unroll
        for (int j = 0; j < 4; j++) {
            int row = wr + m * 16 + kg * 4 + j;
            float mean = (redS[0][row] + redS[1][row] +
                          redS[2][row] + redS[3][row]) * (1.f / 256.f);
            float var  = (redQ[0][row] + redQ[1][row] +
                          redQ[2][row] + redQ[3][row]) * (1.f / 256.f)
                         - mean * mean;
            float inv  = rsqrtf(var + 1e-5f);
            #pragma unroll
            for (int n = 0; n < 4; n++) {
                int col = wc * 64 + n * 16 + l15;
                float o = (acc[m][n][j] - mean) * inv * gc[n] + bc[n];
                size_t gi = (size_t)(bm + row) * 256 + col;
                if (FIN) ((float*)Co)[gi] = o + bf2f(res16[gi]);
                else     ((short*)Co)[gi] = f2bf(o);
            }
        }
}

// Q GEMM with fused attention-Z epilogue -> Qz bf16 (XCD-swizzled)
__global__ __launch_bounds__(256) void gemm_qz(
    const short* __restrict__ Ab, const short* __restrict__ Bt,
    const float* __restrict__ Ksb, short* __restrict__ Qz)
{
    __shared__ short AlF[8192];
    __shared__ short BlF[8192];
    const int nwg = gridDim.x * gridDim.y;
    const int lid = blockIdx.y * gridDim.x + blockIdx.x;
    const int swz = xcd_swz(lid, nwg);
    const int bn  = (swz % gridDim.x) * 128;
    const int bm  = (swz / gridDim.x) * 128;
    f32x4 acc[4][4];
    #pragma unroll
    for (int m = 0; m < 4; m++)
        #pragma unroll
        for (int n = 0; n < 4; n++)
            acc[m][n] = (f32x4){0.f, 0.f, 0.f, 0.f};

    gemm_core<GA_PLAIN, 0>(Ab, nullptr, Bt, 256, bm, bn, AlF, BlF, acc);

    const int lane = threadIdx.x & 63;
    const int wave = threadIdx.x >> 6;
    const int wr = (wave >> 1) * 64, wc = (wave & 1) * 64;
    const int l15 = lane & 15;
    const int b = bm >> 14;
    float Ksf[4];
    #pragma unroll
    for (int n = 0; n < 4; n++)
        Ksf[n] = Ksb[b * 256 + bn + wc + n * 16 + l15];
    #pragma unroll
    for (int m = 0; m < 4; m++)
        #pragma unroll
        for (int n = 0; n < 4; n++)
            #pragma unroll
            for (int j = 0; j < 4; j++) {
                float c = acc[m][n][j];
                acc[m][n][j] = c > 0.f ? c + 1.f : expf(c);   // elu+1
            }
    #pragma unroll
    for (int hh = 0; hh < 2; hh++) {
        #pragma unroll
        for (int m = 0; m < 4; m++)
            #pragma unroll
            for (int j = 0; j < 4; j++) {
                float part = acc[m][2 * hh][j] * Ksf[2 * hh]
                           + acc[m][2 * hh + 1][j] * Ksf[2 * hh + 1];
                part += __shfl_xor(part, 1, 64);
                part += __shfl_xor(part, 2, 64);
                part += __shfl_xor(part, 4, 64);
                part += __shfl_xor(part, 8, 64);
                float z = 4096.f / (part + 1e-6f);
                acc[m][2 * hh][j]     *= z;
                acc[m][2 * hh + 1][j] *= z;
            }
    }
    const int r0 = (lane >> 4) * 4;
    #pragma unroll
    for (int n = 0; n < 4; n++) {
        int col = bn + wc + n * 16 + l15;
        #pragma unroll
        for (int m = 0; m < 4; m++) {
            int rowb = bm + wr + m * 16 + r0;
            #pragma unroll
            for (int j = 0; j < 4; j++)
                Qz[(size_t)(rowb + j) * 256 + col] = f2bf(acc[m][n][j]);
        }
    }
}

// LayerNorm: 1 row (C=256) per wave (bf16 in/out) — conv-LN only
__global__ __launch_bounds__(256) void ln_bf16(
    const short* __restrict__ in, const float* __restrict__ g,
    const float* __restrict__ bta, short* __restrict__ out)
{
    const int wave = threadIdx.x >> 6, lane = threadIdx.x & 63;
    const size_t row = (size_t)blockIdx.x * 4 + wave;
    short4 s = reinterpret_cast<const short4*>(in)[row * 64 + lane];
    float v[4] = {bf2f(s.x), bf2f(s.y), bf2f(s.z), bf2f(s.w)};
    float s1 = v[0] + v[1] + v[2] + v[3];
    float s2 = v[0]*v[0] + v[1]*v[1] + v[2]*v[2] + v[3]*v[3];
    #pragma unroll
    for (int off = 1; off < 64; off <<= 1) {
        s1 += __shfl_xor(s1, off, 64);
        s2 += __shfl_xor(s2, off, 64);
    }
    float mean = s1 * (1.f / 256.f);
    float var  = s2 * (1.f / 256.f) - mean * mean;
    float inv  = rsqrtf(var + 1e-5f);
    float4 gg = reinterpret_cast<const float4*>(g)[lane];
    float4 bb = reinterpret_cast<const float4*>(bta)[lane];
    short4 o;
    o.x = f2bf((v[0] - mean) * inv * gg.x + bb.x);
    o.y = f2bf((v[1] - mean) * inv * gg.y + bb.y);
    o.z = f2bf((v[2] - mean) * inv * gg.z + bb.z);
    o.w = f2bf((v[3] - mean) * inv * gg.w + bb.w);
    reinterpret_cast<short4*>(out)[row * 64 + lane] = o;
}

// partial KV over a 128-row s-chunk; KVm fused [row][512]: K cols 0..255,
// V cols 256..511
__global__ __launch_bounds__(256) void kv_partial(
    const short* __restrict__ KVm,
    float* __restrict__ pKV, float* __restrict__ pKs)
{
    int blk = blockIdx.x;
    int bh = blk >> 5, chunk = blk & 31;
    int b = bh >> 3, h = bh & 7;
    int tid = threadIdx.x;
    int e = tid & 31, dq = tid >> 5;
    int d_l = tid & 31, r_l = tid >> 5;
    __shared__ float Ks[16][32], Vs[16][32];
    float acc[4] = {0.f, 0.f, 0.f, 0.f};
    float ks = 0.f;
    const size_t base = ((size_t)b * 4096 + chunk * 128) * 512 + h * 32;

    for (int s0 = 0; s0 < 128; s0 += 16) {
        Ks[r_l][d_l]     = bf2f(KVm[base + (size_t)(s0 + r_l) * 512 + d_l]);
        Ks[r_l + 8][d_l] = bf2f(KVm[base + (size_t)(s0 + r_l + 8) * 512 + d_l]);
        Vs[r_l][d_l]     = bf2f(KVm[base + (size_t)(s0 + r_l) * 512 + 256 + d_l]);
        Vs[r_l + 8][d_l] = bf2f(KVm[base + (size_t)(s0 + r_l + 8) * 512 + 256 + d_l]);
        __syncthreads();
        #pragma unroll
        for (int sr = 0; sr < 16; sr++) {
            float vv = Vs[sr][e];
            #pragma unroll
            for (int i = 0; i < 4; i++)
                acc[i] = fmaf(Ks[sr][dq * 4 + i], vv, acc[i]);
        }
        if (tid < 32) {
            #pragma unroll
            for (int sr = 0; sr < 16; sr++) ks += Ks[sr][tid];
        }
        __syncthreads();
    }
    #pragma unroll
    for (int i = 0; i < 4; i++)
        pKV[(size_t)blk * 1024 + (dq * 4 + i) * 32 + e] = acc[i];
    if (tid < 32) pKs[blk * 32 + tid] = ks;
}

// reduce 32 chunks -> KV[bh][1024], Ksum[bh][32]
__global__ __launch_bounds__(256) void kv_reduce(
    const float* __restrict__ pKV, const float* __restrict__ pKs,
    float* __restrict__ KV, float* __restrict__ Ksum)
{
    int bh = blockIdx.x;
    int tid = threadIdx.x;
    float s0 = 0.f, s1 = 0.f, s2 = 0.f, s3 = 0.f;
    for (int c = 0; c < 32; c++) {
        const float* p = &pKV[(size_t)(bh * 32 + c) * 1024];
        s0 += p[tid]; s1 += p[tid + 256]; s2 += p[tid + 512]; s3 += p[tid + 768];
    }
    KV[bh * 1024 + tid]       = s0;
    KV[bh * 1024 + tid + 256] = s1;
    KV[bh * 1024 + tid + 512] = s2;
    KV[bh * 1024 + tid + 768] = s3;
    if (tid < 32) {
        float s = 0.f;
        for (int c = 0; c < 32; c++) s += pKs[(bh * 32 + c) * 32 + tid];
        Ksum[bh * 32 + tid] = s;
    }
}

extern "C" void kernel_launch(void* const* d_in, const int* in_sizes, int n_in,
                              void* d_out, int out_size, void* d_ws, size_t ws_size,
                              hipStream_t stream) {
    const float* x      = (const float*)d_in[0];
    const float* sr_w   = (const float*)d_in[1];
    const float* sr_b   = (const float*)d_in[2];
    const float* norm_g = (const float*)d_in[3];
    const float* norm_b = (const float*)d_in[4];
    const float* wq     = (const float*)d_in[5];
    const float* wk     = (const float*)d_in[6];
    const float* wv     = (const float*)d_in[7];
    const float* wm     = (const float*)d_in[8];
    const float* mlp_w1 = (const float*)d_in[9];
    const float* mlp_w2 = (const float*)d_in[10];
    const float* n1_g   = (const float*)d_in[11];
    const float* n1_b   = (const float*)d_in[12];
    const float* n2_g   = (const float*)d_in[13];
    const float* n2_b   = (const float*)d_in[14];
    float* out = (float*)d_out;

    // ---- workspace layout (~141 MB of ~256 MiB) ----
    short* Wct = (short*)d_ws;          // [256][1024]
    short* Wqt = Wct + 262144;          // [256][256]
    short* Wkt = Wqt + 65536;           // [256][256]  \ contiguous = [512][256]
    short* Wvt = Wkt + 65536;           // [256][256]  /
    short* W1t = Wvt + 65536;           // [512][512]
    short* W2t = W1t + 262144;          // [256][512]
    short* W2a = W2t + 131072;          // [4][256][256]
    float* KVb = (float*)(W2a + 262144);// 32768 f
    float* Ksb = KVb + 32768;           // 1024 f
    float* pKs = Ksb + 1024;            // 32768 f
    float* pKV = pKs + 32768;           // 1048576 f
    short* xb16 = (short*)(pKV + 1048576);   // [65536][256] 32MB
    short* SCR  = xb16 + 16777216;           // 32MB scratch:
    short* xs16 = SCR;                  //   [16384][256] 8MB
    short* KVm  = SCR + 4194304;        //   [16384][512] 16MB fused K|V
    short* Qz   = SCR;                  // ALIAS 32MB (xs/KVm dead)
    short* Hc   = SCR + 16777216;       // [65536][512] 64MB
    short* Mb16 = (short*)d_out;        // msg_ln bf16 in d_out (overwritten)

    const float inv_S = 1.f / 4096.f;

    // prep: weights + x cast
    prep_weights<<<3328, 256, 0, stream>>>(
        sr_w, wq, wk, wv, mlp_w1, mlp_w2, Wct, Wqt, Wkt, Wvt, W1t, W2t);
    cast_bf16<<<2048, 256, 0, stream>>>(x, xb16, 4194304);

    // conv as GEMM + bias -> xs16; LN in place
    gemm_bf16<GA_CONV, EP_BIAS, 0><<<dim3(2, 128), 256, 0, stream>>>(
        xb16, nullptr, Wct, sr_b, xs16, 256, 1024, 0.f);
    ln_bf16<<<4096, 256, 0, stream>>>(xs16, norm_g, norm_b, xs16);

    // fused K|V GEMM: B = Wkt||Wvt [512][256]
    gemm_bf16<GA_PLAIN, EP_KV, 0><<<dim3(4, 128), 256, 0, stream>>>(
        xs16, nullptr, Wkt, nullptr, KVm, 512, 256, inv_S);

    // KV + Ksum, fold KV@wm -> W2a
    kv_partial<<<1024, 256, 0, stream>>>(KVm, pKV, pKs);
    kv_reduce<<<32, 256, 0, stream>>>(pKV, pKs, KVb, Ksb);
    w2_prep<<<1024, 256, 0, stream>>>(KVb, wm, W2a);

    // Qz = Z .* (elu(x@wq)+1)  [bf16] (aliases dead xs/KVm)
    gemm_qz<<<dim3(2, 512), 256, 0, stream>>>(xb16, Wqt, Ksb, Qz);

    // msg_ln = LN1(Qz @ W2a[b]) -> Mb16 (bf16, in d_out)  [fused, 512 thr]
    gemm_ln<1, 0><<<512, 512, 0, stream>>>(
        Qz, W2a, n1_g, n1_b, nullptr, Mb16, 256);

    // h = relu([x|msg_ln] @ w1) -> Hc  (XCD-swizzled A-panel reuse)
    gemm_bf16<GA_CONCAT, EP_RELU, 0><<<dim3(4, 512), 256, 0, stream>>>(
        xb16, Mb16, W1t, nullptr, Hc, 512, 512, 0.f);

    // out = LN2(h @ w2) + x  (fused; residual read bf16; 512 thr)
    gemm_ln<0, 1><<<512, 512, 0, stream>>>(
        Hc, W2t, n2_g, n2_b, xb16, out, 512);
}

// Round 14
// 238.079 us; speedup vs baseline: 6.5992x; 1.0033x over previous
//
#include <hip/hip_runtime.h>
#include <math.h>

// ---------------------------------------------------------------------------
// GlobalSubSampleAttn round 13 (resubmit — round-13 bench died on infra):
//  - gemm_core v2: BM=256 x BN=128, 512 threads (8 waves, 4 row x 2 col),
//    acc[4][4]/wave, LDS 48KB.  Per-thread staging 8 -> 6 gload16/K-step
//    (B panel amortized over 2x rows); per-block MFMA doubles.
//    (round 12: mlp1 698 TF, MfmaUtil 28%, VALUBusy 45% = staging-issue bound)
//  - grids: conv(2,64) KV(4,64) qz(2,256) mlp1(4,256); bm = swz/gx*256
//  - gemm_ln / kv chain / prep unchanged from round 12 (238.9 us)
// B=4, N=16384, C=256, S=4096, NHEAD=8, D=32
// ---------------------------------------------------------------------------

#define EP_NONE  0
#define EP_BIAS  1
#define EP_ELU1  2
#define EP_SCALE 3
#define EP_RELU  4
#define EP_KV    5

#define GA_PLAIN  0
#define GA_CONV   1
#define GA_CONCAT 2

typedef __attribute__((ext_vector_type(8))) short short8v;   // 8 bf16
typedef __attribute__((ext_vector_type(4))) float f32x4;

__device__ inline short f2bf(float f) {
    unsigned u = __float_as_uint(f);
    u += 0x7FFFu + ((u >> 16) & 1u);      // round-to-nearest-even
    return (short)(u >> 16);
}
__device__ inline float bf2f(short s) {
    return __uint_as_float(((unsigned)(unsigned short)s) << 16);
}

__device__ inline void gload16(const void* g, void* l) {
    __builtin_amdgcn_global_load_lds(
        (const __attribute__((address_space(1))) void*)g,
        (__attribute__((address_space(3))) void*)l, 16, 0, 0);
}

template<int EPI>
__device__ inline float epilogue(float c, float b, float scale) {
    if (EPI == EP_BIAS)  return c + b;
    if (EPI == EP_ELU1)  return c > 0.f ? c + 1.f : expf(c);   // elu(c)+1
    if (EPI == EP_SCALE) return c * scale;
    if (EPI == EP_RELU)  return fmaxf(c, 0.f);
    return c;
}

// XCD-chunked bijective swizzle (nwg % 8 == 0 for all our grids)
__device__ inline int xcd_swz(int lid, int nwg) {
    return (lid & 7) * (nwg >> 3) + (lid >> 3);
}

// x fp32 -> bf16 (vector)
__global__ __launch_bounds__(256) void cast_bf16(
    const float* __restrict__ in, short* __restrict__ ob, int n4)
{
    int i = blockIdx.x * 256 + threadIdx.x;
    int stride = gridDim.x * 256;
    for (; i < n4; i += stride) {
        float4 v = reinterpret_cast<const float4*>(in)[i];
        short4 s;
        s.x = f2bf(v.x); s.y = f2bf(v.y); s.z = f2bf(v.z); s.w = f2bf(v.w);
        reinterpret_cast<short4*>(ob)[i] = s;
    }
}

// all weight transposes in one launch (3328 blocks)
__global__ __launch_bounds__(256) void prep_weights(
    const float* __restrict__ srw, const float* __restrict__ wq,
    const float* __restrict__ wk,  const float* __restrict__ wv,
    const float* __restrict__ w1,  const float* __restrict__ w2,
    short* __restrict__ Wct, short* __restrict__ Wqt, short* __restrict__ Wkt,
    short* __restrict__ Wvt, short* __restrict__ W1t, short* __restrict__ W2t)
{
    int bid = blockIdx.x, tid = threadIdx.x;
    if (bid < 1024) {                       // conv: [o][k=p*256+ci]
        int idx = bid * 256 + tid;
        int k = idx & 1023, o = idx >> 10;
        int p = k >> 8, ci = k & 255;
        Wct[idx] = f2bf(srw[(o << 10) + (ci << 2) + p]);
    } else if (bid < 1792) {                // wq/wk/wv: [n][k] 256x256
        int which = (bid - 1024) >> 8;
        int idx = ((bid - 1024) & 255) * 256 + tid;
        int n = idx >> 8, k = idx & 255;
        const float* W = which == 0 ? wq : (which == 1 ? wk : wv);
        short* Wt = which == 0 ? Wqt : (which == 1 ? Wkt : Wvt);
        Wt[idx] = f2bf(W[k * 256 + n]);
    } else if (bid < 2816) {                // mlp_w1: [n][k] 512x512
        int idx = (bid - 1792) * 256 + tid;
        int n = idx >> 9, k = idx & 511;
        W1t[idx] = f2bf(w1[k * 512 + n]);
    } else {                                // mlp_w2: [n][k] 256x512
        int idx = (bid - 2816) * 256 + tid;
        int n = idx >> 9, k = idx & 511;
        W2t[idx] = f2bf(w2[k * 256 + n]);
    }
}

// W2a[b][n][k=h*32+d] = sum_v KV[b,h,d,v] * wm[h*32+v, n]   (bf16 Bt form)
__global__ __launch_bounds__(256) void w2_prep(
    const float* __restrict__ KVb, const float* __restrict__ wm,
    short* __restrict__ W2a)
{
    int b = blockIdx.x >> 8, n = blockIdx.x & 255;
    int tid = threadIdx.x;                 // = k
    __shared__ float wcol[256];
    wcol[tid] = wm[tid * 256 + n];
    __syncthreads();
    int h = tid >> 5, d = tid & 31;
    const float* kv = &KVb[b * 8192 + h * 1024 + d * 32];
    float s = 0.f;
    #pragma unroll
    for (int v = 0; v < 32; v++) s = fmaf(kv[v], wcol[h * 32 + v], s);
    W2a[((size_t)(b * 256 + n) << 8) + tid] = f2bf(s);
}

// ---------------------------------------------------------------------------
// gemm_core v2: 512 threads, BM=256 x BN=128, 8 waves (4 row x 2 col).
// LDS: A [256][64] 32KB + B [128][64] 16KB.  Swizzled gload_lds + ds_read.
// ---------------------------------------------------------------------------
template<int GATHER, int BB>
__device__ inline void gemm_core(
    const short* __restrict__ Ab, const short* __restrict__ A2b,
    const short* __restrict__ Bt, int K, int bm, int bn,
    short* AlF, short* BlF, f32x4 acc[4][4])
{
    const int tid  = threadIdx.x;          // 0..511
    const int lane = tid & 63;
    const int wave = tid >> 6;             // 0..7
    const int wr   = (wave >> 1) * 64;     // 0,64,128,192
    const int wc   = (wave & 1) * 64;      // 0,64
    const int l15  = lane & 15;
    const int kg   = lane >> 4;
    const int srow = tid >> 3;             // 0..63
    const int sc   = tid & 7;

    if (BB) Bt += (size_t)(bm >> 14) << 16;

    for (int k0 = 0; k0 < K; k0 += 64) {
        __syncthreads();
        #pragma unroll
        for (int q = 0; q < 4; q++) {      // A: 256 rows
            int row = q * 64 + srow;
            int cp  = sc ^ (row & 7);
            const short* ga;
            if (GATHER == GA_PLAIN) {
                ga = Ab + (size_t)(bm + row) * K + k0 + cp * 8;
            } else if (GATHER == GA_CONCAT) {
                const short* base = (k0 < 256) ? Ab : A2b;
                ga = base + ((size_t)(bm + row) << 8) + (k0 & 255) + cp * 8;
            } else { // GA_CONV
                int grow = bm + row;
                int b = grow >> 12, s = grow & 4095;
                int ii = s >> 6, jj = s & 63;
                int p = k0 >> 8;
                int kh = p >> 1, kw = p & 1;
                int pix = (b << 14) + ((2 * ii + kh) << 7) + (2 * jj + kw);
                ga = Ab + ((size_t)pix << 8) + (k0 & 255) + cp * 8;
            }
            gload16(ga, &AlF[(q * 512 + wave * 64) * 8]);
        }
        #pragma unroll
        for (int q = 0; q < 2; q++) {      // B: 128 rows
            int row = q * 64 + srow;
            int cp  = sc ^ (row & 7);
            const short* gb = Bt + (size_t)(bn + row) * K + k0 + cp * 8;
            gload16(gb, &BlF[(q * 512 + wave * 64) * 8]);
        }
        __syncthreads();

        #pragma unroll
        for (int ks = 0; ks < 2; ks++) {
            short8v afr[4], bfr[4];
            #pragma unroll
            for (int m = 0; m < 4; m++) {
                int R = wr + m * 16 + l15;
                afr[m] = *reinterpret_cast<const short8v*>(
                    &AlF[R * 64 + (((ks * 4 + kg) ^ (R & 7)) * 8)]);
            }
            #pragma unroll
            for (int n = 0; n < 4; n++) {
                int R = wc + n * 16 + l15;
                bfr[n] = *reinterpret_cast<const short8v*>(
                    &BlF[R * 64 + (((ks * 4 + kg) ^ (R & 7)) * 8)]);
            }
            #pragma unroll
            for (int m = 0; m < 4; m++)
                #pragma unroll
                for (int n = 0; n < 4; n++)
                    acc[m][n] = __builtin_amdgcn_mfma_f32_16x16x32_bf16(
                        afr[m], bfr[n], acc[m][n], 0, 0, 0);
        }
    }
}

// generic 256x128 GEMM, bf16 output, XCD-swizzled block order (cols fastest)
template<int GATHER, int EPI, int BB>
__global__ __launch_bounds__(512) void gemm_bf16(
    const short* __restrict__ Ab, const short* __restrict__ A2b,
    const short* __restrict__ Bt, const float* __restrict__ bias,
    short* __restrict__ Cb, int N, int K, float scale)
{
    __shared__ short AlF[16384];   // [256][64]
    __shared__ short BlF[8192];    // [128][64]
    const int nwg = gridDim.x * gridDim.y;
    const int lid = blockIdx.y * gridDim.x + blockIdx.x;
    const int swz = xcd_swz(lid, nwg);
    const int bn  = (swz % gridDim.x) * 128;   // col = fast index
    const int bm  = (swz / gridDim.x) * 256;
    f32x4 acc[4][4];
    #pragma unroll
    for (int m = 0; m < 4; m++)
        #pragma unroll
        for (int n = 0; n < 4; n++)
            acc[m][n] = (f32x4){0.f, 0.f, 0.f, 0.f};

    gemm_core<GATHER, BB>(Ab, A2b, Bt, K, bm, bn, AlF, BlF, acc);

    const int lane = threadIdx.x & 63;
    const int wave = threadIdx.x >> 6;
    const int wr = (wave >> 1) * 64, wc = (wave & 1) * 64;
    const int l15 = lane & 15, r0 = (lane >> 4) * 4;
    #pragma unroll
    for (int n = 0; n < 4; n++) {
        int col = bn + wc + n * 16 + l15;
        float bb = (EPI == EP_BIAS) ? bias[col] : 0.f;
        #pragma unroll
        for (int m = 0; m < 4; m++) {
            int rowb = bm + wr + m * 16 + r0;
            #pragma unroll
            for (int j = 0; j < 4; j++) {
                float c = acc[m][n][j];
                float o;
                if (EPI == EP_KV)
                    o = (bn < 256) ? (c > 0.f ? c + 1.f : expf(c)) : c * scale;
                else
                    o = epilogue<EPI>(c, bb, scale);
                Cb[(size_t)(rowb + j) * N + col] = f2bf(o);
            }
        }
    }
}

// ---------------------------------------------------------------------------
// gemm_ln v3 (unchanged): 512 threads, BM=128, BN=256, 8 waves (2 row x 4 col)
//   FIN=0: out bf16 = LN(acc)                  (QzW2a -> msg_ln)
//   FIN=1: out f32  = LN(acc) + bf2f(res16)    (mlp2  -> final out)
// ---------------------------------------------------------------------------
template<int BB, int FIN>
__global__ __launch_bounds__(512) void gemm_ln(
    const short* __restrict__ Ab, const short* __restrict__ Bt,
    const float* __restrict__ g, const float* __restrict__ bv,
    const short* __restrict__ res16, void* __restrict__ Co, int K)
{
    __shared__ short Al[8192];      // [128][64]
    __shared__ short Bl[16384];     // [256][64]
    __shared__ float redS[4][128], redQ[4][128];
    const int tid  = threadIdx.x;
    const int lane = tid & 63;
    const int wave = tid >> 6;          // 0..7
    const int wr   = (wave >> 2) * 64;  // row half
    const int wc   = wave & 3;          // col quarter
    const int l15  = lane & 15;
    const int kg   = lane >> 4;
    const int srow = tid >> 3;          // 0..63
    const int sc   = tid & 7;
    const int bm   = blockIdx.x * 128;
    const short* Bp = BB ? Bt + ((size_t)(bm >> 14) << 16) : Bt;

    f32x4 acc[4][4];
    #pragma unroll
    for (int m = 0; m < 4; m++)
        #pragma unroll
        for (int n = 0; n < 4; n++)
            acc[m][n] = (f32x4){0.f, 0.f, 0.f, 0.f};

    for (int k0 = 0; k0 < K; k0 += 64) {
        __syncthreads();
        #pragma unroll
        for (int q = 0; q < 2; q++) {       // A: 128 rows
            int row = q * 64 + srow;
            int cp  = sc ^ (row & 7);
            gload16(Ab + (size_t)(bm + row) * K + k0 + cp * 8,
                    &Al[(q * 512 + wave * 64) * 8]);
        }
        #pragma unroll
        for (int q = 0; q < 4; q++) {       // B: 256 rows
            int row = q * 64 + srow;
            int cp  = sc ^ (row & 7);
            gload16(Bp + (size_t)row * K + k0 + cp * 8,
                    &Bl[(q * 512 + wave * 64) * 8]);
        }
        __syncthreads();

        #pragma unroll
        for (int ks = 0; ks < 2; ks++) {
            short8v afr[4], bfr[4];
            #pragma unroll
            for (int m = 0; m < 4; m++) {
                int R = wr + m * 16 + l15;
                afr[m] = *reinterpret_cast<const short8v*>(
                    &Al[R * 64 + (((ks * 4 + kg) ^ (R & 7)) * 8)]);
            }
            #pragma unroll
            for (int n = 0; n < 4; n++) {
                int R = wc * 64 + n * 16 + l15;
                bfr[n] = *reinterpret_cast<const short8v*>(
                    &Bl[R * 64 + (((ks * 4 + kg) ^ (R & 7)) * 8)]);
            }
            #pragma unroll
            for (int m = 0; m < 4; m++)
                #pragma unroll
                for (int n = 0; n < 4; n++)
                    acc[m][n] = __builtin_amdgcn_mfma_f32_16x16x32_bf16(
                        afr[m], bfr[n], acc[m][n], 0, 0, 0);
        }
    }

    // ---- fused LayerNorm epilogue ----
    #pragma unroll
    for (int m = 0; m < 4; m++)
        #pragma unroll
        for (int j = 0; j < 4; j++) {
            float s1 = 0.f, s2 = 0.f;
            #pragma unroll
            for (int n = 0; n < 4; n++) {
                float v = acc[m][n][j];
                s1 += v; s2 += v * v;
            }
            s1 += __shfl_xor(s1, 1, 64); s2 += __shfl_xor(s2, 1, 64);
            s1 += __shfl_xor(s1, 2, 64); s2 += __shfl_xor(s2, 2, 64);
            s1 += __shfl_xor(s1, 4, 64); s2 += __shfl_xor(s2, 4, 64);
            s1 += __shfl_xor(s1, 8, 64); s2 += __shfl_xor(s2, 8, 64);
            if (l15 == 0) {
                int row = wr + m * 16 + kg * 4 + j;
                redS[wc][row] = s1;
                redQ[wc][row] = s2;
            }
        }
    __syncthreads();

    float gc[4], bc[4];
    #pragma unroll
    for (int n = 0; n < 4; n++) {
        int col = wc * 64 + n * 16 + l15;
        gc[n] = g[col]; bc[n] = bv[col];
    }
    #pragma unroll
    for (int m = 0; m < 4; m++)
        #pragma unroll
        for (int j = 0; j < 4; j++) {
            int row = wr + m * 16 + kg * 4 + j;
            float mean = (redS[0][row] + redS[1][row] +
                          redS[2][row] + redS[3][row]) * (1.f / 256.f);
            float var  = (redQ[0][row] + redQ[1][row] +
                          redQ[2][row] + redQ[3][row]) * (1.f / 256.f)
                         - mean * mean;
            float inv  = rsqrtf(var + 1e-5f);
            #pragma unroll
            for (int n = 0; n < 4; n++) {
                int col = wc * 64 + n * 16 + l15;
                float o = (acc[m][n][j] - mean) * inv * gc[n] + bc[n];
                size_t gi = (size_t)(bm + row) * 256 + col;
                if (FIN) ((float*)Co)[gi] = o + bf2f(res16[gi]);
                else     ((short*)Co)[gi] = f2bf(o);
            }
        }
}

// Q GEMM with fused attention-Z epilogue -> Qz bf16 (512 thr, 256x128 tile)
__global__ __launch_bounds__(512) void gemm_qz(
    const short* __restrict__ Ab, const short* __restrict__ Bt,
    const float* __restrict__ Ksb, short* __restrict__ Qz)
{
    __shared__ short AlF[16384];
    __shared__ short BlF[8192];
    const int nwg = gridDim.x * gridDim.y;
    const int lid = blockIdx.y * gridDim.x + blockIdx.x;
    const int swz = xcd_swz(lid, nwg);
    const int bn  = (swz % gridDim.x) * 128;
    const int bm  = (swz / gridDim.x) * 256;
    f32x4 acc[4][4];
    #pragma unroll
    for (int m = 0; m < 4; m++)
        #pragma unroll
        for (int n = 0; n < 4; n++)
            acc[m][n] = (f32x4){0.f, 0.f, 0.f, 0.f};

    gemm_core<GA_PLAIN, 0>(Ab, nullptr, Bt, 256, bm, bn, AlF, BlF, acc);

    const int lane = threadIdx.x & 63;
    const int wave = threadIdx.x >> 6;
    const int wr = (wave >> 1) * 64, wc = (wave & 1) * 64;
    const int l15 = lane & 15;
    const int b = bm >> 14;
    float Ksf[4];
    #pragma unroll
    for (int n = 0; n < 4; n++)
        Ksf[n] = Ksb[b * 256 + bn + wc + n * 16 + l15];
    #pragma unroll
    for (int m = 0; m < 4; m++)
        #pragma unroll
        for (int n = 0; n < 4; n++)
            #pragma unroll
            for (int j = 0; j < 4; j++) {
                float c = acc[m][n][j];
                acc[m][n][j] = c > 0.f ? c + 1.f : expf(c);   // elu+1
            }
    #pragma unroll
    for (int hh = 0; hh < 2; hh++) {
        #pragma unroll
        for (int m = 0; m < 4; m++)
            #pragma unroll
            for (int j = 0; j < 4; j++) {
                float part = acc[m][2 * hh][j] * Ksf[2 * hh]
                           + acc[m][2 * hh + 1][j] * Ksf[2 * hh + 1];
                part += __shfl_xor(part, 1, 64);
                part += __shfl_xor(part, 2, 64);
                part += __shfl_xor(part, 4, 64);
                part += __shfl_xor(part, 8, 64);
                float z = 4096.f / (part + 1e-6f);
                acc[m][2 * hh][j]     *= z;
                acc[m][2 * hh + 1][j] *= z;
            }
    }
    const int r0 = (lane >> 4) * 4;
    #pragma unroll
    for (int n = 0; n < 4; n++) {
        int col = bn + wc + n * 16 + l15;
        #pragma unroll
        for (int m = 0; m < 4; m++) {
            int rowb = bm + wr + m * 16 + r0;
            #pragma unroll
            for (int j = 0; j < 4; j++)
                Qz[(size_t)(rowb + j) * 256 + col] = f2bf(acc[m][n][j]);
        }
    }
}

// LayerNorm: 1 row (C=256) per wave (bf16 in/out) — conv-LN only
__global__ __launch_bounds__(256) void ln_bf16(
    const short* __restrict__ in, const float* __restrict__ g,
    const float* __restrict__ bta, short* __restrict__ out)
{
    const int wave = threadIdx.x >> 6, lane = threadIdx.x & 63;
    const size_t row = (size_t)blockIdx.x * 4 + wave;
    short4 s = reinterpret_cast<const short4*>(in)[row * 64 + lane];
    float v[4] = {bf2f(s.x), bf2f(s.y), bf2f(s.z), bf2f(s.w)};
    float s1 = v[0] + v[1] + v[2] + v[3];
    float s2 = v[0]*v[0] + v[1]*v[1] + v[2]*v[2] + v[3]*v[3];
    #pragma unroll
    for (int off = 1; off < 64; off <<= 1) {
        s1 += __shfl_xor(s1, off, 64);
        s2 += __shfl_xor(s2, off, 64);
    }
    float mean = s1 * (1.f / 256.f);
    float var  = s2 * (1.f / 256.f) - mean * mean;
    float inv  = rsqrtf(var + 1e-5f);
    float4 gg = reinterpret_cast<const float4*>(g)[lane];
    float4 bb = reinterpret_cast<const float4*>(bta)[lane];
    short4 o;
    o.x = f2bf((v[0] - mean) * inv * gg.x + bb.x);
    o.y = f2bf((v[1] - mean) * inv * gg.y + bb.y);
    o.z = f2bf((v[2] - mean) * inv * gg.z + bb.z);
    o.w = f2bf((v[3] - mean) * inv * gg.w + bb.w);
    reinterpret_cast<short4*>(out)[row * 64 + lane] = o;
}

// partial KV over a 128-row s-chunk; KVm fused [row][512]: K cols 0..255,
// V cols 256..511
__global__ __launch_bounds__(256) void kv_partial(
    const short* __restrict__ KVm,
    float* __restrict__ pKV, float* __restrict__ pKs)
{
    int blk = blockIdx.x;
    int bh = blk >> 5, chunk = blk & 31;
    int b = bh >> 3, h = bh & 7;
    int tid = threadIdx.x;
    int e = tid & 31, dq = tid >> 5;
    int d_l = tid & 31, r_l = tid >> 5;
    __shared__ float Ks[16][32], Vs[16][32];
    float acc[4] = {0.f, 0.f, 0.f, 0.f};
    float ks = 0.f;
    const size_t base = ((size_t)b * 4096 + chunk * 128) * 512 + h * 32;

    for (int s0 = 0; s0 < 128; s0 += 16) {
        Ks[r_l][d_l]     = bf2f(KVm[base + (size_t)(s0 + r_l) * 512 + d_l]);
        Ks[r_l + 8][d_l] = bf2f(KVm[base + (size_t)(s0 + r_l + 8) * 512 + d_l]);
        Vs[r_l][d_l]     = bf2f(KVm[base + (size_t)(s0 + r_l) * 512 + 256 + d_l]);
        Vs[r_l + 8][d_l] = bf2f(KVm[base + (size_t)(s0 + r_l + 8) * 512 + 256 + d_l]);
        __syncthreads();
        #pragma unroll
        for (int sr = 0; sr < 16; sr++) {
            float vv = Vs[sr][e];
            #pragma unroll
            for (int i = 0; i < 4; i++)
                acc[i] = fmaf(Ks[sr][dq * 4 + i], vv, acc[i]);
        }
        if (tid < 32) {
            #pragma unroll
            for (int sr = 0; sr < 16; sr++) ks += Ks[sr][tid];
        }
        __syncthreads();
    }
    #pragma unroll
    for (int i = 0; i < 4; i++)
        pKV[(size_t)blk * 1024 + (dq * 4 + i) * 32 + e] = acc[i];
    if (tid < 32) pKs[blk * 32 + tid] = ks;
}

// reduce 32 chunks -> KV[bh][1024], Ksum[bh][32]
__global__ __launch_bounds__(256) void kv_reduce(
    const float* __restrict__ pKV, const float* __restrict__ pKs,
    float* __restrict__ KV, float* __restrict__ Ksum)
{
    int bh = blockIdx.x;
    int tid = threadIdx.x;
    float s0 = 0.f, s1 = 0.f, s2 = 0.f, s3 = 0.f;
    for (int c = 0; c < 32; c++) {
        const float* p = &pKV[(size_t)(bh * 32 + c) * 1024];
        s0 += p[tid]; s1 += p[tid + 256]; s2 += p[tid + 512]; s3 += p[tid + 768];
    }
    KV[bh * 1024 + tid]       = s0;
    KV[bh * 1024 + tid + 256] = s1;
    KV[bh * 1024 + tid + 512] = s2;
    KV[bh * 1024 + tid + 768] = s3;
    if (tid < 32) {
        float s = 0.f;
        for (int c = 0; c < 32; c++) s += pKs[(bh * 32 + c) * 32 + tid];
        Ksum[bh * 32 + tid] = s;
    }
}

extern "C" void kernel_launch(void* const* d_in, const int* in_sizes, int n_in,
                              void* d_out, int out_size, void* d_ws, size_t ws_size,
                              hipStream_t stream) {
    const float* x      = (const float*)d_in[0];
    const float* sr_w   = (const float*)d_in[1];
    const float* sr_b   = (const float*)d_in[2];
    const float* norm_g = (const float*)d_in[3];
    const float* norm_b = (const float*)d_in[4];
    const float* wq     = (const float*)d_in[5];
    const float* wk     = (const float*)d_in[6];
    const float* wv     = (const float*)d_in[7];
    const float* wm     = (const float*)d_in[8];
    const float* mlp_w1 = (const float*)d_in[9];
    const float* mlp_w2 = (const float*)d_in[10];
    const float* n1_g   = (const float*)d_in[11];
    const float* n1_b   = (const float*)d_in[12];
    const float* n2_g   = (const float*)d_in[13];
    const float* n2_b   = (const float*)d_in[14];
    float* out = (float*)d_out;

    // ---- workspace layout (~141 MB of ~256 MiB) ----
    short* Wct = (short*)d_ws;          // [256][1024]
    short* Wqt = Wct + 262144;          // [256][256]
    short* Wkt = Wqt + 65536;           // [256][256]  \ contiguous = [512][256]
    short* Wvt = Wkt + 65536;           // [256][256]  /
    short* W1t = Wvt + 65536;           // [512][512]
    short* W2t = W1t + 262144;          // [256][512]
    short* W2a = W2t + 131072;          // [4][256][256]
    float* KVb = (float*)(W2a + 262144);// 32768 f
    float* Ksb = KVb + 32768;           // 1024 f
    float* pKs = Ksb + 1024;            // 32768 f
    float* pKV = pKs + 32768;           // 1048576 f
    short* xb16 = (short*)(pKV + 1048576);   // [65536][256] 32MB
    short* SCR  = xb16 + 16777216;           // 32MB scratch:
    short* xs16 = SCR;                  //   [16384][256] 8MB
    short* KVm  = SCR + 4194304;        //   [16384][512] 16MB fused K|V
    short* Qz   = SCR;                  // ALIAS 32MB (xs/KVm dead)
    short* Hc   = SCR + 16777216;       // [65536][512] 64MB
    short* Mb16 = (short*)d_out;        // msg_ln bf16 in d_out (overwritten)

    const float inv_S = 1.f / 4096.f;

    // prep: weights + x cast
    prep_weights<<<3328, 256, 0, stream>>>(
        sr_w, wq, wk, wv, mlp_w1, mlp_w2, Wct, Wqt, Wkt, Wvt, W1t, W2t);
    cast_bf16<<<2048, 256, 0, stream>>>(x, xb16, 4194304);

    // conv as GEMM + bias -> xs16; LN in place
    gemm_bf16<GA_CONV, EP_BIAS, 0><<<dim3(2, 64), 512, 0, stream>>>(
        xb16, nullptr, Wct, sr_b, xs16, 256, 1024, 0.f);
    ln_bf16<<<4096, 256, 0, stream>>>(xs16, norm_g, norm_b, xs16);

    // fused K|V GEMM: B = Wkt||Wvt [512][256]
    gemm_bf16<GA_PLAIN, EP_KV, 0><<<dim3(4, 64), 512, 0, stream>>>(
        xs16, nullptr, Wkt, nullptr, KVm, 512, 256, inv_S);

    // KV + Ksum, fold KV@wm -> W2a
    kv_partial<<<1024, 256, 0, stream>>>(KVm, pKV, pKs);
    kv_reduce<<<32, 256, 0, stream>>>(pKV, pKs, KVb, Ksb);
    w2_prep<<<1024, 256, 0, stream>>>(KVb, wm, W2a);

    // Qz = Z .* (elu(x@wq)+1)  [bf16] (aliases dead xs/KVm)
    gemm_qz<<<dim3(2, 256), 512, 0, stream>>>(xb16, Wqt, Ksb, Qz);

    // msg_ln = LN1(Qz @ W2a[b]) -> Mb16 (bf16, in d_out)  [fused]
    gemm_ln<1, 0><<<512, 512, 0, stream>>>(
        Qz, W2a, n1_g, n1_b, nullptr, Mb16, 256);

    // h = relu([x|msg_ln] @ w1) -> Hc  (256x128 tiles, XCD-swizzled)
    gemm_bf16<GA_CONCAT, EP_RELU, 0><<<dim3(4, 256), 512, 0, stream>>>(
        xb16, Mb16, W1t, nullptr, Hc, 512, 512, 0.f);

    // out = LN2(h @ w2) + x  (fused; residual read bf16)
    gemm_ln<0, 1><<<512, 512, 0, stream>>>(
        Hc, W2t, n2_g, n2_b, xb16, out, 512);
}